// Round 2
// baseline (4133.515 us; speedup 1.0000x reference)
//
#include <hip/hip_runtime.h>
#include <hip/hip_bf16.h>

// ---------------- problem constants ----------------
#define H_DIM 256
#define O_DIM 128
#define NEXP 4
#define G_DIM 64

#define FLAG_BETA 1
#define FLAG_RELU 2

// ---------------- utility: zero ints ----------------
__global__ void zero_i_kernel(int* __restrict__ p, long n) {
    long i = (long)blockIdx.x * blockDim.x + threadIdx.x;
    if (i < n) p[i] = 0;
}

// ---------------- encoder stage 1: u = relu(x[:,4:10] @ enc_W1 + b1) ----------------
__global__ void encoder1_kernel(const float* __restrict__ x, const float* __restrict__ W1,
                                const float* __restrict__ b1, float* __restrict__ u,
                                int N, int F) {
    int n = blockIdx.x;
    int j = threadIdx.x;                      // 0..255
    float acc = b1[j];
    #pragma unroll
    for (int c = 0; c < 6; ++c)
        acc += x[(long)n * F + 4 + c] * W1[c * H_DIM + j];
    u[(long)n * H_DIM + j] = fmaxf(acc, 0.f);
}

// ---------------- generic tiled SGEMM, K fixed = 256 ----------------
// C = act( beta*C + A @ W + bias ), A:(M,256) W:(256,Nc) C:(M,Nc) row-major
__global__ __launch_bounds__(256)
void gemm256_kernel(const float* __restrict__ A,
                    const float* __restrict__ W,
                    const float* __restrict__ bias,
                    float* __restrict__ C,
                    int M, int Nc, int flags) {
    const int K = 256;
    __shared__ float As[16][68];   // [k][row]
    __shared__ float Ws[16][68];   // [k][col]

    int tid = threadIdx.x;
    int tx = tid & 15, ty = tid >> 4;
    int row0 = blockIdx.x * 64;
    int col0 = blockIdx.y * 64;
    float acc[4][4] = {};

    int lrow = tid >> 2, kq = tid & 3;        // A-load: 64 rows x 4 float4
    int wk = tid >> 4, wc = (tid & 15) * 4;   // W-load: 16 k-rows x 16 float4

    for (int k0 = 0; k0 < K; k0 += 16) {
        float4 av = make_float4(0.f, 0.f, 0.f, 0.f);
        int arow = row0 + lrow;
        if (arow < M) av = *(const float4*)(A + (long)arow * K + k0 + kq * 4);
        As[kq * 4 + 0][lrow] = av.x;
        As[kq * 4 + 1][lrow] = av.y;
        As[kq * 4 + 2][lrow] = av.z;
        As[kq * 4 + 3][lrow] = av.w;
        float4 wv = *(const float4*)(W + (long)(k0 + wk) * Nc + col0 + wc);
        *(float4*)&Ws[wk][wc] = wv;
        __syncthreads();
        #pragma unroll
        for (int kk = 0; kk < 16; ++kk) {
            float a[4], b[4];
            #pragma unroll
            for (int i = 0; i < 4; ++i) a[i] = As[kk][ty * 4 + i];
            #pragma unroll
            for (int j = 0; j < 4; ++j) b[j] = Ws[kk][tx * 4 + j];
            #pragma unroll
            for (int i = 0; i < 4; ++i)
                #pragma unroll
                for (int j = 0; j < 4; ++j) acc[i][j] += a[i] * b[j];
        }
        __syncthreads();
    }
    #pragma unroll
    for (int i = 0; i < 4; ++i) {
        int r = row0 + ty * 4 + i;
        if (r >= M) break;
        #pragma unroll
        for (int j = 0; j < 4; ++j) {
            int c = col0 + tx * 4 + j;
            float v = acc[i][j];
            if (flags & FLAG_BETA) v += C[(long)r * Nc + c];
            if (bias) v += bias[c];
            if (flags & FLAG_RELU) v = fmaxf(v, 0.f);
            C[(long)r * Nc + c] = v;
        }
    }
}

// ---------------- graph-stat histograms ----------------
__global__ void hist_nodes_kernel(const int* __restrict__ batch, int n, int* __restrict__ gn) {
    __shared__ int bins[G_DIM];
    int t = threadIdx.x;
    if (t < G_DIM) bins[t] = 0;
    __syncthreads();
    for (long i = (long)blockIdx.x * blockDim.x + t; i < n; i += (long)gridDim.x * blockDim.x)
        atomicAdd(&bins[batch[i]], 1);
    __syncthreads();
    if (t < G_DIM) atomicAdd(&gn[t], bins[t]);
}

__global__ void hist_edges_kernel(const int* __restrict__ ei, const int* __restrict__ batch,
                                  int E, int* __restrict__ ge) {
    __shared__ int bins[G_DIM];
    int t = threadIdx.x;
    if (t < G_DIM) bins[t] = 0;
    __syncthreads();
    for (long i = (long)blockIdx.x * blockDim.x + t; i < E; i += (long)gridDim.x * blockDim.x)
        atomicAdd(&bins[batch[ei[i]]], 1);   // src = ei[0*E + i]
    __syncthreads();
    if (t < G_DIM) atomicAdd(&ge[t], bins[t]);
}

// ---------------- graph stats ----------------
__global__ void graph_stats_kernel(const int* __restrict__ gn, const int* __restrict__ ge,
                                   float* __restrict__ feats_norm, float* __restrict__ logn_norm) {
    int g = threadIdx.x;                      // 64 threads = 1 wave
    float nv = fmaxf((float)gn[g], 1.0f);
    float ev = (float)ge[g];
    float density = ev / fmaxf(nv * (nv - 1.0f), 1.0f);
    float logn = logf(nv);
    float mn = logn, mx = logn;
    for (int o = 32; o; o >>= 1) {
        mn = fminf(mn, __shfl_xor(mn, o));
        mx = fmaxf(mx, __shfl_xor(mx, o));
    }
    logn_norm[g] = (logn - mn) / (mx - mn + 1e-6f);
    float f[3] = {nv, ev, density};
    #pragma unroll
    for (int c = 0; c < 3; ++c) {
        float s = f[c];
        for (int o = 32; o; o >>= 1) s += __shfl_xor(s, o);
        float mean = s / 64.f;
        float d = f[c] - mean;
        float v = d * d;
        for (int o = 32; o; o >>= 1) v += __shfl_xor(v, o);
        float stdv = sqrtf(v / 64.f);
        feats_norm[g * 3 + c] = d / (stdv + 1e-6f);
    }
}

// ---------------- router epilogue ----------------
__global__ __launch_bounds__(256)
void router_epi_kernel(const float* __restrict__ t, const int* __restrict__ batch,
                       const float* __restrict__ feats_norm, const float* __restrict__ logn_norm,
                       const float* __restrict__ rW1, const float* __restrict__ rb1,
                       const float* __restrict__ lng, const float* __restrict__ lnb,
                       const float* __restrict__ rW2, const float* __restrict__ rb2,
                       const float* __restrict__ centers, float* __restrict__ w, int N) {
    int wave = threadIdx.x >> 6, lane = threadIdx.x & 63;
    int n = blockIdx.x * 4 + wave;
    if (n >= N) return;
    int g = batch[n];
    float sf0 = feats_norm[g * 3 + 0], sf1 = feats_norm[g * 3 + 1], sf2 = feats_norm[g * 3 + 2];
    float ln = logn_norm[g];
    float tv[4];
    #pragma unroll
    for (int q = 0; q < 4; ++q) {
        int j = lane + 64 * q;
        tv[q] = t[(long)n * H_DIM + j] + rb1[j]
              + sf0 * rW1[256 * H_DIM + j] + sf1 * rW1[257 * H_DIM + j] + sf2 * rW1[258 * H_DIM + j];
    }
    float s = tv[0] + tv[1] + tv[2] + tv[3];
    for (int o = 32; o; o >>= 1) s += __shfl_xor(s, o);
    float mean = s / 256.f;
    float vs = 0.f;
    #pragma unroll
    for (int q = 0; q < 4; ++q) { float d = tv[q] - mean; vs += d * d; }
    for (int o = 32; o; o >>= 1) vs += __shfl_xor(vs, o);
    float rstd = rsqrtf(vs / 256.f + 1e-5f);
    float le[NEXP] = {0.f, 0.f, 0.f, 0.f};
    #pragma unroll
    for (int q = 0; q < 4; ++q) {
        int j = lane + 64 * q;
        float y = (tv[q] - mean) * rstd * lng[j] + lnb[j];
        y = fmaxf(y, 0.f);
        #pragma unroll
        for (int e = 0; e < NEXP; ++e) le[e] += y * rW2[j * NEXP + e];
    }
    #pragma unroll
    for (int e = 0; e < NEXP; ++e)
        for (int o = 32; o; o >>= 1) le[e] += __shfl_xor(le[e], o);
    if (lane == 0) {
        float p[NEXP];
        float m = -1e30f;
        #pragma unroll
        for (int e = 0; e < NEXP; ++e) {
            float d = ln - centers[e];
            float lv = 0.7f * (le[e] + rb2[e]) + 0.3f * (-(d * d));
            p[e] = lv;
            m = fmaxf(m, lv);
        }
        float ssum = 0.f;
        #pragma unroll
        for (int e = 0; e < NEXP; ++e) { p[e] = expf(p[e] - m); ssum += p[e]; }
        #pragma unroll
        for (int e = 0; e < NEXP; ++e) p[e] /= ssum;
        int i1 = 0;
        for (int e = 1; e < NEXP; ++e) if (p[e] > p[i1]) i1 = e;
        int i2 = -1;
        for (int e = 0; e < NEXP; ++e) { if (e == i1) continue; if (i2 < 0 || p[e] > p[i2]) i2 = e; }
        float denom = p[i1] + p[i2] + 1e-8f;
        float out4[NEXP] = {0.f, 0.f, 0.f, 0.f};
        out4[i1] = p[i1] / denom;
        out4[i2] = p[i2] / denom;
        #pragma unroll
        for (int e = 0; e < NEXP; ++e) w[(long)n * NEXP + e] = out4[e];
    }
}

// ---------------- CSR build ----------------
__global__ void count_dst_kernel(const int* __restrict__ ei, int E, int* __restrict__ cnt) {
    int i = blockIdx.x * blockDim.x + threadIdx.x;
    if (i < E) atomicAdd(&cnt[ei[E + i]], 1);
}

__global__ __launch_bounds__(1024)
void scan_kernel(const int* __restrict__ cnt, int* __restrict__ row_ptr, int n) {
    __shared__ int buf[1024];
    __shared__ int carry_s;
    int tid = threadIdx.x;
    if (tid == 0) carry_s = 0;
    __syncthreads();
    for (int base = 0; base < n; base += 1024) {
        int v = (base + tid < n) ? cnt[base + tid] : 0;
        buf[tid] = v;
        __syncthreads();
        for (int off = 1; off < 1024; off <<= 1) {
            int tv = (tid >= off) ? buf[tid - off] : 0;
            __syncthreads();
            buf[tid] += tv;
            __syncthreads();
        }
        int carry = carry_s;
        if (base + tid < n) row_ptr[base + tid] = carry + buf[tid] - v;
        __syncthreads();
        if (tid == 1023) carry_s = carry + buf[1023];
        __syncthreads();
    }
    if (tid == 0) row_ptr[n] = carry_s;
}

__global__ void fill_csr_kernel(const int* __restrict__ ei, int E, const int* __restrict__ row_ptr,
                                int* __restrict__ fillc, int* __restrict__ srcs) {
    int i = blockIdx.x * blockDim.x + threadIdx.x;
    if (i < E) {
        int d = ei[E + i];
        int pos = row_ptr[d] + atomicAdd(&fillc[d], 1);
        srcs[pos] = ei[i];
    }
}

// ---------------- CSR gather: out[n,:] = sum_{s in in(n)} feat[s,:]  (Hd=256) ----------------
__global__ void agg_gather_kernel(const float* __restrict__ feat, float* __restrict__ out,
                                  const int* __restrict__ row_ptr, const int* __restrict__ srcs,
                                  int N) {
    int n = blockIdx.x;
    int j = threadIdx.x;
    float acc = 0.f;
    int p0 = row_ptr[n], p1 = row_ptr[n + 1];
    for (int p = p0; p < p1; ++p)
        acc += feat[(long)srcs[p] * H_DIM + j];
    out[(long)n * H_DIM + j] = acc;
}

// ---------------- per-expert final: out (+)= w[n,e]*(Agg(P)[n,:] + R[n,:] + b2e) ----------------
__global__ __launch_bounds__(128)
void final_mix_e_kernel(const float* __restrict__ P, const float* __restrict__ R,
                        const float* __restrict__ b2e, const float* __restrict__ wts, int e,
                        const int* __restrict__ row_ptr, const int* __restrict__ srcs,
                        float* __restrict__ out, int N, int init) {
    int n = blockIdx.x, o = threadIdx.x;
    float we = wts[(long)n * NEXP + e];
    float prev = init ? 0.f : out[(long)n * O_DIM + o];
    if (we == 0.f) {
        if (init) out[(long)n * O_DIM + o] = 0.f;
        return;
    }
    float acc = R[(long)n * O_DIM + o] + b2e[o];
    int p0 = row_ptr[n], p1 = row_ptr[n + 1];
    for (int p = p0; p < p1; ++p)
        acc += P[(long)srcs[p] * O_DIM + o];
    out[(long)n * O_DIM + o] = prev + we * acc;
}

// ==================== host launcher ====================
extern "C" void kernel_launch(void* const* d_in, const int* in_sizes, int n_in,
                              void* d_out, int out_size, void* d_ws, size_t ws_size,
                              hipStream_t stream) {
    const float* x       = (const float*)d_in[0];
    const int*   ei      = (const int*)  d_in[1];
    const int*   batch   = (const int*)  d_in[2];
    const float* enc_W1  = (const float*)d_in[3];
    const float* enc_b1  = (const float*)d_in[4];
    const float* enc_W2  = (const float*)d_in[5];
    const float* enc_b2  = (const float*)d_in[6];
    const float* r_W1    = (const float*)d_in[7];
    const float* r_b1    = (const float*)d_in[8];
    const float* ln_g    = (const float*)d_in[9];
    const float* ln_b    = (const float*)d_in[10];
    const float* r_W2    = (const float*)d_in[11];
    const float* r_b2    = (const float*)d_in[12];
    const float* centers = (const float*)d_in[13];
    const float* W0_rel  = (const float*)d_in[14];
    const float* b0_rel  = (const float*)d_in[15];
    const float* W0_root = (const float*)d_in[16];
    const float* W1_rel  = (const float*)d_in[17];
    const float* b1_rel  = (const float*)d_in[18];
    const float* W1_root = (const float*)d_in[19];
    const float* W2_rel  = (const float*)d_in[20];
    const float* b2_rel  = (const float*)d_in[21];
    const float* W2_root = (const float*)d_in[22];

    const int N = in_sizes[2];
    const int E = in_sizes[1] / 2;
    const int F = in_sizes[0] / N;

    // ---- workspace layout (256B-aligned slabs); peak ~210 MB ----
    char* ws = (char*)d_ws;
    size_t off = 0;
    auto alloc = [&](size_t bytes) -> void* {
        void* p = ws + off;
        off += (bytes + 255) & ~(size_t)255;
        return p;
    };
    int* cnt      = (int*)alloc((size_t)N * 4);
    int* fillc    = (int*)alloc((size_t)N * 4);
    int* gn       = (int*)alloc((size_t)G_DIM * 4);
    int* ge       = (int*)alloc((size_t)G_DIM * 4);
    size_t zero_bytes = off;                       // zero cnt..ge (incl. padding)
    int* row_ptr  = (int*)alloc((size_t)(N + 1) * 4);
    int* srcs     = (int*)alloc((size_t)E * 4);
    float* feats_norm = (float*)alloc((size_t)G_DIM * 3 * 4);
    float* logn_norm  = (float*)alloc((size_t)G_DIM * 4);
    float* wts    = (float*)alloc((size_t)N * NEXP * 4);
    float* h      = (float*)alloc((size_t)N * H_DIM * 4);   // 51.2 MB
    float* T      = (float*)alloc((size_t)N * H_DIM * 4);   // 51.2 MB scratch (u, t, W0_rel-prod, W1_rel-prod)
    float* buf0   = (float*)alloc((size_t)N * H_DIM * 4);   // 51.2 MB (hE0, then P|R)
    float* U      = (float*)alloc((size_t)N * H_DIM * 4);   // 51.2 MB (aggE / hE1)
    (void)ws_size; (void)out_size; (void)n_in;

    float* u = T;
    float* t = T;
    float* P = buf0;                                  // buf0 dead after layer-1 root GEMM
    float* R = buf0 + (size_t)N * O_DIM;
    float* out = (float*)d_out;

    dim3 blk256(256);
    dim3 gH((N + 63) / 64, H_DIM / 64, 1);
    dim3 gO((N + 63) / 64, O_DIM / 64, 1);

    // 0) zero counters
    {
        long nz = (long)(zero_bytes / 4);
        zero_i_kernel<<<dim3((nz + 255) / 256), blk256, 0, stream>>>((int*)ws, nz);
    }
    // 1) encoder stage 1 -> u (in T)
    encoder1_kernel<<<dim3(N), blk256, 0, stream>>>(x, enc_W1, enc_b1, u, N, F);
    // 2) h = u @ enc_W2 + enc_b2
    gemm256_kernel<<<gH, blk256, 0, stream>>>(u, enc_W2, enc_b2, h, N, H_DIM, 0);
    // 3-5) graph stats
    hist_nodes_kernel<<<dim3(256), blk256, 0, stream>>>(batch, N, gn);
    hist_edges_kernel<<<dim3(512), blk256, 0, stream>>>(ei, batch, E, ge);
    graph_stats_kernel<<<dim3(1), dim3(64), 0, stream>>>(gn, ge, feats_norm, logn_norm);
    // 6) t = h @ r_W1[0:256,:]  (into T)
    gemm256_kernel<<<gH, blk256, 0, stream>>>(h, r_W1, nullptr, t, N, H_DIM, 0);
    // 7) router epilogue -> wts
    router_epi_kernel<<<dim3((N + 3) / 4), blk256, 0, stream>>>(
        t, batch, feats_norm, logn_norm, r_W1, r_b1, ln_g, ln_b, r_W2, r_b2, centers, wts, N);
    // 8-10) CSR build
    count_dst_kernel<<<dim3((E + 255) / 256), blk256, 0, stream>>>(ei, E, cnt);
    scan_kernel<<<dim3(1), dim3(1024), 0, stream>>>(cnt, row_ptr, N);
    fill_csr_kernel<<<dim3((E + 255) / 256), blk256, 0, stream>>>(ei, E, row_ptr, fillc, srcs);

    const long sWH = (long)H_DIM * H_DIM;
    const long sWO = (long)H_DIM * O_DIM;
    // ---- per-expert pipeline (slab-reusing; uses Agg(X)@W == Agg(X@W)) ----
    for (int e = 0; e < NEXP; ++e) {
        // T = h @ W0_rel[e]
        gemm256_kernel<<<gH, blk256, 0, stream>>>(h, W0_rel + e * sWH, nullptr, T, N, H_DIM, 0);
        // buf0 = Agg(T)
        agg_gather_kernel<<<dim3(N), blk256, 0, stream>>>(T, buf0, row_ptr, srcs, N);
        // buf0 = relu(buf0 + h @ W0_root[e] + b0[e])
        gemm256_kernel<<<gH, blk256, 0, stream>>>(h, W0_root + e * sWH, b0_rel + e * H_DIM,
                                                  buf0, N, H_DIM, FLAG_BETA | FLAG_RELU);
        // T = buf0 @ W1_rel[e]
        gemm256_kernel<<<gH, blk256, 0, stream>>>(buf0, W1_rel + e * sWH, nullptr, T, N, H_DIM, 0);
        // U = Agg(T)
        agg_gather_kernel<<<dim3(N), blk256, 0, stream>>>(T, U, row_ptr, srcs, N);
        // U = relu(U + buf0 @ W1_root[e] + b1[e])   (hE1)
        gemm256_kernel<<<gH, blk256, 0, stream>>>(buf0, W1_root + e * sWH, b1_rel + e * H_DIM,
                                                  U, N, H_DIM, FLAG_BETA | FLAG_RELU);
        // P = U @ W2_rel[e]; R = U @ W2_root[e]   (into dead buf0)
        gemm256_kernel<<<gO, blk256, 0, stream>>>(U, W2_rel + e * sWO, nullptr, P, N, O_DIM, 0);
        gemm256_kernel<<<gO, blk256, 0, stream>>>(U, W2_root + e * sWO, nullptr, R, N, O_DIM, 0);
        // out (+)= w[:,e] * (Agg(P) + R + b2[e])
        final_mix_e_kernel<<<dim3(N), dim3(128), 0, stream>>>(
            P, R, b2_rel + e * O_DIM, wts, e, row_ptr, srcs, out, N, e == 0 ? 1 : 0);
    }
}

// Round 4
// 3277.860 us; speedup vs baseline: 1.2610x; 1.2610x over previous
//
#include <hip/hip_runtime.h>
#include <hip/hip_bf16.h>

// ---------------- problem constants ----------------
#define H_DIM 256
#define O_DIM 128
#define NEXP 4
#define G_DIM 64

#define FLAG_BETA 1
#define FLAG_RELU 2

typedef unsigned short ushort_t;
typedef unsigned int uint_t;
typedef __attribute__((ext_vector_type(8))) short short8;
typedef __attribute__((ext_vector_type(4))) float floatx4;

// ---------------- bf16 helpers (RNE) ----------------
__device__ __forceinline__ float bf2f(ushort_t u) {
    union { uint_t i; float f; } c; c.i = ((uint_t)u) << 16; return c.f;
}
__device__ __forceinline__ ushort_t f2bf(float f) {
    union { float f; uint_t i; } c; c.f = f;
    uint_t x = c.i;
    uint_t r = (x + 0x7fffu + ((x >> 16) & 1u)) >> 16;
    return (ushort_t)r;
}

// ---------------- async global->LDS 16B ----------------
__device__ __forceinline__ void load16_lds(const void* g, void* l) {
    __builtin_amdgcn_global_load_lds(
        (const __attribute__((address_space(1))) unsigned int*)g,
        (__attribute__((address_space(3))) unsigned int*)l, 16, 0, 0);
}

// ---------------- utility: zero ints ----------------
__global__ void zero_i_kernel(int* __restrict__ p, long n) {
    long i = (long)blockIdx.x * blockDim.x + threadIdx.x;
    if (i < n) p[i] = 0;
}

// ---------------- weight transpose + split to bf16 hi/lo: Wt[z][n][k] = W[z][k][n] ----------------
__global__ void wsplit_kernel(const float* __restrict__ W, ushort_t* __restrict__ Wh,
                              ushort_t* __restrict__ Wl, int K, int Nc) {
    int z = blockIdx.y;
    int i = blockIdx.x * 256 + threadIdx.x;      // i = n*K + k
    if (i >= K * Nc) return;
    int nn = i / K, kk = i - nn * K;
    float v = W[(long)z * K * Nc + (long)kk * Nc + nn];
    ushort_t hi = f2bf(v);
    Wh[(long)z * K * Nc + i] = hi;
    Wl[(long)z * K * Nc + i] = f2bf(v - bf2f(hi));
}

// ---------------- encoder stage 1 (fp32, round-2 verified) ----------------
__global__ void encoder1_kernel(const float* __restrict__ x, const float* __restrict__ W1,
                                const float* __restrict__ b1, float* __restrict__ u,
                                int N, int F) {
    int n = blockIdx.x;
    int j = threadIdx.x;                      // 0..255
    float acc = b1[j];
    #pragma unroll
    for (int c = 0; c < 6; ++c)
        acc += x[(long)n * F + 4 + c] * W1[c * H_DIM + j];
    u[(long)n * H_DIM + j] = fmaxf(acc, 0.f);
}

// ---------------- fp32 vector SGEMM (round-2 verified) — used for router path only ----------------
__global__ __launch_bounds__(256)
void gemm256_kernel(const float* __restrict__ A,
                    const float* __restrict__ W,
                    const float* __restrict__ bias,
                    float* __restrict__ C,
                    int M, int Nc, int flags) {
    const int K = 256;
    __shared__ float As[16][68];
    __shared__ float Ws[16][68];

    int tid = threadIdx.x;
    int tx = tid & 15, ty = tid >> 4;
    int row0 = blockIdx.x * 64;
    int col0 = blockIdx.y * 64;
    float acc[4][4] = {};

    int lrow = tid >> 2, kq = tid & 3;
    int wk = tid >> 4, wc = (tid & 15) * 4;

    for (int k0 = 0; k0 < K; k0 += 16) {
        float4 av = make_float4(0.f, 0.f, 0.f, 0.f);
        int arow = row0 + lrow;
        if (arow < M) av = *(const float4*)(A + (long)arow * K + k0 + kq * 4);
        As[kq * 4 + 0][lrow] = av.x;
        As[kq * 4 + 1][lrow] = av.y;
        As[kq * 4 + 2][lrow] = av.z;
        As[kq * 4 + 3][lrow] = av.w;
        float4 wv = *(const float4*)(W + (long)(k0 + wk) * Nc + col0 + wc);
        *(float4*)&Ws[wk][wc] = wv;
        __syncthreads();
        #pragma unroll
        for (int kk = 0; kk < 16; ++kk) {
            float a[4], b[4];
            #pragma unroll
            for (int i = 0; i < 4; ++i) a[i] = As[kk][ty * 4 + i];
            #pragma unroll
            for (int j = 0; j < 4; ++j) b[j] = Ws[kk][tx * 4 + j];
            #pragma unroll
            for (int i = 0; i < 4; ++i)
                #pragma unroll
                for (int j = 0; j < 4; ++j) acc[i][j] += a[i] * b[j];
        }
        __syncthreads();
    }
    #pragma unroll
    for (int i = 0; i < 4; ++i) {
        int r = row0 + ty * 4 + i;
        if (r >= M) break;
        #pragma unroll
        for (int j = 0; j < 4; ++j) {
            int c = col0 + tx * 4 + j;
            float v = acc[i][j];
            if (flags & FLAG_BETA) v += C[(long)r * Nc + c];
            if (bias) v += bias[c];
            if (flags & FLAG_RELU) v = fmaxf(v, 0.f);
            C[(long)r * Nc + c] = v;
        }
    }
}

// ---------------- split-bf16 MFMA GEMM: C = act([add] + A @ Wt^T + [bias]), fp32 in/out ----------------
// A: (M,256) fp32 row-major. Wh/Wl: (Nc,256) bf16 row-major (transposed, hi/lo split).
// A*W ~= Ah*Wh + Ah*Wl + Al*Wh (fp32 accum) -> ~2^-18 relative error.
// 128x128 tile, BK=32, 4 waves (2x2), each wave 64x64 via 4x4 frags of 16x16x32.
__global__ __launch_bounds__(256)
void gemm_mfma3_kernel(const float* __restrict__ A,
                       const ushort_t* __restrict__ Wh, const ushort_t* __restrict__ Wl,
                       const float* __restrict__ addsrc, const float* __restrict__ bias,
                       float* __restrict__ C, int M, int Nc, int flags) {
    __shared__ alignas(16) float    Asl[128 * 32];   // [m][k] fp32, 128B rows (16 KB)
    __shared__ alignas(16) ushort_t Bhs[128 * 32];   // [n][k] bf16 hi (8 KB)
    __shared__ alignas(16) ushort_t Bls[128 * 32];   // [n][k] bf16 lo (8 KB)
    const int tid = threadIdx.x;
    const int wave = tid >> 6, lane = tid & 63;
    const int row0 = blockIdx.x * 128, col0 = blockIdx.y * 128;
    const int wr = (wave >> 1) * 64, wc = (wave & 1) * 64;

    floatx4 acc[4][4] = {};

    // ---- A staging (fp32): 4 instrs/wave, 8 rows each; lane -> (sr=lane>>3, sc=(lane&7)*4 floats)
    const int asr = lane >> 3, asc = (lane & 7) * 4;
    const float* Ag[4];
    float* Alds[4];
    #pragma unroll
    for (int q = 0; q < 4; ++q) {
        int ar = row0 + wave * 32 + q * 8 + asr;
        ar = ar < M ? ar : M - 1;                 // clamp; tail rows discarded at store
        Ag[q] = A + (long)ar * 256 + asc;
        Alds[q] = &Asl[(wave * 32 + q * 8) * 32];
    }
    // ---- B staging (bf16): 2 instrs/wave per array; lane -> (sr=lane>>2, sc=(lane&3)*8 bf16)
    const int bsr = lane >> 2, bsc = (lane & 3) * 8;
    const ushort_t* Bhg0 = Wh + (long)(col0 + wave * 32 + bsr) * 256 + bsc;
    const ushort_t* Bhg1 = Bhg0 + 16 * 256;
    const ushort_t* Blg0 = Wl + (long)(col0 + wave * 32 + bsr) * 256 + bsc;
    const ushort_t* Blg1 = Blg0 + 16 * 256;
    ushort_t* Bhl0 = &Bhs[(wave * 32) * 32];
    ushort_t* Bhl1 = &Bhs[(wave * 32 + 16) * 32];
    ushort_t* Bll0 = &Bls[(wave * 32) * 32];
    ushort_t* Bll1 = &Bls[(wave * 32 + 16) * 32];

    const int fm = lane & 15, fq = lane >> 4;

    for (int k0 = 0; k0 < 256; k0 += 32) {
        #pragma unroll
        for (int q = 0; q < 4; ++q) load16_lds(Ag[q] + k0, Alds[q]);
        load16_lds(Bhg0 + k0, Bhl0);
        load16_lds(Bhg1 + k0, Bhl1);
        load16_lds(Blg0 + k0, Bll0);
        load16_lds(Blg1 + k0, Bll1);
        __syncthreads();

        short8 ah[4], al[4], bh[4], bl[4];
        #pragma unroll
        for (int i = 0; i < 4; ++i) {
            const float* ap = &Asl[(wr + i * 16 + fm) * 32 + fq * 8];
            float4 v0 = *(const float4*)ap;
            float4 v1 = *(const float4*)(ap + 4);
            float av[8] = {v0.x, v0.y, v0.z, v0.w, v1.x, v1.y, v1.z, v1.w};
            #pragma unroll
            for (int j = 0; j < 8; ++j) {
                ushort_t hi = f2bf(av[j]);
                ah[i][j] = (short)hi;
                al[i][j] = (short)f2bf(av[j] - bf2f(hi));
            }
        }
        #pragma unroll
        for (int j = 0; j < 4; ++j) {
            bh[j] = *(const short8*)&Bhs[(wc + j * 16 + fm) * 32 + fq * 8];
            bl[j] = *(const short8*)&Bls[(wc + j * 16 + fm) * 32 + fq * 8];
        }
        #pragma unroll
        for (int i = 0; i < 4; ++i)
            #pragma unroll
            for (int j = 0; j < 4; ++j) {
                acc[i][j] = __builtin_amdgcn_mfma_f32_16x16x32_bf16(al[i], bh[j], acc[i][j], 0, 0, 0);
                acc[i][j] = __builtin_amdgcn_mfma_f32_16x16x32_bf16(ah[i], bl[j], acc[i][j], 0, 0, 0);
                acc[i][j] = __builtin_amdgcn_mfma_f32_16x16x32_bf16(ah[i], bh[j], acc[i][j], 0, 0, 0);
            }
        __syncthreads();
    }

    // epilogue: C/D layout col=lane&15, row=(lane>>4)*4+reg  [verified m89]
    #pragma unroll
    for (int i = 0; i < 4; ++i) {
        #pragma unroll
        for (int j = 0; j < 4; ++j) {
            int col = col0 + wc + j * 16 + fm;
            int rowb = row0 + wr + i * 16 + fq * 4;
            #pragma unroll
            for (int r = 0; r < 4; ++r) {
                int row = rowb + r;
                if (row < M) {
                    float v = acc[i][j][r];
                    if (flags & FLAG_BETA) v += addsrc[(long)row * Nc + col];
                    if (bias) v += bias[col];
                    if (flags & FLAG_RELU) v = fmaxf(v, 0.f);
                    C[(long)row * Nc + col] = v;
                }
            }
        }
    }
}

// ---------------- graph-stat histograms ----------------
__global__ void hist_nodes_kernel(const int* __restrict__ batch, int n, int* __restrict__ gn) {
    __shared__ int bins[G_DIM];
    int t = threadIdx.x;
    if (t < G_DIM) bins[t] = 0;
    __syncthreads();
    for (long i = (long)blockIdx.x * blockDim.x + t; i < n; i += (long)gridDim.x * blockDim.x)
        atomicAdd(&bins[batch[i]], 1);
    __syncthreads();
    if (t < G_DIM) atomicAdd(&gn[t], bins[t]);
}

__global__ void hist_edges_kernel(const int* __restrict__ ei, const int* __restrict__ batch,
                                  int E, int* __restrict__ ge) {
    __shared__ int bins[G_DIM];
    int t = threadIdx.x;
    if (t < G_DIM) bins[t] = 0;
    __syncthreads();
    for (long i = (long)blockIdx.x * blockDim.x + t; i < E; i += (long)gridDim.x * blockDim.x)
        atomicAdd(&bins[batch[ei[i]]], 1);
    __syncthreads();
    if (t < G_DIM) atomicAdd(&ge[t], bins[t]);
}

// ---------------- graph stats ----------------
__global__ void graph_stats_kernel(const int* __restrict__ gn, const int* __restrict__ ge,
                                   float* __restrict__ feats_norm, float* __restrict__ logn_norm) {
    int g = threadIdx.x;
    float nv = fmaxf((float)gn[g], 1.0f);
    float ev = (float)ge[g];
    float density = ev / fmaxf(nv * (nv - 1.0f), 1.0f);
    float logn = logf(nv);
    float mn = logn, mx = logn;
    for (int o = 32; o; o >>= 1) {
        mn = fminf(mn, __shfl_xor(mn, o));
        mx = fmaxf(mx, __shfl_xor(mx, o));
    }
    logn_norm[g] = (logn - mn) / (mx - mn + 1e-6f);
    float f[3] = {nv, ev, density};
    #pragma unroll
    for (int c = 0; c < 3; ++c) {
        float s = f[c];
        for (int o = 32; o; o >>= 1) s += __shfl_xor(s, o);
        float mean = s / 64.f;
        float d = f[c] - mean;
        float v = d * d;
        for (int o = 32; o; o >>= 1) v += __shfl_xor(v, o);
        float stdv = sqrtf(v / 64.f);
        feats_norm[g * 3 + c] = d / (stdv + 1e-6f);
    }
}

// ---------------- router epilogue (round-2 verified) ----------------
__global__ __launch_bounds__(256)
void router_epi_kernel(const float* __restrict__ t, const int* __restrict__ batch,
                       const float* __restrict__ feats_norm, const float* __restrict__ logn_norm,
                       const float* __restrict__ rW1, const float* __restrict__ rb1,
                       const float* __restrict__ lng, const float* __restrict__ lnb,
                       const float* __restrict__ rW2, const float* __restrict__ rb2,
                       const float* __restrict__ centers, float* __restrict__ w, int N) {
    int wave = threadIdx.x >> 6, lane = threadIdx.x & 63;
    int n = blockIdx.x * 4 + wave;
    if (n >= N) return;
    int g = batch[n];
    float sf0 = feats_norm[g * 3 + 0], sf1 = feats_norm[g * 3 + 1], sf2 = feats_norm[g * 3 + 2];
    float ln = logn_norm[g];
    float tv[4];
    #pragma unroll
    for (int q = 0; q < 4; ++q) {
        int j = lane + 64 * q;
        tv[q] = t[(long)n * H_DIM + j] + rb1[j]
              + sf0 * rW1[256 * H_DIM + j] + sf1 * rW1[257 * H_DIM + j] + sf2 * rW1[258 * H_DIM + j];
    }
    float s = tv[0] + tv[1] + tv[2] + tv[3];
    for (int o = 32; o; o >>= 1) s += __shfl_xor(s, o);
    float mean = s / 256.f;
    float vs = 0.f;
    #pragma unroll
    for (int q = 0; q < 4; ++q) { float d = tv[q] - mean; vs += d * d; }
    for (int o = 32; o; o >>= 1) vs += __shfl_xor(vs, o);
    float rstd = rsqrtf(vs / 256.f + 1e-5f);
    float le[NEXP] = {0.f, 0.f, 0.f, 0.f};
    #pragma unroll
    for (int q = 0; q < 4; ++q) {
        int j = lane + 64 * q;
        float y = (tv[q] - mean) * rstd * lng[j] + lnb[j];
        y = fmaxf(y, 0.f);
        #pragma unroll
        for (int e = 0; e < NEXP; ++e) le[e] += y * rW2[j * NEXP + e];
    }
    #pragma unroll
    for (int e = 0; e < NEXP; ++e)
        for (int o = 32; o; o >>= 1) le[e] += __shfl_xor(le[e], o);
    if (lane == 0) {
        float p[NEXP];
        float m = -1e30f;
        #pragma unroll
        for (int e = 0; e < NEXP; ++e) {
            float d = ln - centers[e];
            float lv = 0.7f * (le[e] + rb2[e]) + 0.3f * (-(d * d));
            p[e] = lv;
            m = fmaxf(m, lv);
        }
        float ssum = 0.f;
        #pragma unroll
        for (int e = 0; e < NEXP; ++e) { p[e] = expf(p[e] - m); ssum += p[e]; }
        #pragma unroll
        for (int e = 0; e < NEXP; ++e) p[e] /= ssum;
        int i1 = 0;
        for (int e = 1; e < NEXP; ++e) if (p[e] > p[i1]) i1 = e;
        int i2 = -1;
        for (int e = 0; e < NEXP; ++e) { if (e == i1) continue; if (i2 < 0 || p[e] > p[i2]) i2 = e; }
        float denom = p[i1] + p[i2] + 1e-8f;
        float out4[NEXP] = {0.f, 0.f, 0.f, 0.f};
        out4[i1] = p[i1] / denom;
        out4[i2] = p[i2] / denom;
        #pragma unroll
        for (int e = 0; e < NEXP; ++e) w[(long)n * NEXP + e] = out4[e];
    }
}

// ---------------- CSR build ----------------
__global__ void count_dst_kernel(const int* __restrict__ ei, int E, int* __restrict__ cnt) {
    int i = blockIdx.x * blockDim.x + threadIdx.x;
    if (i < E) atomicAdd(&cnt[ei[E + i]], 1);
}

__global__ __launch_bounds__(1024)
void scan_kernel(const int* __restrict__ cnt, int* __restrict__ row_ptr, int n) {
    __shared__ int buf[1024];
    __shared__ int carry_s;
    int tid = threadIdx.x;
    if (tid == 0) carry_s = 0;
    __syncthreads();
    for (int base = 0; base < n; base += 1024) {
        int v = (base + tid < n) ? cnt[base + tid] : 0;
        buf[tid] = v;
        __syncthreads();
        for (int off = 1; off < 1024; off <<= 1) {
            int tv = (tid >= off) ? buf[tid - off] : 0;
            __syncthreads();
            buf[tid] += tv;
            __syncthreads();
        }
        int carry = carry_s;
        if (base + tid < n) row_ptr[base + tid] = carry + buf[tid] - v;
        __syncthreads();
        if (tid == 1023) carry_s = carry + buf[1023];
        __syncthreads();
    }
    if (tid == 0) row_ptr[n] = carry_s;
}

__global__ void fill_csr_kernel(const int* __restrict__ ei, int E, const int* __restrict__ row_ptr,
                                int* __restrict__ fillc, int* __restrict__ srcs) {
    int i = blockIdx.x * blockDim.x + threadIdx.x;
    if (i < E) {
        int d = ei[E + i];
        int pos = row_ptr[d] + atomicAdd(&fillc[d], 1);
        srcs[pos] = ei[i];
    }
}

// ---------------- CSR gather (fp32, round-2 verified) ----------------
__global__ void agg_gather_kernel(const float* __restrict__ feat, float* __restrict__ out,
                                  const int* __restrict__ row_ptr, const int* __restrict__ srcs,
                                  int N) {
    int n = blockIdx.x;
    int j = threadIdx.x;
    float acc = 0.f;
    int p0 = row_ptr[n], p1 = row_ptr[n + 1];
    for (int p = p0; p < p1; ++p)
        acc += feat[(long)srcs[p] * H_DIM + j];
    out[(long)n * H_DIM + j] = acc;
}

// ---------------- per-expert final (fp32, round-2 verified) ----------------
__global__ __launch_bounds__(128)
void final_mix_e_kernel(const float* __restrict__ P, const float* __restrict__ R,
                        const float* __restrict__ b2e, const float* __restrict__ wts, int e,
                        const int* __restrict__ row_ptr, const int* __restrict__ srcs,
                        float* __restrict__ out, int N, int init) {
    int n = blockIdx.x, o = threadIdx.x;
    float we = wts[(long)n * NEXP + e];
    float prev = init ? 0.f : out[(long)n * O_DIM + o];
    if (we == 0.f) {
        if (init) out[(long)n * O_DIM + o] = 0.f;
        return;
    }
    float acc = R[(long)n * O_DIM + o] + b2e[o];
    int p0 = row_ptr[n], p1 = row_ptr[n + 1];
    for (int p = p0; p < p1; ++p)
        acc += P[(long)srcs[p] * O_DIM + o];
    out[(long)n * O_DIM + o] = prev + we * acc;
}

// ==================== host launcher ====================
extern "C" void kernel_launch(void* const* d_in, const int* in_sizes, int n_in,
                              void* d_out, int out_size, void* d_ws, size_t ws_size,
                              hipStream_t stream) {
    const float* x       = (const float*)d_in[0];
    const int*   ei      = (const int*)  d_in[1];
    const int*   batch   = (const int*)  d_in[2];
    const float* enc_W1  = (const float*)d_in[3];
    const float* enc_b1  = (const float*)d_in[4];
    const float* enc_W2  = (const float*)d_in[5];
    const float* enc_b2  = (const float*)d_in[6];
    const float* r_W1    = (const float*)d_in[7];
    const float* r_b1    = (const float*)d_in[8];
    const float* ln_g    = (const float*)d_in[9];
    const float* ln_b    = (const float*)d_in[10];
    const float* r_W2    = (const float*)d_in[11];
    const float* r_b2    = (const float*)d_in[12];
    const float* centers = (const float*)d_in[13];
    const float* W0_rel  = (const float*)d_in[14];
    const float* b0_rel  = (const float*)d_in[15];
    const float* W0_root = (const float*)d_in[16];
    const float* W1_rel  = (const float*)d_in[17];
    const float* b1_rel  = (const float*)d_in[18];
    const float* W1_root = (const float*)d_in[19];
    const float* W2_rel  = (const float*)d_in[20];
    const float* b2_rel  = (const float*)d_in[21];
    const float* W2_root = (const float*)d_in[22];

    const int N = in_sizes[2];
    const int E = in_sizes[1] / 2;
    const int F = in_sizes[0] / N;

    // ---- workspace layout (256B-aligned slabs); peak ~215 MB ----
    char* ws = (char*)d_ws;
    size_t off = 0;
    auto alloc = [&](size_t bytes) -> void* {
        void* p = ws + off;
        off += (bytes + 255) & ~(size_t)255;
        return p;
    };
    int* cnt      = (int*)alloc((size_t)N * 4);
    int* fillc    = (int*)alloc((size_t)N * 4);
    int* gn       = (int*)alloc((size_t)G_DIM * 4);
    int* ge       = (int*)alloc((size_t)G_DIM * 4);
    size_t zero_bytes = off;
    int* row_ptr  = (int*)alloc((size_t)(N + 1) * 4);
    int* srcs     = (int*)alloc((size_t)E * 4);
    float* feats_norm = (float*)alloc((size_t)G_DIM * 3 * 4);
    float* logn_norm  = (float*)alloc((size_t)G_DIM * 4);
    float* wts    = (float*)alloc((size_t)N * NEXP * 4);
    // transposed bf16 hi/lo expert weights
    const long sWH = (long)H_DIM * H_DIM;
    const long sWO = (long)H_DIM * O_DIM;
    ushort_t* w0rel_h  = (ushort_t*)alloc((size_t)NEXP * sWH * 2);
    ushort_t* w0rel_l  = (ushort_t*)alloc((size_t)NEXP * sWH * 2);
    ushort_t* w0root_h = (ushort_t*)alloc((size_t)NEXP * sWH * 2);
    ushort_t* w0root_l = (ushort_t*)alloc((size_t)NEXP * sWH * 2);
    ushort_t* w1rel_h  = (ushort_t*)alloc((size_t)NEXP * sWH * 2);
    ushort_t* w1rel_l  = (ushort_t*)alloc((size_t)NEXP * sWH * 2);
    ushort_t* w1root_h = (ushort_t*)alloc((size_t)NEXP * sWH * 2);
    ushort_t* w1root_l = (ushort_t*)alloc((size_t)NEXP * sWH * 2);
    ushort_t* w2rel_h  = (ushort_t*)alloc((size_t)NEXP * sWO * 2);
    ushort_t* w2rel_l  = (ushort_t*)alloc((size_t)NEXP * sWO * 2);
    ushort_t* w2root_h = (ushort_t*)alloc((size_t)NEXP * sWO * 2);
    ushort_t* w2root_l = (ushort_t*)alloc((size_t)NEXP * sWO * 2);
    // fp32 activation slabs (each N*256*4 B = 51.2 MB)
    float* h    = (float*)alloc((size_t)N * H_DIM * 4);
    float* T    = (float*)alloc((size_t)N * H_DIM * 4);
    float* buf0 = (float*)alloc((size_t)N * H_DIM * 4);
    float* U    = (float*)alloc((size_t)N * H_DIM * 4);
    (void)ws_size; (void)out_size; (void)n_in;

    float* u    = T;                       // dead before T's first expert use
    float* tf32 = buf0;                    // router t overlays buf0 (dead then)
    float* P    = buf0;                    // buf0 dead after layer-1 root GEMM
    float* R    = buf0 + (size_t)N * O_DIM;
    float* out  = (float*)d_out;

    dim3 blk256(256);
    dim3 gRH((N + 63) / 64, H_DIM / 64, 1);       // fp32 SGEMM grid (router path)
    dim3 gH((N + 127) / 128, H_DIM / 128, 1);     // MFMA grid, Nc=256
    dim3 gO((N + 127) / 128, O_DIM / 128, 1);     // MFMA grid, Nc=128

    // 0) zero counters
    {
        long nz = (long)(zero_bytes / 4);
        zero_i_kernel<<<dim3((nz + 255) / 256), blk256, 0, stream>>>((int*)ws, nz);
    }
    // 0b) expert-weight transpose + hi/lo split
    wsplit_kernel<<<dim3((int)((sWH + 255) / 256), NEXP), blk256, 0, stream>>>(W0_rel,  w0rel_h,  w0rel_l,  H_DIM, H_DIM);
    wsplit_kernel<<<dim3((int)((sWH + 255) / 256), NEXP), blk256, 0, stream>>>(W0_root, w0root_h, w0root_l, H_DIM, H_DIM);
    wsplit_kernel<<<dim3((int)((sWH + 255) / 256), NEXP), blk256, 0, stream>>>(W1_rel,  w1rel_h,  w1rel_l,  H_DIM, H_DIM);
    wsplit_kernel<<<dim3((int)((sWH + 255) / 256), NEXP), blk256, 0, stream>>>(W1_root, w1root_h, w1root_l, H_DIM, H_DIM);
    wsplit_kernel<<<dim3((int)((sWO + 255) / 256), NEXP), blk256, 0, stream>>>(W2_rel,  w2rel_h,  w2rel_l,  H_DIM, O_DIM);
    wsplit_kernel<<<dim3((int)((sWO + 255) / 256), NEXP), blk256, 0, stream>>>(W2_root, w2root_h, w2root_l, H_DIM, O_DIM);
    // 1) encoder stage 1 -> u (fp32, in T)
    encoder1_kernel<<<dim3(N), blk256, 0, stream>>>(x, enc_W1, enc_b1, u, N, F);
    // 2) h = u @ enc_W2 + enc_b2  (fp32 SGEMM — router path exactness)
    gemm256_kernel<<<gRH, blk256, 0, stream>>>(u, enc_W2, enc_b2, h, N, H_DIM, 0);
    // 3-5) graph stats
    hist_nodes_kernel<<<dim3(256), blk256, 0, stream>>>(batch, N, gn);
    hist_edges_kernel<<<dim3(512), blk256, 0, stream>>>(ei, batch, E, ge);
    graph_stats_kernel<<<dim3(1), dim3(64), 0, stream>>>(gn, ge, feats_norm, logn_norm);
    // 6) t = h @ r_W1[0:256,:]  (fp32 SGEMM)
    gemm256_kernel<<<gRH, blk256, 0, stream>>>(h, r_W1, nullptr, tf32, N, H_DIM, 0);
    // 7) router epilogue -> wts
    router_epi_kernel<<<dim3((N + 3) / 4), blk256, 0, stream>>>(
        tf32, batch, feats_norm, logn_norm, r_W1, r_b1, ln_g, ln_b, r_W2, r_b2, centers, wts, N);
    // 8-10) CSR build
    count_dst_kernel<<<dim3((E + 255) / 256), blk256, 0, stream>>>(ei, E, cnt);
    scan_kernel<<<dim3(1), dim3(1024), 0, stream>>>(cnt, row_ptr, N);
    fill_csr_kernel<<<dim3((E + 255) / 256), blk256, 0, stream>>>(ei, E, row_ptr, fillc, srcs);

    // ---- per-expert pipeline (Agg(X)@W == Agg(X@W)); split-bf16 MFMA GEMMs ----
    for (int e = 0; e < NEXP; ++e) {
        // T = h @ W0_rel[e]
        gemm_mfma3_kernel<<<gH, blk256, 0, stream>>>(h, w0rel_h + e * sWH, w0rel_l + e * sWH,
                                                     nullptr, nullptr, T, N, H_DIM, 0);
        // buf0 = Agg(T)
        agg_gather_kernel<<<dim3(N), blk256, 0, stream>>>(T, buf0, row_ptr, srcs, N);
        // buf0 = relu(buf0 + h @ W0_root[e] + b0[e])
        gemm_mfma3_kernel<<<gH, blk256, 0, stream>>>(h, w0root_h + e * sWH, w0root_l + e * sWH,
                                                     buf0, b0_rel + e * H_DIM, buf0, N, H_DIM,
                                                     FLAG_BETA | FLAG_RELU);
        // T = buf0 @ W1_rel[e]
        gemm_mfma3_kernel<<<gH, blk256, 0, stream>>>(buf0, w1rel_h + e * sWH, w1rel_l + e * sWH,
                                                     nullptr, nullptr, T, N, H_DIM, 0);
        // U = Agg(T)
        agg_gather_kernel<<<dim3(N), blk256, 0, stream>>>(T, U, row_ptr, srcs, N);
        // U = relu(U + buf0 @ W1_root[e] + b1[e])
        gemm_mfma3_kernel<<<gH, blk256, 0, stream>>>(buf0, w1root_h + e * sWH, w1root_l + e * sWH,
                                                     U, b1_rel + e * H_DIM, U, N, H_DIM,
                                                     FLAG_BETA | FLAG_RELU);
        // P = U @ W2_rel[e]; R = U @ W2_root[e]  (into dead buf0)
        gemm_mfma3_kernel<<<gO, blk256, 0, stream>>>(U, w2rel_h + e * sWO, w2rel_l + e * sWO,
                                                     nullptr, nullptr, P, N, O_DIM, 0);
        gemm_mfma3_kernel<<<gO, blk256, 0, stream>>>(U, w2root_h + e * sWO, w2root_l + e * sWO,
                                                     nullptr, nullptr, R, N, O_DIM, 0);
        // out (+)= w[:,e] * (Agg(P) + R + b2[e])
        final_mix_e_kernel<<<dim3(N), dim3(128), 0, stream>>>(
            P, R, b2_rel + e * O_DIM, wts, e, row_ptr, srcs, out, N, e == 0 ? 1 : 0);
    }
}

// Round 5
// 2303.980 us; speedup vs baseline: 1.7941x; 1.4227x over previous
//
#include <hip/hip_runtime.h>
#include <hip/hip_bf16.h>

// ---------------- problem constants ----------------
#define H_DIM 256
#define O_DIM 128
#define NEXP 4
#define G_DIM 64

typedef unsigned short ushort_t;
typedef unsigned int uint_t;
typedef __attribute__((ext_vector_type(8))) short short8;
typedef __attribute__((ext_vector_type(4))) float floatx4;

// ---------------- bf16 helpers (RNE) ----------------
__device__ __forceinline__ float bf2f(ushort_t u) {
    union { uint_t i; float f; } c; c.i = ((uint_t)u) << 16; return c.f;
}
__device__ __forceinline__ ushort_t f2bf(float f) {
    union { float f; uint_t i; } c; c.f = f;
    uint_t x = c.i;
    uint_t r = (x + 0x7fffu + ((x >> 16) & 1u)) >> 16;
    return (ushort_t)r;
}

// ---------------- async global->LDS 16B ----------------
__device__ __forceinline__ void load16_lds(const void* g, void* l) {
    __builtin_amdgcn_global_load_lds(
        (const __attribute__((address_space(1))) unsigned int*)g,
        (__attribute__((address_space(3))) unsigned int*)l, 16, 0, 0);
}

// ---------------- utility: zero ints ----------------
__global__ void zero_i_kernel(int* __restrict__ p, long n) {
    long i = (long)blockIdx.x * blockDim.x + threadIdx.x;
    if (i < n) p[i] = 0;
}

// ---------------- fused weight prep ----------------
// vertical k-concat: Wt[z][n][k], k<256 from Wa[z][k][n], k>=256 from Wb[z][k-256][n]; Nc=256, K=512
__global__ void wsplit2_kernel(const float* __restrict__ Wa, const float* __restrict__ Wb,
                               ushort_t* __restrict__ Wh, ushort_t* __restrict__ Wl) {
    int z = blockIdx.y;
    int i = blockIdx.x * 256 + threadIdx.x;        // 256n * 512k
    if (i >= 131072) return;
    int nn = i >> 9, kk = i & 511;
    float v = (kk < 256) ? Wa[(long)z * 65536 + kk * 256 + nn]
                         : Wb[(long)z * 65536 + (kk - 256) * 256 + nn];
    ushort_t hi = f2bf(v);
    long o = (long)z * 131072 + i;
    Wh[o] = hi; Wl[o] = f2bf(v - bf2f(hi));
}

// horizontal n-concat: Wt[z][n][k], n<128 from W2_rel[z][k][n], else W2_root[z][k][n-128]; Nc=256, K=256
__global__ void wsplitcat_kernel(const float* __restrict__ Wa, const float* __restrict__ Wb,
                                 ushort_t* __restrict__ Wh, ushort_t* __restrict__ Wl) {
    int z = blockIdx.y;
    int i = blockIdx.x * 256 + threadIdx.x;        // 256n * 256k
    if (i >= 65536) return;
    int nn = i >> 8, kk = i & 255;
    float v = (nn < 128) ? Wa[(long)z * 32768 + kk * 128 + nn]
                         : Wb[(long)z * 32768 + kk * 128 + (nn - 128)];
    ushort_t hi = f2bf(v);
    long o = (long)z * 65536 + i;
    Wh[o] = hi; Wl[o] = f2bf(v - bf2f(hi));
}

// ---------------- encoder stage 1 (fp32, verified) ----------------
__global__ void encoder1_kernel(const float* __restrict__ x, const float* __restrict__ W1,
                                const float* __restrict__ b1, float* __restrict__ u,
                                int N, int F) {
    int n = blockIdx.x;
    int j = threadIdx.x;
    float acc = b1[j];
    #pragma unroll
    for (int c = 0; c < 6; ++c)
        acc += x[(long)n * F + 4 + c] * W1[c * H_DIM + j];
    u[(long)n * H_DIM + j] = fmaxf(acc, 0.f);
}

// ---------------- fp32 vector SGEMM (router path only, round-2 verified) ----------------
__global__ __launch_bounds__(256)
void gemm256_kernel(const float* __restrict__ A, const float* __restrict__ W,
                    const float* __restrict__ bias, float* __restrict__ C,
                    int M, int Nc) {
    const int K = 256;
    __shared__ float As[16][68];
    __shared__ float Ws[16][68];
    int tid = threadIdx.x;
    int tx = tid & 15, ty = tid >> 4;
    int row0 = blockIdx.x * 64;
    int col0 = blockIdx.y * 64;
    float acc[4][4] = {};
    int lrow = tid >> 2, kq = tid & 3;
    int wk = tid >> 4, wc = (tid & 15) * 4;
    for (int k0 = 0; k0 < K; k0 += 16) {
        float4 av = make_float4(0.f, 0.f, 0.f, 0.f);
        int arow = row0 + lrow;
        if (arow < M) av = *(const float4*)(A + (long)arow * K + k0 + kq * 4);
        As[kq * 4 + 0][lrow] = av.x;
        As[kq * 4 + 1][lrow] = av.y;
        As[kq * 4 + 2][lrow] = av.z;
        As[kq * 4 + 3][lrow] = av.w;
        float4 wv = *(const float4*)(W + (long)(k0 + wk) * Nc + col0 + wc);
        *(float4*)&Ws[wk][wc] = wv;
        __syncthreads();
        #pragma unroll
        for (int kk = 0; kk < 16; ++kk) {
            float a[4], b[4];
            #pragma unroll
            for (int i = 0; i < 4; ++i) a[i] = As[kk][ty * 4 + i];
            #pragma unroll
            for (int j = 0; j < 4; ++j) b[j] = Ws[kk][tx * 4 + j];
            #pragma unroll
            for (int i = 0; i < 4; ++i)
                #pragma unroll
                for (int j = 0; j < 4; ++j) acc[i][j] += a[i] * b[j];
        }
        __syncthreads();
    }
    #pragma unroll
    for (int i = 0; i < 4; ++i) {
        int r = row0 + ty * 4 + i;
        if (r >= M) break;
        #pragma unroll
        for (int j = 0; j < 4; ++j) {
            int c = col0 + tx * 4 + j;
            float v = acc[i][j];
            if (bias) v += bias[c];
            C[(long)r * Nc + c] = v;
        }
    }
}

// ---------------- MFMA GEMM, templated A halves (fp32 split-3 or bf16 2-product) ----------------
// C = [relu]( sum_halves A_half @ B^T + [bias] ); B fused (Nc, Kb) bf16 hi/lo, Kb = NH*256.
// A halves each (M,256). 128x128 tile, BK=32, 4 waves 2x2, 4x4 frags of 16x16x32.
template<int NH, bool A1BF, bool A2BF>
__global__ __launch_bounds__(256)
void gemm_moe_kernel(const void* __restrict__ A1v, const void* __restrict__ A2v,
                     const ushort_t* __restrict__ Bh, const ushort_t* __restrict__ Bl,
                     const float* __restrict__ bias,
                     float* __restrict__ Cf, ushort_t* __restrict__ Cbf,
                     int M, int Nc, int Kb, int relu) {
    __shared__ alignas(16) unsigned char AslRaw[128 * 32 * 4];   // 16 KB (fp32) / 8 KB (bf16)
    __shared__ alignas(16) ushort_t Bhs[128 * 32];
    __shared__ alignas(16) ushort_t Bls[128 * 32];
    float* Aslf = (float*)AslRaw;
    ushort_t* Aslu = (ushort_t*)AslRaw;

    const int tid = threadIdx.x, wave = tid >> 6, lane = tid & 63;
    const int row0 = blockIdx.x * 128, col0 = blockIdx.y * 128;
    const int wr = (wave >> 1) * 64, wcx = (wave & 1) * 64;
    floatx4 acc[4][4] = {};

    // fp32 staging map: 8 lanes/row, 4 rounds
    const int asr = lane >> 3, asc = (lane & 7) * 4;
    long aoff_f[4];
    #pragma unroll
    for (int q = 0; q < 4; ++q) {
        int ar = row0 + wave * 32 + q * 8 + asr;
        ar = ar < M ? ar : M - 1;
        aoff_f[q] = (long)ar * 256 + asc;
    }
    // bf16 staging map: 4 lanes/row, 2 rounds
    const int bsr = lane >> 2, bsc = (lane & 3) * 8;
    long aoff_b[2];
    #pragma unroll
    for (int q = 0; q < 2; ++q) {
        int ar = row0 + wave * 32 + q * 16 + bsr;
        ar = ar < M ? ar : M - 1;
        aoff_b[q] = (long)ar * 256 + bsc;
    }
    // B staging
    const long brow = (long)(col0 + wave * 32 + bsr) * Kb + bsc;
    const ushort_t* Bhg0 = Bh + brow;
    const ushort_t* Bhg1 = Bh + brow + (long)16 * Kb;
    const ushort_t* Blg0 = Bl + brow;
    const ushort_t* Blg1 = Bl + brow + (long)16 * Kb;
    ushort_t* Bhl0 = &Bhs[(wave * 32) * 32];
    ushort_t* Bhl1 = &Bhs[(wave * 32 + 16) * 32];
    ushort_t* Bll0 = &Bls[(wave * 32) * 32];
    ushort_t* Bll1 = &Bls[(wave * 32 + 16) * 32];

    const int fm = lane & 15, fq = lane >> 4;

    #pragma unroll
    for (int half = 0; half < NH; ++half) {
        const bool ABF = (half == 0) ? A1BF : A2BF;
        const char* Abase = (const char*)(half == 0 ? A1v : A2v);
        for (int k0 = 0; k0 < 256; k0 += 32) {
            const int kk = half * 256 + k0;
            if (ABF) {
                const ushort_t* Au = (const ushort_t*)Abase;
                load16_lds(Au + aoff_b[0] + k0, &Aslu[(wave * 32) * 32]);
                load16_lds(Au + aoff_b[1] + k0, &Aslu[(wave * 32 + 16) * 32]);
            } else {
                const float* Af = (const float*)Abase;
                #pragma unroll
                for (int q = 0; q < 4; ++q)
                    load16_lds(Af + aoff_f[q] + k0, &Aslf[(wave * 32 + q * 8) * 32]);
            }
            load16_lds(Bhg0 + kk, Bhl0);
            load16_lds(Bhg1 + kk, Bhl1);
            load16_lds(Blg0 + kk, Bll0);
            load16_lds(Blg1 + kk, Bll1);
            __syncthreads();

            short8 bh[4], bl[4];
            #pragma unroll
            for (int j = 0; j < 4; ++j) {
                bh[j] = *(const short8*)&Bhs[(wcx + j * 16 + fm) * 32 + fq * 8];
                bl[j] = *(const short8*)&Bls[(wcx + j * 16 + fm) * 32 + fq * 8];
            }
            if (ABF) {
                short8 a[4];
                #pragma unroll
                for (int i = 0; i < 4; ++i)
                    a[i] = *(const short8*)&Aslu[(wr + i * 16 + fm) * 32 + fq * 8];
                #pragma unroll
                for (int i = 0; i < 4; ++i)
                    #pragma unroll
                    for (int j = 0; j < 4; ++j) {
                        acc[i][j] = __builtin_amdgcn_mfma_f32_16x16x32_bf16(a[i], bl[j], acc[i][j], 0, 0, 0);
                        acc[i][j] = __builtin_amdgcn_mfma_f32_16x16x32_bf16(a[i], bh[j], acc[i][j], 0, 0, 0);
                    }
            } else {
                short8 ah[4], al[4];
                #pragma unroll
                for (int i = 0; i < 4; ++i) {
                    const float* ap = &Aslf[(wr + i * 16 + fm) * 32 + fq * 8];
                    float4 v0 = *(const float4*)ap;
                    float4 v1 = *(const float4*)(ap + 4);
                    float av[8] = {v0.x, v0.y, v0.z, v0.w, v1.x, v1.y, v1.z, v1.w};
                    #pragma unroll
                    for (int j = 0; j < 8; ++j) {
                        ushort_t hi = f2bf(av[j]);
                        ah[i][j] = (short)hi;
                        al[i][j] = (short)f2bf(av[j] - bf2f(hi));
                    }
                }
                #pragma unroll
                for (int i = 0; i < 4; ++i)
                    #pragma unroll
                    for (int j = 0; j < 4; ++j) {
                        acc[i][j] = __builtin_amdgcn_mfma_f32_16x16x32_bf16(al[i], bh[j], acc[i][j], 0, 0, 0);
                        acc[i][j] = __builtin_amdgcn_mfma_f32_16x16x32_bf16(ah[i], bl[j], acc[i][j], 0, 0, 0);
                        acc[i][j] = __builtin_amdgcn_mfma_f32_16x16x32_bf16(ah[i], bh[j], acc[i][j], 0, 0, 0);
                    }
            }
            __syncthreads();
        }
    }

    // epilogue: C/D layout col=lane&15, row=(lane>>4)*4+reg  [verified m89]
    #pragma unroll
    for (int i = 0; i < 4; ++i) {
        #pragma unroll
        for (int j = 0; j < 4; ++j) {
            int col = col0 + wcx + j * 16 + fm;
            int rowb = row0 + wr + i * 16 + fq * 4;
            #pragma unroll
            for (int r = 0; r < 4; ++r) {
                int row = rowb + r;
                if (row < M) {
                    float v = acc[i][j][r];
                    if (bias) v += bias[col];
                    if (relu) v = fmaxf(v, 0.f);
                    if (Cf)  Cf[(long)row * Nc + col] = v;
                    if (Cbf) Cbf[(long)row * Nc + col] = f2bf(v);
                }
            }
        }
    }
}

// ---------------- graph-stat histograms ----------------
__global__ void hist_nodes_kernel(const int* __restrict__ batch, int n, int* __restrict__ gn) {
    __shared__ int bins[G_DIM];
    int t = threadIdx.x;
    if (t < G_DIM) bins[t] = 0;
    __syncthreads();
    for (long i = (long)blockIdx.x * blockDim.x + t; i < n; i += (long)gridDim.x * blockDim.x)
        atomicAdd(&bins[batch[i]], 1);
    __syncthreads();
    if (t < G_DIM) atomicAdd(&gn[t], bins[t]);
}

__global__ void hist_edges_kernel(const int* __restrict__ ei, const int* __restrict__ batch,
                                  int E, int* __restrict__ ge) {
    __shared__ int bins[G_DIM];
    int t = threadIdx.x;
    if (t < G_DIM) bins[t] = 0;
    __syncthreads();
    for (long i = (long)blockIdx.x * blockDim.x + t; i < E; i += (long)gridDim.x * blockDim.x)
        atomicAdd(&bins[batch[ei[i]]], 1);
    __syncthreads();
    if (t < G_DIM) atomicAdd(&ge[t], bins[t]);
}

// ---------------- graph stats ----------------
__global__ void graph_stats_kernel(const int* __restrict__ gn, const int* __restrict__ ge,
                                   float* __restrict__ feats_norm, float* __restrict__ logn_norm) {
    int g = threadIdx.x;
    float nv = fmaxf((float)gn[g], 1.0f);
    float ev = (float)ge[g];
    float density = ev / fmaxf(nv * (nv - 1.0f), 1.0f);
    float logn = logf(nv);
    float mn = logn, mx = logn;
    for (int o = 32; o; o >>= 1) {
        mn = fminf(mn, __shfl_xor(mn, o));
        mx = fmaxf(mx, __shfl_xor(mx, o));
    }
    logn_norm[g] = (logn - mn) / (mx - mn + 1e-6f);
    float f[3] = {nv, ev, density};
    #pragma unroll
    for (int c = 0; c < 3; ++c) {
        float s = f[c];
        for (int o = 32; o; o >>= 1) s += __shfl_xor(s, o);
        float mean = s / 64.f;
        float d = f[c] - mean;
        float v = d * d;
        for (int o = 32; o; o >>= 1) v += __shfl_xor(v, o);
        float stdv = sqrtf(v / 64.f);
        feats_norm[g * 3 + c] = d / (stdv + 1e-6f);
    }
}

// ---------------- router epilogue (verified) ----------------
__global__ __launch_bounds__(256)
void router_epi_kernel(const float* __restrict__ t, const int* __restrict__ batch,
                       const float* __restrict__ feats_norm, const float* __restrict__ logn_norm,
                       const float* __restrict__ rW1, const float* __restrict__ rb1,
                       const float* __restrict__ lng, const float* __restrict__ lnb,
                       const float* __restrict__ rW2, const float* __restrict__ rb2,
                       const float* __restrict__ centers, float* __restrict__ w, int N) {
    int wave = threadIdx.x >> 6, lane = threadIdx.x & 63;
    int n = blockIdx.x * 4 + wave;
    if (n >= N) return;
    int g = batch[n];
    float sf0 = feats_norm[g * 3 + 0], sf1 = feats_norm[g * 3 + 1], sf2 = feats_norm[g * 3 + 2];
    float ln = logn_norm[g];
    float tv[4];
    #pragma unroll
    for (int q = 0; q < 4; ++q) {
        int j = lane + 64 * q;
        tv[q] = t[(long)n * H_DIM + j] + rb1[j]
              + sf0 * rW1[256 * H_DIM + j] + sf1 * rW1[257 * H_DIM + j] + sf2 * rW1[258 * H_DIM + j];
    }
    float s = tv[0] + tv[1] + tv[2] + tv[3];
    for (int o = 32; o; o >>= 1) s += __shfl_xor(s, o);
    float mean = s / 256.f;
    float vs = 0.f;
    #pragma unroll
    for (int q = 0; q < 4; ++q) { float d = tv[q] - mean; vs += d * d; }
    for (int o = 32; o; o >>= 1) vs += __shfl_xor(vs, o);
    float rstd = rsqrtf(vs / 256.f + 1e-5f);
    float le[NEXP] = {0.f, 0.f, 0.f, 0.f};
    #pragma unroll
    for (int q = 0; q < 4; ++q) {
        int j = lane + 64 * q;
        float y = (tv[q] - mean) * rstd * lng[j] + lnb[j];
        y = fmaxf(y, 0.f);
        #pragma unroll
        for (int e = 0; e < NEXP; ++e) le[e] += y * rW2[j * NEXP + e];
    }
    #pragma unroll
    for (int e = 0; e < NEXP; ++e)
        for (int o = 32; o; o >>= 1) le[e] += __shfl_xor(le[e], o);
    if (lane == 0) {
        float p[NEXP];
        float m = -1e30f;
        #pragma unroll
        for (int e = 0; e < NEXP; ++e) {
            float d = ln - centers[e];
            float lv = 0.7f * (le[e] + rb2[e]) + 0.3f * (-(d * d));
            p[e] = lv;
            m = fmaxf(m, lv);
        }
        float ssum = 0.f;
        #pragma unroll
        for (int e = 0; e < NEXP; ++e) { p[e] = expf(p[e] - m); ssum += p[e]; }
        #pragma unroll
        for (int e = 0; e < NEXP; ++e) p[e] /= ssum;
        int i1 = 0;
        for (int e = 1; e < NEXP; ++e) if (p[e] > p[i1]) i1 = e;
        int i2 = -1;
        for (int e = 0; e < NEXP; ++e) { if (e == i1) continue; if (i2 < 0 || p[e] > p[i2]) i2 = e; }
        float denom = p[i1] + p[i2] + 1e-8f;
        float out4[NEXP] = {0.f, 0.f, 0.f, 0.f};
        out4[i1] = p[i1] / denom;
        out4[i2] = p[i2] / denom;
        #pragma unroll
        for (int e = 0; e < NEXP; ++e) w[(long)n * NEXP + e] = out4[e];
    }
}

// ---------------- CSR build ----------------
__global__ void count_dst_kernel(const int* __restrict__ ei, int E, int* __restrict__ cnt) {
    int i = blockIdx.x * blockDim.x + threadIdx.x;
    if (i < E) atomicAdd(&cnt[ei[E + i]], 1);
}

__global__ __launch_bounds__(1024)
void scan_kernel(const int* __restrict__ cnt, int* __restrict__ row_ptr, int n) {
    __shared__ int buf[1024];
    __shared__ int carry_s;
    int tid = threadIdx.x;
    if (tid == 0) carry_s = 0;
    __syncthreads();
    for (int base = 0; base < n; base += 1024) {
        int v = (base + tid < n) ? cnt[base + tid] : 0;
        buf[tid] = v;
        __syncthreads();
        for (int off = 1; off < 1024; off <<= 1) {
            int tv = (tid >= off) ? buf[tid - off] : 0;
            __syncthreads();
            buf[tid] += tv;
            __syncthreads();
        }
        int carry = carry_s;
        if (base + tid < n) row_ptr[base + tid] = carry + buf[tid] - v;
        __syncthreads();
        if (tid == 1023) carry_s = carry + buf[1023];
        __syncthreads();
    }
    if (tid == 0) row_ptr[n] = carry_s;
}

__global__ void fill_csr_kernel(const int* __restrict__ ei, int E, const int* __restrict__ row_ptr,
                                int* __restrict__ fillc, int* __restrict__ srcs) {
    int i = blockIdx.x * blockDim.x + threadIdx.x;
    if (i < E) {
        int d = ei[E + i];
        int pos = row_ptr[d] + atomicAdd(&fillc[d], 1);
        srcs[pos] = ei[i];
    }
}

// ---------------- gathers (wave per node, width 256) ----------------
// fp32 in -> bf16 out (agg_h)
__global__ __launch_bounds__(256)
void agg_f2b_kernel(const float* __restrict__ feat, ushort_t* __restrict__ out,
                    const int* __restrict__ rp, const int* __restrict__ srcs, int N) {
    int wave = threadIdx.x >> 6, lane = threadIdx.x & 63;
    int n = blockIdx.x * 4 + wave;
    if (n >= N) return;
    float a0 = 0.f, a1 = 0.f, a2 = 0.f, a3 = 0.f;
    int p0 = rp[n], p1 = rp[n + 1];
    const float* base = feat + lane * 4;
    for (int p = p0; p < p1; ++p) {
        long s = srcs[p];
        float4 v = *(const float4*)(base + s * H_DIM);
        a0 += v.x; a1 += v.y; a2 += v.z; a3 += v.w;
    }
    uint2 o;
    o.x = (uint_t)f2bf(a0) | ((uint_t)f2bf(a1) << 16);
    o.y = (uint_t)f2bf(a2) | ((uint_t)f2bf(a3) << 16);
    *(uint2*)(out + (long)n * H_DIM + lane * 4) = o;
}

// bf16 in -> fp32 out (Agg(hE0))
__global__ __launch_bounds__(256)
void agg_b2f_kernel(const ushort_t* __restrict__ feat, float* __restrict__ out,
                    const int* __restrict__ rp, const int* __restrict__ srcs, int N) {
    int wave = threadIdx.x >> 6, lane = threadIdx.x & 63;
    int n = blockIdx.x * 4 + wave;
    if (n >= N) return;
    float a0 = 0.f, a1 = 0.f, a2 = 0.f, a3 = 0.f;
    int p0 = rp[n], p1 = rp[n + 1];
    const ushort_t* base = feat + lane * 4;
    for (int p = p0; p < p1; ++p) {
        long s = srcs[p];
        uint2 v = *(const uint2*)(base + s * H_DIM);
        a0 += bf2f((ushort_t)(v.x & 0xffff));
        a1 += bf2f((ushort_t)(v.x >> 16));
        a2 += bf2f((ushort_t)(v.y & 0xffff));
        a3 += bf2f((ushort_t)(v.y >> 16));
    }
    float4 o = make_float4(a0, a1, a2, a3);
    *(float4*)(out + (long)n * H_DIM + lane * 4) = o;
}

// ---------------- per-expert final: out (+)= w[n,e]*(Agg(P)[n,:] + R[n,:] + b2e) ----------------
// PR: (N,256) bf16, cols 0..127 = P, 128..255 = R
__global__ __launch_bounds__(256)
void final_mix_kernel(const ushort_t* __restrict__ PR, const float* __restrict__ b2e,
                      const float* __restrict__ wts, int e,
                      const int* __restrict__ rp, const int* __restrict__ srcs,
                      float* __restrict__ out, int N, int init) {
    int wave = threadIdx.x >> 6, lane = threadIdx.x & 63;
    int n = blockIdx.x * 4 + wave;
    if (n >= N) return;
    int c0 = lane * 2;
    float we = wts[(long)n * NEXP + e];
    long obase = (long)n * O_DIM + c0;
    float o0 = init ? 0.f : out[obase];
    float o1 = init ? 0.f : out[obase + 1];
    if (we != 0.f) {
        uint_t rv = *(const uint_t*)(PR + (long)n * 256 + 128 + c0);
        float a0 = bf2f((ushort_t)(rv & 0xffff)) + b2e[c0];
        float a1 = bf2f((ushort_t)(rv >> 16)) + b2e[c0 + 1];
        int p0 = rp[n], p1 = rp[n + 1];
        const ushort_t* base = PR + c0;
        for (int p = p0; p < p1; ++p) {
            long s = srcs[p];
            uint_t pv = *(const uint_t*)(base + s * 256);
            a0 += bf2f((ushort_t)(pv & 0xffff));
            a1 += bf2f((ushort_t)(pv >> 16));
        }
        o0 += we * a0;
        o1 += we * a1;
    }
    out[obase] = o0;
    out[obase + 1] = o1;
}

// ==================== host launcher ====================
extern "C" void kernel_launch(void* const* d_in, const int* in_sizes, int n_in,
                              void* d_out, int out_size, void* d_ws, size_t ws_size,
                              hipStream_t stream) {
    const float* x       = (const float*)d_in[0];
    const int*   ei      = (const int*)  d_in[1];
    const int*   batch   = (const int*)  d_in[2];
    const float* enc_W1  = (const float*)d_in[3];
    const float* enc_b1  = (const float*)d_in[4];
    const float* enc_W2  = (const float*)d_in[5];
    const float* enc_b2  = (const float*)d_in[6];
    const float* r_W1    = (const float*)d_in[7];
    const float* r_b1    = (const float*)d_in[8];
    const float* ln_g    = (const float*)d_in[9];
    const float* ln_b    = (const float*)d_in[10];
    const float* r_W2    = (const float*)d_in[11];
    const float* r_b2    = (const float*)d_in[12];
    const float* centers = (const float*)d_in[13];
    const float* W0_rel  = (const float*)d_in[14];
    const float* b0_rel  = (const float*)d_in[15];
    const float* W0_root = (const float*)d_in[16];
    const float* W1_rel  = (const float*)d_in[17];
    const float* b1_rel  = (const float*)d_in[18];
    const float* W1_root = (const float*)d_in[19];
    const float* W2_rel  = (const float*)d_in[20];
    const float* b2_rel  = (const float*)d_in[21];
    const float* W2_root = (const float*)d_in[22];

    const int N = in_sizes[2];
    const int E = in_sizes[1] / 2;
    const int F = in_sizes[0] / N;

    // ---- workspace layout (256B-aligned slabs); peak ~241 MB ----
    char* ws = (char*)d_ws;
    size_t off = 0;
    auto alloc = [&](size_t bytes) -> void* {
        void* p = ws + off;
        off += (bytes + 255) & ~(size_t)255;
        return p;
    };
    int* cnt      = (int*)alloc((size_t)N * 4);
    int* fillc    = (int*)alloc((size_t)N * 4);
    int* gn       = (int*)alloc((size_t)G_DIM * 4);
    int* ge       = (int*)alloc((size_t)G_DIM * 4);
    size_t zero_bytes = off;
    int* row_ptr  = (int*)alloc((size_t)(N + 1) * 4);
    int* srcs     = (int*)alloc((size_t)E * 4);
    float* feats_norm = (float*)alloc((size_t)G_DIM * 3 * 4);
    float* logn_norm  = (float*)alloc((size_t)G_DIM * 4);
    float* wts    = (float*)alloc((size_t)N * NEXP * 4);
    // fused bf16 hi/lo weights
    ushort_t* wf0_h = (ushort_t*)alloc((size_t)NEXP * 131072 * 2);
    ushort_t* wf0_l = (ushort_t*)alloc((size_t)NEXP * 131072 * 2);
    ushort_t* wf1_h = (ushort_t*)alloc((size_t)NEXP * 131072 * 2);
    ushort_t* wf1_l = (ushort_t*)alloc((size_t)NEXP * 131072 * 2);
    ushort_t* wfin_h = (ushort_t*)alloc((size_t)NEXP * 65536 * 2);
    ushort_t* wfin_l = (ushort_t*)alloc((size_t)NEXP * 65536 * 2);
    // fp32 slabs (51.2 MB each)
    float* h    = (float*)alloc((size_t)N * H_DIM * 4);
    float* buf0 = (float*)alloc((size_t)N * H_DIM * 4);
    float* U    = (float*)alloc((size_t)N * H_DIM * 4);
    // bf16 slabs (25.6 MB each)
    ushort_t* aggh_bf = (ushort_t*)alloc((size_t)N * H_DIM * 2);
    ushort_t* hE1_bf  = (ushort_t*)alloc((size_t)N * H_DIM * 2);
    ushort_t* BF      = (ushort_t*)alloc((size_t)N * H_DIM * 2);   // buf0_bf -> PR, per expert
    (void)ws_size; (void)out_size; (void)n_in;

    float* u    = buf0;                    // dead before expert loop writes buf0
    float* tf32 = U;                       // dead before expert loop writes U
    float* out  = (float*)d_out;

    dim3 blk256(256);
    dim3 gR((N + 63) / 64, H_DIM / 64, 1);         // fp32 SGEMM grid (router path)
    dim3 gM((N + 127) / 128, 2, 1);                // MFMA grid, Nc=256
    dim3 gAgg((N + 3) / 4);

    // 0) zero counters
    {
        long nz = (long)(zero_bytes / 4);
        zero_i_kernel<<<dim3((nz + 255) / 256), blk256, 0, stream>>>((int*)ws, nz);
    }
    // 0b) fused weight prep
    wsplit2_kernel<<<dim3(512, NEXP), blk256, 0, stream>>>(W0_rel, W0_root, wf0_h, wf0_l);
    wsplit2_kernel<<<dim3(512, NEXP), blk256, 0, stream>>>(W1_rel, W1_root, wf1_h, wf1_l);
    wsplitcat_kernel<<<dim3(256, NEXP), blk256, 0, stream>>>(W2_rel, W2_root, wfin_h, wfin_l);
    // 1) encoder stage 1 -> u (fp32, in buf0)
    encoder1_kernel<<<dim3(N), blk256, 0, stream>>>(x, enc_W1, enc_b1, u, N, F);
    // 2) h = u @ enc_W2 + enc_b2  (fp32 SGEMM — router exactness)
    gemm256_kernel<<<gR, blk256, 0, stream>>>(u, enc_W2, enc_b2, h, N, H_DIM);
    // 3-5) graph stats
    hist_nodes_kernel<<<dim3(256), blk256, 0, stream>>>(batch, N, gn);
    hist_edges_kernel<<<dim3(512), blk256, 0, stream>>>(ei, batch, E, ge);
    graph_stats_kernel<<<dim3(1), dim3(64), 0, stream>>>(gn, ge, feats_norm, logn_norm);
    // 6) t = h @ r_W1[0:256,:]  (fp32 SGEMM, into U slab)
    gemm256_kernel<<<gR, blk256, 0, stream>>>(h, r_W1, nullptr, tf32, N, H_DIM);
    // 7) router epilogue -> wts
    router_epi_kernel<<<dim3((N + 3) / 4), blk256, 0, stream>>>(
        tf32, batch, feats_norm, logn_norm, r_W1, r_b1, ln_g, ln_b, r_W2, r_b2, centers, wts, N);
    // 8-10) CSR build
    count_dst_kernel<<<dim3((E + 255) / 256), blk256, 0, stream>>>(ei, E, cnt);
    scan_kernel<<<dim3(1), dim3(1024), 0, stream>>>(cnt, row_ptr, N);
    fill_csr_kernel<<<dim3((E + 255) / 256), blk256, 0, stream>>>(ei, E, row_ptr, fillc, srcs);
    // 11) agg_h = Agg(h) once, bf16 out (reference aggregates h before W0_rel)
    agg_f2b_kernel<<<gAgg, blk256, 0, stream>>>(h, aggh_bf, row_ptr, srcs, N);

    // ---- per-expert pipeline ----
    for (int e = 0; e < NEXP; ++e) {
        // buf0 = relu([agg_h | h] @ [W0_rel;W0_root]^T + b0); fp32 + bf16 shadow (for gather)
        gemm_moe_kernel<2, true, false><<<gM, blk256, 0, stream>>>(
            aggh_bf, h, wf0_h + (long)e * 131072, wf0_l + (long)e * 131072,
            b0_rel + e * H_DIM, buf0, BF, N, 256, 512, 1);
        // U = Agg(buf0_bf)  (fp32)
        agg_b2f_kernel<<<gAgg, blk256, 0, stream>>>(BF, U, row_ptr, srcs, N);
        // hE1_bf = relu([U | buf0] @ [W1_rel;W1_root]^T + b1)  (bf16 only)
        gemm_moe_kernel<2, false, false><<<gM, blk256, 0, stream>>>(
            U, buf0, wf1_h + (long)e * 131072, wf1_l + (long)e * 131072,
            b1_rel + e * H_DIM, nullptr, hE1_bf, N, 256, 512, 1);
        // [P|R] = hE1 @ [W2_rel|W2_root]^T  (bf16 only, into BF)
        gemm_moe_kernel<1, true, false><<<gM, blk256, 0, stream>>>(
            hE1_bf, nullptr, wfin_h + (long)e * 65536, wfin_l + (long)e * 65536,
            nullptr, nullptr, BF, N, 256, 256, 0);
        // out (+)= w[:,e] * (Agg(P) + R + b2[e])
        final_mix_kernel<<<gAgg, blk256, 0, stream>>>(
            BF, b2_rel + e * O_DIM, wts, e, row_ptr, srcs, out, N, e == 0 ? 1 : 0);
    }
}

// Round 6
// 1707.350 us; speedup vs baseline: 2.4210x; 1.3494x over previous
//
#include <hip/hip_runtime.h>
#include <hip/hip_bf16.h>

// ---------------- problem constants ----------------
#define H_DIM 256
#define O_DIM 128
#define NEXP 4
#define G_DIM 64

typedef unsigned short ushort_t;
typedef unsigned int uint_t;
typedef __attribute__((ext_vector_type(8))) short short8;
typedef __attribute__((ext_vector_type(4))) float floatx4;

// ---------------- bf16 helpers (RNE) ----------------
__device__ __forceinline__ float bf2f(ushort_t u) {
    union { uint_t i; float f; } c; c.i = ((uint_t)u) << 16; return c.f;
}
__device__ __forceinline__ ushort_t f2bf(float f) {
    union { float f; uint_t i; } c; c.f = f;
    uint_t x = c.i;
    uint_t r = (x + 0x7fffu + ((x >> 16) & 1u)) >> 16;
    return (ushort_t)r;
}

// ---------------- async global->LDS 16B ----------------
__device__ __forceinline__ void load16_lds(const void* g, void* l) {
    __builtin_amdgcn_global_load_lds(
        (const __attribute__((address_space(1))) unsigned int*)g,
        (__attribute__((address_space(3))) unsigned int*)l, 16, 0, 0);
}

// ---------------- utility: zero ints ----------------
__global__ void zero_i_kernel(int* __restrict__ p, long n) {
    long i = (long)blockIdx.x * blockDim.x + threadIdx.x;
    if (i < n) p[i] = 0;
}

// ---------------- fused weight prep ----------------
// vertical k-concat: Wt[z][n][k], k<256 from Wa[z][k][n], k>=256 from Wb[z][k-256][n]; Nc=256, K=512
__global__ void wsplit2_kernel(const float* __restrict__ Wa, const float* __restrict__ Wb,
                               ushort_t* __restrict__ Wh, ushort_t* __restrict__ Wl) {
    int z = blockIdx.y;
    int i = blockIdx.x * 256 + threadIdx.x;        // 256n * 512k
    if (i >= 131072) return;
    int nn = i >> 9, kk = i & 511;
    float v = (kk < 256) ? Wa[(long)z * 65536 + kk * 256 + nn]
                         : Wb[(long)z * 65536 + (kk - 256) * 256 + nn];
    ushort_t hi = f2bf(v);
    long o = (long)z * 131072 + i;
    Wh[o] = hi; Wl[o] = f2bf(v - bf2f(hi));
}

// horizontal n-concat: Wt[z][n][k], n<128 from W2_rel[z][k][n], else W2_root[z][k][n-128]; Nc=256, K=256
__global__ void wsplitcat_kernel(const float* __restrict__ Wa, const float* __restrict__ Wb,
                                 ushort_t* __restrict__ Wh, ushort_t* __restrict__ Wl) {
    int z = blockIdx.y;
    int i = blockIdx.x * 256 + threadIdx.x;        // 256n * 256k
    if (i >= 65536) return;
    int nn = i >> 8, kk = i & 255;
    float v = (nn < 128) ? Wa[(long)z * 32768 + kk * 128 + nn]
                         : Wb[(long)z * 32768 + kk * 128 + (nn - 128)];
    ushort_t hi = f2bf(v);
    long o = (long)z * 65536 + i;
    Wh[o] = hi; Wl[o] = f2bf(v - bf2f(hi));
}

// ---------------- encoder stage 1 (fp32, verified) ----------------
__global__ void encoder1_kernel(const float* __restrict__ x, const float* __restrict__ W1,
                                const float* __restrict__ b1, float* __restrict__ u,
                                int N, int F) {
    int n = blockIdx.x;
    int j = threadIdx.x;
    float acc = b1[j];
    #pragma unroll
    for (int c = 0; c < 6; ++c)
        acc += x[(long)n * F + 4 + c] * W1[c * H_DIM + j];
    u[(long)n * H_DIM + j] = fmaxf(acc, 0.f);
}

// ---------------- fp32 vector SGEMM (router path, verified) + optional bf16 shadow ----------------
__global__ __launch_bounds__(256)
void gemm256_kernel(const float* __restrict__ A, const float* __restrict__ W,
                    const float* __restrict__ bias, float* __restrict__ C,
                    ushort_t* __restrict__ Cbf, int M, int Nc) {
    const int K = 256;
    __shared__ float As[16][68];
    __shared__ float Ws[16][68];
    int tid = threadIdx.x;
    int tx = tid & 15, ty = tid >> 4;
    int row0 = blockIdx.x * 64;
    int col0 = blockIdx.y * 64;
    float acc[4][4] = {};
    int lrow = tid >> 2, kq = tid & 3;
    int wk = tid >> 4, wc = (tid & 15) * 4;
    for (int k0 = 0; k0 < K; k0 += 16) {
        float4 av = make_float4(0.f, 0.f, 0.f, 0.f);
        int arow = row0 + lrow;
        if (arow < M) av = *(const float4*)(A + (long)arow * K + k0 + kq * 4);
        As[kq * 4 + 0][lrow] = av.x;
        As[kq * 4 + 1][lrow] = av.y;
        As[kq * 4 + 2][lrow] = av.z;
        As[kq * 4 + 3][lrow] = av.w;
        float4 wv = *(const float4*)(W + (long)(k0 + wk) * Nc + col0 + wc);
        *(float4*)&Ws[wk][wc] = wv;
        __syncthreads();
        #pragma unroll
        for (int kk = 0; kk < 16; ++kk) {
            float a[4], b[4];
            #pragma unroll
            for (int i = 0; i < 4; ++i) a[i] = As[kk][ty * 4 + i];
            #pragma unroll
            for (int j = 0; j < 4; ++j) b[j] = Ws[kk][tx * 4 + j];
            #pragma unroll
            for (int i = 0; i < 4; ++i)
                #pragma unroll
                for (int j = 0; j < 4; ++j) acc[i][j] += a[i] * b[j];
        }
        __syncthreads();
    }
    #pragma unroll
    for (int i = 0; i < 4; ++i) {
        int r = row0 + ty * 4 + i;
        if (r >= M) break;
        #pragma unroll
        for (int j = 0; j < 4; ++j) {
            int c = col0 + tx * 4 + j;
            float v = acc[i][j];
            if (bias) v += bias[c];
            C[(long)r * Nc + c] = v;
            if (Cbf) Cbf[(long)r * Nc + c] = f2bf(v);
        }
    }
}

// ---------------- MFMA GEMM, z-batched experts, swizzled LDS ----------------
// C[z] = [relu]( sum_halves A_half[z] @ B[z]^T + [bias[z]] ); B fused (Nc=256, Kb) bf16 hi/lo.
// A halves each (M,256), fp32 (split-3) or bf16 (2-product). 128x128 tile, BK=32,
// 4 waves 2x2, 4x4 frags of 16x16x32. Byte strides for A; element strides otherwise.
// LDS source-address swizzle: fp32 rows XOR(row&7) on 8x16B chunks; bf16 rows
// add-rotate((row>>1)&3) on 4x16B chunks -> <=2-way bank aliasing (free, m136).
template<int NH, bool A1BF, bool A2BF>
__global__ __launch_bounds__(256)
void gemm_moe_kernel(const void* __restrict__ A1v, long sA1z,
                     const void* __restrict__ A2v, long sA2z,
                     const ushort_t* __restrict__ Bh, const ushort_t* __restrict__ Bl, long sBz,
                     const float* __restrict__ bias, int sBiasz,
                     ushort_t* __restrict__ Cbf, long sCz,
                     int M, int Nc, int Kb, int relu) {
    constexpr int ASZ = (A1BF && (NH == 1 || A2BF)) ? (128 * 32 * 2) : (128 * 32 * 4);
    __shared__ alignas(16) unsigned char AslRaw[ASZ];
    __shared__ alignas(16) ushort_t Bhs[128 * 32];
    __shared__ alignas(16) ushort_t Bls[128 * 32];
    float* Aslf = (float*)AslRaw;
    ushort_t* Aslu = (ushort_t*)AslRaw;

    const int tid = threadIdx.x, wave = tid >> 6, lane = tid & 63;
    const int z = blockIdx.z;
    const int row0 = blockIdx.x * 128, col0 = blockIdx.y * 128;
    const int wr = (wave >> 1) * 64, wcx = (wave & 1) * 64;
    floatx4 acc[4][4] = {};

    const char* A1b = (const char*)A1v + (long)z * sA1z;
    const char* A2b = (const char*)A2v + (long)z * sA2z;
    Bh += (long)z * sBz; Bl += (long)z * sBz;
    if (bias) bias += (long)z * sBiasz;
    Cbf += (long)z * sCz;

    // fp32 A staging map: 8 lanes/row (8x16B chunks), XOR swizzle
    const int asr = lane >> 3;                    // row in group of 8
    const int fgc = (lane & 7) ^ asr;             // global chunk to fetch
    long aoff_f[4];
    #pragma unroll
    for (int q = 0; q < 4; ++q) {
        int ar = row0 + wave * 32 + q * 8 + asr;
        ar = ar < M ? ar : M - 1;
        aoff_f[q] = (long)ar * 256 + fgc * 4;
    }
    // bf16 A staging map: 4 lanes/row (4x16B chunks), add-rotate swizzle
    const int bsr = lane >> 2;                    // row in group of 16
    const int bgc = ((lane & 3) - (bsr >> 1)) & 3;
    long aoff_b[2];
    #pragma unroll
    for (int q = 0; q < 2; ++q) {
        int ar = row0 + wave * 32 + q * 16 + bsr;
        ar = ar < M ? ar : M - 1;
        aoff_b[q] = (long)ar * 256 + bgc * 8;
    }
    // B staging (bf16 map; Nc=256 so no clamp)
    const long brow = (long)(col0 + wave * 32 + bsr) * Kb + bgc * 8;
    const ushort_t* Bhg0 = Bh + brow;
    const ushort_t* Bhg1 = Bh + brow + (long)16 * Kb;
    const ushort_t* Blg0 = Bl + brow;
    const ushort_t* Blg1 = Bl + brow + (long)16 * Kb;
    ushort_t* Bhl0 = &Bhs[(wave * 32) * 32];
    ushort_t* Bhl1 = &Bhs[(wave * 32 + 16) * 32];
    ushort_t* Bll0 = &Bls[(wave * 32) * 32];
    ushort_t* Bll1 = &Bls[(wave * 32 + 16) * 32];

    const int fm = lane & 15, fq = lane >> 4;

    #pragma unroll
    for (int half = 0; half < NH; ++half) {
        const bool ABF = (half == 0) ? A1BF : A2BF;
        const char* Ab = (half == 0) ? A1b : A2b;
        for (int k0 = 0; k0 < 256; k0 += 32) {
            const int kk = half * 256 + k0;
            if (ABF) {
                const ushort_t* Au = (const ushort_t*)Ab;
                load16_lds(Au + aoff_b[0] + k0, &Aslu[(wave * 32) * 32]);
                load16_lds(Au + aoff_b[1] + k0, &Aslu[(wave * 32 + 16) * 32]);
            } else {
                const float* Af = (const float*)Ab;
                #pragma unroll
                for (int q = 0; q < 4; ++q)
                    load16_lds(Af + aoff_f[q] + k0, &Aslf[(wave * 32 + q * 8) * 32]);
            }
            load16_lds(Bhg0 + kk, Bhl0);
            load16_lds(Bhg1 + kk, Bhl1);
            load16_lds(Blg0 + kk, Bll0);
            load16_lds(Blg1 + kk, Bll1);
            __syncthreads();

            short8 bh[4], bl[4];
            #pragma unroll
            for (int j = 0; j < 4; ++j) {
                int row = wcx + j * 16 + fm;
                int slot = (fq + ((row >> 1) & 3)) & 3;
                bh[j] = *(const short8*)&Bhs[row * 32 + slot * 8];
                bl[j] = *(const short8*)&Bls[row * 32 + slot * 8];
            }
            if (ABF) {
                short8 a[4];
                #pragma unroll
                for (int i = 0; i < 4; ++i) {
                    int row = wr + i * 16 + fm;
                    int slot = (fq + ((row >> 1) & 3)) & 3;
                    a[i] = *(const short8*)&Aslu[row * 32 + slot * 8];
                }
                #pragma unroll
                for (int i = 0; i < 4; ++i)
                    #pragma unroll
                    for (int j = 0; j < 4; ++j) {
                        acc[i][j] = __builtin_amdgcn_mfma_f32_16x16x32_bf16(a[i], bl[j], acc[i][j], 0, 0, 0);
                        acc[i][j] = __builtin_amdgcn_mfma_f32_16x16x32_bf16(a[i], bh[j], acc[i][j], 0, 0, 0);
                    }
            } else {
                short8 ah[4], al[4];
                #pragma unroll
                for (int i = 0; i < 4; ++i) {
                    int row = wr + i * 16 + fm;
                    int r7 = row & 7;
                    float4 v0 = *(const float4*)&Aslf[row * 32 + ((2 * fq) ^ r7) * 4];
                    float4 v1 = *(const float4*)&Aslf[row * 32 + ((2 * fq + 1) ^ r7) * 4];
                    float av[8] = {v0.x, v0.y, v0.z, v0.w, v1.x, v1.y, v1.z, v1.w};
                    #pragma unroll
                    for (int j = 0; j < 8; ++j) {
                        ushort_t hi = f2bf(av[j]);
                        ah[i][j] = (short)hi;
                        al[i][j] = (short)f2bf(av[j] - bf2f(hi));
                    }
                }
                #pragma unroll
                for (int i = 0; i < 4; ++i)
                    #pragma unroll
                    for (int j = 0; j < 4; ++j) {
                        acc[i][j] = __builtin_amdgcn_mfma_f32_16x16x32_bf16(al[i], bh[j], acc[i][j], 0, 0, 0);
                        acc[i][j] = __builtin_amdgcn_mfma_f32_16x16x32_bf16(ah[i], bl[j], acc[i][j], 0, 0, 0);
                        acc[i][j] = __builtin_amdgcn_mfma_f32_16x16x32_bf16(ah[i], bh[j], acc[i][j], 0, 0, 0);
                    }
            }
            __syncthreads();
        }
    }

    // epilogue: C/D layout col=lane&15, row=(lane>>4)*4+reg  [verified m89]
    #pragma unroll
    for (int i = 0; i < 4; ++i) {
        #pragma unroll
        for (int j = 0; j < 4; ++j) {
            int col = col0 + wcx + j * 16 + fm;
            int rowb = row0 + wr + i * 16 + fq * 4;
            #pragma unroll
            for (int r = 0; r < 4; ++r) {
                int row = rowb + r;
                if (row < M) {
                    float v = acc[i][j][r];
                    if (bias) v += bias[col];
                    if (relu) v = fmaxf(v, 0.f);
                    Cbf[(long)row * Nc + col] = f2bf(v);
                }
            }
        }
    }
}

// ---------------- graph-stat histograms ----------------
__global__ void hist_nodes_kernel(const int* __restrict__ batch, int n, int* __restrict__ gn) {
    __shared__ int bins[G_DIM];
    int t = threadIdx.x;
    if (t < G_DIM) bins[t] = 0;
    __syncthreads();
    for (long i = (long)blockIdx.x * blockDim.x + t; i < n; i += (long)gridDim.x * blockDim.x)
        atomicAdd(&bins[batch[i]], 1);
    __syncthreads();
    if (t < G_DIM) atomicAdd(&gn[t], bins[t]);
}

__global__ void hist_edges_kernel(const int* __restrict__ ei, const int* __restrict__ batch,
                                  int E, int* __restrict__ ge) {
    __shared__ int bins[G_DIM];
    int t = threadIdx.x;
    if (t < G_DIM) bins[t] = 0;
    __syncthreads();
    for (long i = (long)blockIdx.x * blockDim.x + t; i < E; i += (long)gridDim.x * blockDim.x)
        atomicAdd(&bins[batch[ei[i]]], 1);
    __syncthreads();
    if (t < G_DIM) atomicAdd(&ge[t], bins[t]);
}

// ---------------- graph stats ----------------
__global__ void graph_stats_kernel(const int* __restrict__ gn, const int* __restrict__ ge,
                                   float* __restrict__ feats_norm, float* __restrict__ logn_norm) {
    int g = threadIdx.x;
    float nv = fmaxf((float)gn[g], 1.0f);
    float ev = (float)ge[g];
    float density = ev / fmaxf(nv * (nv - 1.0f), 1.0f);
    float logn = logf(nv);
    float mn = logn, mx = logn;
    for (int o = 32; o; o >>= 1) {
        mn = fminf(mn, __shfl_xor(mn, o));
        mx = fmaxf(mx, __shfl_xor(mx, o));
    }
    logn_norm[g] = (logn - mn) / (mx - mn + 1e-6f);
    float f[3] = {nv, ev, density};
    #pragma unroll
    for (int c = 0; c < 3; ++c) {
        float s = f[c];
        for (int o = 32; o; o >>= 1) s += __shfl_xor(s, o);
        float mean = s / 64.f;
        float d = f[c] - mean;
        float v = d * d;
        for (int o = 32; o; o >>= 1) v += __shfl_xor(v, o);
        float stdv = sqrtf(v / 64.f);
        feats_norm[g * 3 + c] = d / (stdv + 1e-6f);
    }
}

// ---------------- router epilogue (verified) ----------------
__global__ __launch_bounds__(256)
void router_epi_kernel(const float* __restrict__ t, const int* __restrict__ batch,
                       const float* __restrict__ feats_norm, const float* __restrict__ logn_norm,
                       const float* __restrict__ rW1, const float* __restrict__ rb1,
                       const float* __restrict__ lng, const float* __restrict__ lnb,
                       const float* __restrict__ rW2, const float* __restrict__ rb2,
                       const float* __restrict__ centers, float* __restrict__ w, int N) {
    int wave = threadIdx.x >> 6, lane = threadIdx.x & 63;
    int n = blockIdx.x * 4 + wave;
    if (n >= N) return;
    int g = batch[n];
    float sf0 = feats_norm[g * 3 + 0], sf1 = feats_norm[g * 3 + 1], sf2 = feats_norm[g * 3 + 2];
    float ln = logn_norm[g];
    float tv[4];
    #pragma unroll
    for (int q = 0; q < 4; ++q) {
        int j = lane + 64 * q;
        tv[q] = t[(long)n * H_DIM + j] + rb1[j]
              + sf0 * rW1[256 * H_DIM + j] + sf1 * rW1[257 * H_DIM + j] + sf2 * rW1[258 * H_DIM + j];
    }
    float s = tv[0] + tv[1] + tv[2] + tv[3];
    for (int o = 32; o; o >>= 1) s += __shfl_xor(s, o);
    float mean = s / 256.f;
    float vs = 0.f;
    #pragma unroll
    for (int q = 0; q < 4; ++q) { float d = tv[q] - mean; vs += d * d; }
    for (int o = 32; o; o >>= 1) vs += __shfl_xor(vs, o);
    float rstd = rsqrtf(vs / 256.f + 1e-5f);
    float le[NEXP] = {0.f, 0.f, 0.f, 0.f};
    #pragma unroll
    for (int q = 0; q < 4; ++q) {
        int j = lane + 64 * q;
        float y = (tv[q] - mean) * rstd * lng[j] + lnb[j];
        y = fmaxf(y, 0.f);
        #pragma unroll
        for (int e = 0; e < NEXP; ++e) le[e] += y * rW2[j * NEXP + e];
    }
    #pragma unroll
    for (int e = 0; e < NEXP; ++e)
        for (int o = 32; o; o >>= 1) le[e] += __shfl_xor(le[e], o);
    if (lane == 0) {
        float p[NEXP];
        float m = -1e30f;
        #pragma unroll
        for (int e = 0; e < NEXP; ++e) {
            float d = ln - centers[e];
            float lv = 0.7f * (le[e] + rb2[e]) + 0.3f * (-(d * d));
            p[e] = lv;
            m = fmaxf(m, lv);
        }
        float ssum = 0.f;
        #pragma unroll
        for (int e = 0; e < NEXP; ++e) { p[e] = expf(p[e] - m); ssum += p[e]; }
        #pragma unroll
        for (int e = 0; e < NEXP; ++e) p[e] /= ssum;
        int i1 = 0;
        for (int e = 1; e < NEXP; ++e) if (p[e] > p[i1]) i1 = e;
        int i2 = -1;
        for (int e = 0; e < NEXP; ++e) { if (e == i1) continue; if (i2 < 0 || p[e] > p[i2]) i2 = e; }
        float denom = p[i1] + p[i2] + 1e-8f;
        float out4[NEXP] = {0.f, 0.f, 0.f, 0.f};
        out4[i1] = p[i1] / denom;
        out4[i2] = p[i2] / denom;
        #pragma unroll
        for (int e = 0; e < NEXP; ++e) w[(long)n * NEXP + e] = out4[e];
    }
}

// ---------------- CSR build ----------------
__global__ void count_dst_kernel(const int* __restrict__ ei, int E, int* __restrict__ cnt) {
    int i = blockIdx.x * blockDim.x + threadIdx.x;
    if (i < E) atomicAdd(&cnt[ei[E + i]], 1);
}

__global__ __launch_bounds__(1024)
void scan_kernel(const int* __restrict__ cnt, int* __restrict__ row_ptr, int n) {
    __shared__ int buf[1024];
    __shared__ int carry_s;
    int tid = threadIdx.x;
    if (tid == 0) carry_s = 0;
    __syncthreads();
    for (int base = 0; base < n; base += 1024) {
        int v = (base + tid < n) ? cnt[base + tid] : 0;
        buf[tid] = v;
        __syncthreads();
        for (int off = 1; off < 1024; off <<= 1) {
            int tv = (tid >= off) ? buf[tid - off] : 0;
            __syncthreads();
            buf[tid] += tv;
            __syncthreads();
        }
        int carry = carry_s;
        if (base + tid < n) row_ptr[base + tid] = carry + buf[tid] - v;
        __syncthreads();
        if (tid == 1023) carry_s = carry + buf[1023];
        __syncthreads();
    }
    if (tid == 0) row_ptr[n] = carry_s;
}

__global__ void fill_csr_kernel(const int* __restrict__ ei, int E, const int* __restrict__ row_ptr,
                                int* __restrict__ fillc, int* __restrict__ srcs) {
    int i = blockIdx.x * blockDim.x + threadIdx.x;
    if (i < E) {
        int d = ei[E + i];
        int pos = row_ptr[d] + atomicAdd(&fillc[d], 1);
        srcs[pos] = ei[i];
    }
}

// ---------------- CSR gather bf16->bf16 (fp32 accum), z-batched via grid.y ----------------
__global__ __launch_bounds__(256)
void agg_b2b_kernel(const ushort_t* __restrict__ feat, ushort_t* __restrict__ outp,
                    const int* __restrict__ rp, const int* __restrict__ srcs, int N) {
    long zoff = (long)blockIdx.y * N * H_DIM;
    int wave = threadIdx.x >> 6, lane = threadIdx.x & 63;
    int n = blockIdx.x * 4 + wave;
    if (n >= N) return;
    float a0 = 0.f, a1 = 0.f, a2 = 0.f, a3 = 0.f;
    int p0 = rp[n], p1 = rp[n + 1];
    const ushort_t* base = feat + zoff + lane * 4;
    for (int p = p0; p < p1; ++p) {
        long s = srcs[p];
        uint2 v = *(const uint2*)(base + s * H_DIM);
        a0 += bf2f((ushort_t)(v.x & 0xffff));
        a1 += bf2f((ushort_t)(v.x >> 16));
        a2 += bf2f((ushort_t)(v.y & 0xffff));
        a3 += bf2f((ushort_t)(v.y >> 16));
    }
    uint2 o;
    o.x = (uint_t)f2bf(a0) | ((uint_t)f2bf(a1) << 16);
    o.y = (uint_t)f2bf(a2) | ((uint_t)f2bf(a3) << 16);
    *(uint2*)(outp + zoff + (long)n * H_DIM + lane * 4) = o;
}

// ---------------- final mix, 2 experts per dispatch ----------------
// PR[z]: (N,256) bf16, cols 0..127 = P, 128..255 = R;  out += sum_z w[n,e0+z]*(Agg(P)+R+b2)
__global__ __launch_bounds__(256)
void final_mix2_kernel(const ushort_t* __restrict__ PR, const float* __restrict__ b2,
                       const float* __restrict__ wts, int e0,
                       const int* __restrict__ rp, const int* __restrict__ srcs,
                       float* __restrict__ out, int N, int init) {
    int wave = threadIdx.x >> 6, lane = threadIdx.x & 63;
    int n = blockIdx.x * 4 + wave;
    if (n >= N) return;
    int c0 = lane * 2;
    float w0 = wts[(long)n * NEXP + e0];
    float w1 = wts[(long)n * NEXP + e0 + 1];
    long obase = (long)n * O_DIM + c0;
    float o0 = init ? 0.f : out[obase];
    float o1 = init ? 0.f : out[obase + 1];
    const ushort_t* PR0 = PR;
    const ushort_t* PR1 = PR + (long)N * 256;
    bool u0 = (w0 != 0.f), u1 = (w1 != 0.f);
    if (u0 || u1) {
        float a00 = 0.f, a01 = 0.f, a10 = 0.f, a11 = 0.f;
        int p0 = rp[n], p1 = rp[n + 1];
        if (u0 && u1) {
            for (int p = p0; p < p1; ++p) {
                long s = srcs[p];
                uint_t v0 = *(const uint_t*)(PR0 + s * 256 + c0);
                uint_t v1 = *(const uint_t*)(PR1 + s * 256 + c0);
                a00 += bf2f((ushort_t)(v0 & 0xffff)); a01 += bf2f((ushort_t)(v0 >> 16));
                a10 += bf2f((ushort_t)(v1 & 0xffff)); a11 += bf2f((ushort_t)(v1 >> 16));
            }
        } else {
            const ushort_t* PB = u0 ? PR0 : PR1;
            for (int p = p0; p < p1; ++p) {
                long s = srcs[p];
                uint_t v = *(const uint_t*)(PB + s * 256 + c0);
                a00 += bf2f((ushort_t)(v & 0xffff)); a01 += bf2f((ushort_t)(v >> 16));
            }
            if (u1) { a10 = a00; a11 = a01; a00 = 0.f; a01 = 0.f; }
        }
        if (u0) {
            uint_t rv = *(const uint_t*)(PR0 + (long)n * 256 + 128 + c0);
            o0 += w0 * (a00 + bf2f((ushort_t)(rv & 0xffff)) + b2[e0 * O_DIM + c0]);
            o1 += w0 * (a01 + bf2f((ushort_t)(rv >> 16)) + b2[e0 * O_DIM + c0 + 1]);
        }
        if (u1) {
            uint_t rv = *(const uint_t*)(PR1 + (long)n * 256 + 128 + c0);
            o0 += w1 * (a10 + bf2f((ushort_t)(rv & 0xffff)) + b2[(e0 + 1) * O_DIM + c0]);
            o1 += w1 * (a11 + bf2f((ushort_t)(rv >> 16)) + b2[(e0 + 1) * O_DIM + c0 + 1]);
        }
    }
    out[obase] = o0;
    out[obase + 1] = o1;
}

// ==================== host launcher ====================
extern "C" void kernel_launch(void* const* d_in, const int* in_sizes, int n_in,
                              void* d_out, int out_size, void* d_ws, size_t ws_size,
                              hipStream_t stream) {
    const float* x       = (const float*)d_in[0];
    const int*   ei      = (const int*)  d_in[1];
    const int*   batch   = (const int*)  d_in[2];
    const float* enc_W1  = (const float*)d_in[3];
    const float* enc_b1  = (const float*)d_in[4];
    const float* enc_W2  = (const float*)d_in[5];
    const float* enc_b2  = (const float*)d_in[6];
    const float* r_W1    = (const float*)d_in[7];
    const float* r_b1    = (const float*)d_in[8];
    const float* ln_g    = (const float*)d_in[9];
    const float* ln_b    = (const float*)d_in[10];
    const float* r_W2    = (const float*)d_in[11];
    const float* r_b2    = (const float*)d_in[12];
    const float* centers = (const float*)d_in[13];
    const float* W0_rel  = (const float*)d_in[14];
    const float* b0_rel  = (const float*)d_in[15];
    const float* W0_root = (const float*)d_in[16];
    const float* W1_rel  = (const float*)d_in[17];
    const float* b1_rel  = (const float*)d_in[18];
    const float* W1_root = (const float*)d_in[19];
    const float* W2_rel  = (const float*)d_in[20];
    const float* b2_rel  = (const float*)d_in[21];
    const float* W2_root = (const float*)d_in[22];

    const int N = in_sizes[2];
    const int E = in_sizes[1] / 2;
    const int F = in_sizes[0] / N;

    // ---- workspace layout (256B-aligned slabs); peak ~266 MB ----
    char* ws = (char*)d_ws;
    size_t off = 0;
    auto alloc = [&](size_t bytes) -> void* {
        void* p = ws + off;
        off += (bytes + 255) & ~(size_t)255;
        return p;
    };
    int* cnt      = (int*)alloc((size_t)N * 4);
    int* fillc    = (int*)alloc((size_t)N * 4);
    int* gn       = (int*)alloc((size_t)G_DIM * 4);
    int* ge       = (int*)alloc((size_t)G_DIM * 4);
    size_t zero_bytes = off;
    int* row_ptr  = (int*)alloc((size_t)(N + 1) * 4);
    int* srcs     = (int*)alloc((size_t)E * 4);
    float* feats_norm = (float*)alloc((size_t)G_DIM * 3 * 4);
    float* logn_norm  = (float*)alloc((size_t)G_DIM * 4);
    float* wts    = (float*)alloc((size_t)N * NEXP * 4);
    // fused bf16 hi/lo weights
    ushort_t* wf0_h  = (ushort_t*)alloc((size_t)NEXP * 131072 * 2);
    ushort_t* wf0_l  = (ushort_t*)alloc((size_t)NEXP * 131072 * 2);
    ushort_t* wf1_h  = (ushort_t*)alloc((size_t)NEXP * 131072 * 2);
    ushort_t* wf1_l  = (ushort_t*)alloc((size_t)NEXP * 131072 * 2);
    ushort_t* wfin_h = (ushort_t*)alloc((size_t)NEXP * 65536 * 2);
    ushort_t* wfin_l = (ushort_t*)alloc((size_t)NEXP * 65536 * 2);
    // activation slabs
    const long sE = (long)N * H_DIM;               // per-expert element stride
    float*    h       = (float*)   alloc((size_t)sE * 4);      // 51.2 MB fp32
    ushort_t* h_bf    = (ushort_t*)alloc((size_t)sE * 2);      // 25.6 MB
    ushort_t* aggh_bf = (ushort_t*)alloc((size_t)sE * 2);      // 25.6 MB
    ushort_t* hE0_bf  = (ushort_t*)alloc((size_t)2 * sE * 2);  // 51.2 MB (x2 experts; reused for PR)
    ushort_t* aggE_bf = (ushort_t*)alloc((size_t)2 * sE * 2);  // 51.2 MB
    ushort_t* hE1_bf  = (ushort_t*)alloc((size_t)2 * sE * 2);  // 51.2 MB
    (void)ws_size; (void)out_size; (void)n_in;

    float* u    = (float*)aggE_bf;        // fp32 overlay, dead before expert loop
    float* tf32 = (float*)hE0_bf;         // fp32 overlay, dead before expert loop
    float* out  = (float*)d_out;

    dim3 blk256(256);
    dim3 gR((N + 63) / 64, H_DIM / 64, 1);         // fp32 SGEMM grid (router path)
    dim3 gM((N + 127) / 128, 2, 2);                // MFMA grid: col tiles x 2, experts x 2
    dim3 gAgg((N + 3) / 4);
    dim3 gAgg2((N + 3) / 4, 2);

    // 0) zero counters
    {
        long nz = (long)(zero_bytes / 4);
        zero_i_kernel<<<dim3((nz + 255) / 256), blk256, 0, stream>>>((int*)ws, nz);
    }
    // 0b) fused weight prep
    wsplit2_kernel<<<dim3(512, NEXP), blk256, 0, stream>>>(W0_rel, W0_root, wf0_h, wf0_l);
    wsplit2_kernel<<<dim3(512, NEXP), blk256, 0, stream>>>(W1_rel, W1_root, wf1_h, wf1_l);
    wsplitcat_kernel<<<dim3(256, NEXP), blk256, 0, stream>>>(W2_rel, W2_root, wfin_h, wfin_l);
    // 1) encoder stage 1 -> u
    encoder1_kernel<<<dim3(N), blk256, 0, stream>>>(x, enc_W1, enc_b1, u, N, F);
    // 2) h = u @ enc_W2 + enc_b2 (fp32 SGEMM, + bf16 shadow for the gather)
    gemm256_kernel<<<gR, blk256, 0, stream>>>(u, enc_W2, enc_b2, h, h_bf, N, H_DIM);
    // 3-5) graph stats
    hist_nodes_kernel<<<dim3(256), blk256, 0, stream>>>(batch, N, gn);
    hist_edges_kernel<<<dim3(512), blk256, 0, stream>>>(ei, batch, E, ge);
    graph_stats_kernel<<<dim3(1), dim3(64), 0, stream>>>(gn, ge, feats_norm, logn_norm);
    // 6) t = h @ r_W1[0:256,:] (fp32 SGEMM)
    gemm256_kernel<<<gR, blk256, 0, stream>>>(h, r_W1, nullptr, tf32, nullptr, N, H_DIM);
    // 7) router epilogue -> wts
    router_epi_kernel<<<dim3((N + 3) / 4), blk256, 0, stream>>>(
        tf32, batch, feats_norm, logn_norm, r_W1, r_b1, ln_g, ln_b, r_W2, r_b2, centers, wts, N);
    // 8-10) CSR build
    count_dst_kernel<<<dim3((E + 255) / 256), blk256, 0, stream>>>(ei, E, cnt);
    scan_kernel<<<dim3(1), dim3(1024), 0, stream>>>(cnt, row_ptr, N);
    fill_csr_kernel<<<dim3((E + 255) / 256), blk256, 0, stream>>>(ei, E, row_ptr, fillc, srcs);
    // 11) agg_h = Agg(h_bf), bf16
    agg_b2b_kernel<<<gAgg, blk256, 0, stream>>>(h_bf, aggh_bf, row_ptr, srcs, N);

    // ---- expert pipeline, 2 experts per dispatch (z-batched) ----
    for (int b = 0; b < 2; ++b) {
        const int e0 = b * 2;
        // hE0[z] = relu([agg_h | h] @ [W0_rel;W0_root]^T + b0)   (A shared across z)
        gemm_moe_kernel<2, true, false><<<gM, blk256, 0, stream>>>(
            aggh_bf, 0, h, 0,
            wf0_h + (long)e0 * 131072, wf0_l + (long)e0 * 131072, 131072,
            b0_rel + e0 * H_DIM, H_DIM, hE0_bf, sE, N, 256, 512, 1);
        // aggE[z] = Agg(hE0[z])
        agg_b2b_kernel<<<gAgg2, blk256, 0, stream>>>(hE0_bf, aggE_bf, row_ptr, srcs, N);
        // hE1[z] = relu([aggE | hE0] @ [W1_rel;W1_root]^T + b1)
        gemm_moe_kernel<2, true, true><<<gM, blk256, 0, stream>>>(
            aggE_bf, sE * 2, hE0_bf, sE * 2,
            wf1_h + (long)e0 * 131072, wf1_l + (long)e0 * 131072, 131072,
            b1_rel + e0 * H_DIM, H_DIM, hE1_bf, sE, N, 256, 512, 1);
        // PR[z] = hE1 @ [W2_rel|W2_root]^T   (overlay onto dead hE0)
        gemm_moe_kernel<1, true, true><<<gM, blk256, 0, stream>>>(
            hE1_bf, sE * 2, nullptr, 0,
            wfin_h + (long)e0 * 65536, wfin_l + (long)e0 * 65536, 65536,
            nullptr, 0, hE0_bf, sE, N, 256, 256, 0);
        // out (+)= sum_z w[:,e0+z] * (Agg(P[z]) + R[z] + b2[e0+z])
        final_mix2_kernel<<<gAgg, blk256, 0, stream>>>(
            hE0_bf, b2_rel, wts, e0, row_ptr, srcs, out, N, b == 0 ? 1 : 0);
    }
}

// Round 7
// 1598.215 us; speedup vs baseline: 2.5863x; 1.0683x over previous
//
#include <hip/hip_runtime.h>
#include <hip/hip_bf16.h>

// ---------------- problem constants ----------------
#define H_DIM 256
#define O_DIM 128
#define NEXP 4
#define G_DIM 64

typedef unsigned short ushort_t;
typedef unsigned int uint_t;
typedef __attribute__((ext_vector_type(8))) short short8;
typedef __attribute__((ext_vector_type(4))) float floatx4;

// ---------------- bf16 helpers (RNE) ----------------
__device__ __forceinline__ float bf2f(ushort_t u) {
    union { uint_t i; float f; } c; c.i = ((uint_t)u) << 16; return c.f;
}
__device__ __forceinline__ ushort_t f2bf(float f) {
    union { float f; uint_t i; } c; c.f = f;
    uint_t x = c.i;
    uint_t r = (x + 0x7fffu + ((x >> 16) & 1u)) >> 16;
    return (ushort_t)r;
}

// ---------------- async global->LDS 16B ----------------
__device__ __forceinline__ void load16_lds(const void* g, void* l) {
    __builtin_amdgcn_global_load_lds(
        (const __attribute__((address_space(1))) unsigned int*)g,
        (__attribute__((address_space(3))) unsigned int*)l, 16, 0, 0);
}

// ---------------- utility: zero ints ----------------
__global__ void zero_i_kernel(int* __restrict__ p, long n) {
    long i = (long)blockIdx.x * blockDim.x + threadIdx.x;
    if (i < n) p[i] = 0;
}

// ---------------- fused weight prep ----------------
// vertical k-concat: Wt[z][n][k], k<256 from Wa[z][k][n], k>=256 from Wb[z][k-256][n]; Nc=256, K=512
__global__ void wsplit2_kernel(const float* __restrict__ Wa, const float* __restrict__ Wb,
                               ushort_t* __restrict__ Wh, ushort_t* __restrict__ Wl) {
    int z = blockIdx.y;
    int i = blockIdx.x * 256 + threadIdx.x;        // 256n * 512k
    if (i >= 131072) return;
    int nn = i >> 9, kk = i & 511;
    float v = (kk < 256) ? Wa[(long)z * 65536 + kk * 256 + nn]
                         : Wb[(long)z * 65536 + (kk - 256) * 256 + nn];
    ushort_t hi = f2bf(v);
    long o = (long)z * 131072 + i;
    Wh[o] = hi; Wl[o] = f2bf(v - bf2f(hi));
}

// horizontal n-concat: Wt[z][n][k], n<128 from W2_rel[z][k][n], else W2_root[z][k][n-128]; Nc=256, K=256
__global__ void wsplitcat_kernel(const float* __restrict__ Wa, const float* __restrict__ Wb,
                                 ushort_t* __restrict__ Wh, ushort_t* __restrict__ Wl) {
    int z = blockIdx.y;
    int i = blockIdx.x * 256 + threadIdx.x;        // 256n * 256k
    if (i >= 65536) return;
    int nn = i >> 8, kk = i & 255;
    float v = (nn < 128) ? Wa[(long)z * 32768 + kk * 128 + nn]
                         : Wb[(long)z * 32768 + kk * 128 + (nn - 128)];
    ushort_t hi = f2bf(v);
    long o = (long)z * 65536 + i;
    Wh[o] = hi; Wl[o] = f2bf(v - bf2f(hi));
}

// ---------------- encoder stage 1 (fp32, verified) ----------------
__global__ void encoder1_kernel(const float* __restrict__ x, const float* __restrict__ W1,
                                const float* __restrict__ b1, float* __restrict__ u,
                                int N, int F) {
    int n = blockIdx.x;
    int j = threadIdx.x;
    float acc = b1[j];
    #pragma unroll
    for (int c = 0; c < 6; ++c)
        acc += x[(long)n * F + 4 + c] * W1[c * H_DIM + j];
    u[(long)n * H_DIM + j] = fmaxf(acc, 0.f);
}

// ---------------- fp32 vector SGEMM (router path — DO NOT CHANGE: top-2 flip risk) ----------------
__global__ __launch_bounds__(256)
void gemm256_kernel(const float* __restrict__ A, const float* __restrict__ W,
                    const float* __restrict__ bias, float* __restrict__ C,
                    ushort_t* __restrict__ Cbf, int M, int Nc) {
    const int K = 256;
    __shared__ float As[16][68];
    __shared__ float Ws[16][68];
    int tid = threadIdx.x;
    int tx = tid & 15, ty = tid >> 4;
    int row0 = blockIdx.x * 64;
    int col0 = blockIdx.y * 64;
    float acc[4][4] = {};
    int lrow = tid >> 2, kq = tid & 3;
    int wk = tid >> 4, wc = (tid & 15) * 4;
    for (int k0 = 0; k0 < K; k0 += 16) {
        float4 av = make_float4(0.f, 0.f, 0.f, 0.f);
        int arow = row0 + lrow;
        if (arow < M) av = *(const float4*)(A + (long)arow * K + k0 + kq * 4);
        As[kq * 4 + 0][lrow] = av.x;
        As[kq * 4 + 1][lrow] = av.y;
        As[kq * 4 + 2][lrow] = av.z;
        As[kq * 4 + 3][lrow] = av.w;
        float4 wv = *(const float4*)(W + (long)(k0 + wk) * Nc + col0 + wc);
        *(float4*)&Ws[wk][wc] = wv;
        __syncthreads();
        #pragma unroll
        for (int kk = 0; kk < 16; ++kk) {
            float a[4], b[4];
            #pragma unroll
            for (int i = 0; i < 4; ++i) a[i] = As[kk][ty * 4 + i];
            #pragma unroll
            for (int j = 0; j < 4; ++j) b[j] = Ws[kk][tx * 4 + j];
            #pragma unroll
            for (int i = 0; i < 4; ++i)
                #pragma unroll
                for (int j = 0; j < 4; ++j) acc[i][j] += a[i] * b[j];
        }
        __syncthreads();
    }
    #pragma unroll
    for (int i = 0; i < 4; ++i) {
        int r = row0 + ty * 4 + i;
        if (r >= M) break;
        #pragma unroll
        for (int j = 0; j < 4; ++j) {
            int c = col0 + tx * 4 + j;
            float v = acc[i][j];
            if (bias) v += bias[c];
            C[(long)r * Nc + c] = v;
            if (Cbf) Cbf[(long)r * Nc + c] = f2bf(v);
        }
    }
}

// ---------------- bf16 MFMA GEMM, z-batched experts, swizzled LDS ----------------
// C[z] = [relu]( sum_halves A_half[z](bf16) @ B[z]^T + [bias[z]] ); B fused (Nc=256, Kb) bf16 hi/lo.
// A bf16 2-product (a*bh + a*bl). 128x128 tile, BK=32, 4 waves 2x2, 4x4 frags of 16x16x32.
// Element strides. LDS add-rotate swizzle on 4x16B chunks -> <=2-way bank aliasing (verified R6).
template<int NH>
__global__ __launch_bounds__(256)
void gemm_bf_kernel(const ushort_t* __restrict__ A1, long sA1z,
                    const ushort_t* __restrict__ A2, long sA2z,
                    const ushort_t* __restrict__ Bh, const ushort_t* __restrict__ Bl, long sBz,
                    const float* __restrict__ bias, int sBiasz,
                    ushort_t* __restrict__ Cbf, long sCz,
                    int M, int Nc, int Kb, int relu) {
    __shared__ alignas(16) ushort_t Asl[128 * 32];
    __shared__ alignas(16) ushort_t Bhs[128 * 32];
    __shared__ alignas(16) ushort_t Bls[128 * 32];

    const int tid = threadIdx.x, wave = tid >> 6, lane = tid & 63;
    const int z = blockIdx.z;
    const int row0 = blockIdx.x * 128, col0 = blockIdx.y * 128;
    const int wr = (wave >> 1) * 64, wcx = (wave & 1) * 64;
    floatx4 acc[4][4] = {};

    A1 += (long)z * sA1z;
    A2 += (long)z * sA2z;
    Bh += (long)z * sBz; Bl += (long)z * sBz;
    if (bias) bias += (long)z * sBiasz;
    Cbf += (long)z * sCz;

    // bf16 staging map: 4 lanes/row (4x16B chunks), add-rotate swizzle
    const int bsr = lane >> 2;                    // row in group of 16
    const int bgc = ((lane & 3) - (bsr >> 1)) & 3;
    long aoff_b[2];
    #pragma unroll
    for (int q = 0; q < 2; ++q) {
        int ar = row0 + wave * 32 + q * 16 + bsr;
        ar = ar < M ? ar : M - 1;
        aoff_b[q] = (long)ar * 256 + bgc * 8;
    }
    const long brow = (long)(col0 + wave * 32 + bsr) * Kb + bgc * 8;
    const ushort_t* Bhg0 = Bh + brow;
    const ushort_t* Bhg1 = Bh + brow + (long)16 * Kb;
    const ushort_t* Blg0 = Bl + brow;
    const ushort_t* Blg1 = Bl + brow + (long)16 * Kb;
    ushort_t* Al0  = &Asl[(wave * 32) * 32];
    ushort_t* Al1  = &Asl[(wave * 32 + 16) * 32];
    ushort_t* Bhl0 = &Bhs[(wave * 32) * 32];
    ushort_t* Bhl1 = &Bhs[(wave * 32 + 16) * 32];
    ushort_t* Bll0 = &Bls[(wave * 32) * 32];
    ushort_t* Bll1 = &Bls[(wave * 32 + 16) * 32];

    const int fm = lane & 15, fq = lane >> 4;

    #pragma unroll
    for (int half = 0; half < NH; ++half) {
        const ushort_t* Ab = (half == 0) ? A1 : A2;
        for (int k0 = 0; k0 < 256; k0 += 32) {
            const int kk = half * 256 + k0;
            load16_lds(Ab + aoff_b[0] + k0, Al0);
            load16_lds(Ab + aoff_b[1] + k0, Al1);
            load16_lds(Bhg0 + kk, Bhl0);
            load16_lds(Bhg1 + kk, Bhl1);
            load16_lds(Blg0 + kk, Bll0);
            load16_lds(Blg1 + kk, Bll1);
            __syncthreads();

            short8 a[4], bh[4], bl[4];
            #pragma unroll
            for (int j = 0; j < 4; ++j) {
                int row = wcx + j * 16 + fm;
                int slot = (fq + ((row >> 1) & 3)) & 3;
                bh[j] = *(const short8*)&Bhs[row * 32 + slot * 8];
                bl[j] = *(const short8*)&Bls[row * 32 + slot * 8];
            }
            #pragma unroll
            for (int i = 0; i < 4; ++i) {
                int row = wr + i * 16 + fm;
                int slot = (fq + ((row >> 1) & 3)) & 3;
                a[i] = *(const short8*)&Asl[row * 32 + slot * 8];
            }
            #pragma unroll
            for (int i = 0; i < 4; ++i)
                #pragma unroll
                for (int j = 0; j < 4; ++j) {
                    acc[i][j] = __builtin_amdgcn_mfma_f32_16x16x32_bf16(a[i], bl[j], acc[i][j], 0, 0, 0);
                    acc[i][j] = __builtin_amdgcn_mfma_f32_16x16x32_bf16(a[i], bh[j], acc[i][j], 0, 0, 0);
                }
            __syncthreads();
        }
    }

    // epilogue: C/D layout col=lane&15, row=(lane>>4)*4+reg  [verified m89]
    #pragma unroll
    for (int i = 0; i < 4; ++i) {
        #pragma unroll
        for (int j = 0; j < 4; ++j) {
            int col = col0 + wcx + j * 16 + fm;
            int rowb = row0 + wr + i * 16 + fq * 4;
            #pragma unroll
            for (int r = 0; r < 4; ++r) {
                int row = rowb + r;
                if (row < M) {
                    float v = acc[i][j][r];
                    if (bias) v += bias[col];
                    if (relu) v = fmaxf(v, 0.f);
                    Cbf[(long)row * Nc + col] = f2bf(v);
                }
            }
        }
    }
}

// ---------------- graph-stat histograms ----------------
__global__ void hist_nodes_kernel(const int* __restrict__ batch, int n, int* __restrict__ gn) {
    __shared__ int bins[G_DIM];
    int t = threadIdx.x;
    if (t < G_DIM) bins[t] = 0;
    __syncthreads();
    for (long i = (long)blockIdx.x * blockDim.x + t; i < n; i += (long)gridDim.x * blockDim.x)
        atomicAdd(&bins[batch[i]], 1);
    __syncthreads();
    if (t < G_DIM) atomicAdd(&gn[t], bins[t]);
}

__global__ void hist_edges_kernel(const int* __restrict__ ei, const int* __restrict__ batch,
                                  int E, int* __restrict__ ge) {
    __shared__ int bins[G_DIM];
    int t = threadIdx.x;
    if (t < G_DIM) bins[t] = 0;
    __syncthreads();
    for (long i = (long)blockIdx.x * blockDim.x + t; i < E; i += (long)gridDim.x * blockDim.x)
        atomicAdd(&bins[batch[ei[i]]], 1);
    __syncthreads();
    if (t < G_DIM) atomicAdd(&ge[t], bins[t]);
}

// ---------------- graph stats ----------------
__global__ void graph_stats_kernel(const int* __restrict__ gn, const int* __restrict__ ge,
                                   float* __restrict__ feats_norm, float* __restrict__ logn_norm) {
    int g = threadIdx.x;
    float nv = fmaxf((float)gn[g], 1.0f);
    float ev = (float)ge[g];
    float density = ev / fmaxf(nv * (nv - 1.0f), 1.0f);
    float logn = logf(nv);
    float mn = logn, mx = logn;
    for (int o = 32; o; o >>= 1) {
        mn = fminf(mn, __shfl_xor(mn, o));
        mx = fmaxf(mx, __shfl_xor(mx, o));
    }
    logn_norm[g] = (logn - mn) / (mx - mn + 1e-6f);
    float f[3] = {nv, ev, density};
    #pragma unroll
    for (int c = 0; c < 3; ++c) {
        float s = f[c];
        for (int o = 32; o; o >>= 1) s += __shfl_xor(s, o);
        float mean = s / 64.f;
        float d = f[c] - mean;
        float v = d * d;
        for (int o = 32; o; o >>= 1) v += __shfl_xor(v, o);
        float stdv = sqrtf(v / 64.f);
        feats_norm[g * 3 + c] = d / (stdv + 1e-6f);
    }
}

// ---------------- router epilogue (verified) ----------------
__global__ __launch_bounds__(256)
void router_epi_kernel(const float* __restrict__ t, const int* __restrict__ batch,
                       const float* __restrict__ feats_norm, const float* __restrict__ logn_norm,
                       const float* __restrict__ rW1, const float* __restrict__ rb1,
                       const float* __restrict__ lng, const float* __restrict__ lnb,
                       const float* __restrict__ rW2, const float* __restrict__ rb2,
                       const float* __restrict__ centers, float* __restrict__ w, int N) {
    int wave = threadIdx.x >> 6, lane = threadIdx.x & 63;
    int n = blockIdx.x * 4 + wave;
    if (n >= N) return;
    int g = batch[n];
    float sf0 = feats_norm[g * 3 + 0], sf1 = feats_norm[g * 3 + 1], sf2 = feats_norm[g * 3 + 2];
    float ln = logn_norm[g];
    float tv[4];
    #pragma unroll
    for (int q = 0; q < 4; ++q) {
        int j = lane + 64 * q;
        tv[q] = t[(long)n * H_DIM + j] + rb1[j]
              + sf0 * rW1[256 * H_DIM + j] + sf1 * rW1[257 * H_DIM + j] + sf2 * rW1[258 * H_DIM + j];
    }
    float s = tv[0] + tv[1] + tv[2] + tv[3];
    for (int o = 32; o; o >>= 1) s += __shfl_xor(s, o);
    float mean = s / 256.f;
    float vs = 0.f;
    #pragma unroll
    for (int q = 0; q < 4; ++q) { float d = tv[q] - mean; vs += d * d; }
    for (int o = 32; o; o >>= 1) vs += __shfl_xor(vs, o);
    float rstd = rsqrtf(vs / 256.f + 1e-5f);
    float le[NEXP] = {0.f, 0.f, 0.f, 0.f};
    #pragma unroll
    for (int q = 0; q < 4; ++q) {
        int j = lane + 64 * q;
        float y = (tv[q] - mean) * rstd * lng[j] + lnb[j];
        y = fmaxf(y, 0.f);
        #pragma unroll
        for (int e = 0; e < NEXP; ++e) le[e] += y * rW2[j * NEXP + e];
    }
    #pragma unroll
    for (int e = 0; e < NEXP; ++e)
        for (int o = 32; o; o >>= 1) le[e] += __shfl_xor(le[e], o);
    if (lane == 0) {
        float p[NEXP];
        float m = -1e30f;
        #pragma unroll
        for (int e = 0; e < NEXP; ++e) {
            float d = ln - centers[e];
            float lv = 0.7f * (le[e] + rb2[e]) + 0.3f * (-(d * d));
            p[e] = lv;
            m = fmaxf(m, lv);
        }
        float ssum = 0.f;
        #pragma unroll
        for (int e = 0; e < NEXP; ++e) { p[e] = expf(p[e] - m); ssum += p[e]; }
        #pragma unroll
        for (int e = 0; e < NEXP; ++e) p[e] /= ssum;
        int i1 = 0;
        for (int e = 1; e < NEXP; ++e) if (p[e] > p[i1]) i1 = e;
        int i2 = -1;
        for (int e = 0; e < NEXP; ++e) { if (e == i1) continue; if (i2 < 0 || p[e] > p[i2]) i2 = e; }
        float denom = p[i1] + p[i2] + 1e-8f;
        float out4[NEXP] = {0.f, 0.f, 0.f, 0.f};
        out4[i1] = p[i1] / denom;
        out4[i2] = p[i2] / denom;
        #pragma unroll
        for (int e = 0; e < NEXP; ++e) w[(long)n * NEXP + e] = out4[e];
    }
}

// ---------------- CSR build ----------------
__global__ void count_dst_kernel(const int* __restrict__ ei, int E, int* __restrict__ cnt) {
    int i = blockIdx.x * blockDim.x + threadIdx.x;
    if (i < E) atomicAdd(&cnt[ei[E + i]], 1);
}

__global__ __launch_bounds__(1024)
void scan_kernel(const int* __restrict__ cnt, int* __restrict__ row_ptr, int n) {
    __shared__ int buf[1024];
    __shared__ int carry_s;
    int tid = threadIdx.x;
    if (tid == 0) carry_s = 0;
    __syncthreads();
    for (int base = 0; base < n; base += 1024) {
        int v = (base + tid < n) ? cnt[base + tid] : 0;
        buf[tid] = v;
        __syncthreads();
        for (int off = 1; off < 1024; off <<= 1) {
            int tv = (tid >= off) ? buf[tid - off] : 0;
            __syncthreads();
            buf[tid] += tv;
            __syncthreads();
        }
        int carry = carry_s;
        if (base + tid < n) row_ptr[base + tid] = carry + buf[tid] - v;
        __syncthreads();
        if (tid == 1023) carry_s = carry + buf[1023];
        __syncthreads();
    }
    if (tid == 0) row_ptr[n] = carry_s;
}

__global__ void fill_csr_kernel(const int* __restrict__ ei, int E, const int* __restrict__ row_ptr,
                                int* __restrict__ fillc, int* __restrict__ srcs) {
    int i = blockIdx.x * blockDim.x + threadIdx.x;
    if (i < E) {
        int d = ei[E + i];
        int pos = row_ptr[d] + atomicAdd(&fillc[d], 1);
        srcs[pos] = ei[i];
    }
}

// ---------------- CSR gather bf16->bf16 (fp32 accum), z via grid.y, edge-unrolled x2 ----------------
__global__ __launch_bounds__(256)
void agg_b2b_kernel(const ushort_t* __restrict__ feat, ushort_t* __restrict__ outp,
                    const int* __restrict__ rp, const int* __restrict__ srcs, int N) {
    long zoff = (long)blockIdx.y * N * H_DIM;
    int wave = threadIdx.x >> 6, lane = threadIdx.x & 63;
    int n = blockIdx.x * 4 + wave;
    if (n >= N) return;
    float a0 = 0.f, a1 = 0.f, a2 = 0.f, a3 = 0.f;
    int p0 = rp[n], p1 = rp[n + 1];
    const ushort_t* base = feat + zoff + lane * 4;
    int p = p0;
    for (; p + 1 < p1; p += 2) {
        long s0 = (long)srcs[p] * H_DIM;
        long s1 = (long)srcs[p + 1] * H_DIM;
        uint2 v0 = *(const uint2*)(base + s0);
        uint2 v1 = *(const uint2*)(base + s1);
        a0 += bf2f((ushort_t)(v0.x & 0xffff)) + bf2f((ushort_t)(v1.x & 0xffff));
        a1 += bf2f((ushort_t)(v0.x >> 16))    + bf2f((ushort_t)(v1.x >> 16));
        a2 += bf2f((ushort_t)(v0.y & 0xffff)) + bf2f((ushort_t)(v1.y & 0xffff));
        a3 += bf2f((ushort_t)(v0.y >> 16))    + bf2f((ushort_t)(v1.y >> 16));
    }
    if (p < p1) {
        long s = (long)srcs[p] * H_DIM;
        uint2 v = *(const uint2*)(base + s);
        a0 += bf2f((ushort_t)(v.x & 0xffff));
        a1 += bf2f((ushort_t)(v.x >> 16));
        a2 += bf2f((ushort_t)(v.y & 0xffff));
        a3 += bf2f((ushort_t)(v.y >> 16));
    }
    uint2 o;
    o.x = (uint_t)f2bf(a0) | ((uint_t)f2bf(a1) << 16);
    o.y = (uint_t)f2bf(a2) | ((uint_t)f2bf(a3) << 16);
    *(uint2*)(outp + zoff + (long)n * H_DIM + lane * 4) = o;
}

// ---------------- final mix, EB experts per dispatch (<=2 active per node) ----------------
// PR[z]: (N,256) bf16, cols 0..127 = P, 128..255 = R;  out (+)= sum_z w[n,e0+z]*(Agg(P)+R+b2)
__global__ __launch_bounds__(256)
void final_mixE_kernel(const ushort_t* __restrict__ PR, const float* __restrict__ b2,
                       const float* __restrict__ wts, int e0, int EB,
                       const int* __restrict__ rp, const int* __restrict__ srcs,
                       float* __restrict__ out, int N, int init) {
    int wave = threadIdx.x >> 6, lane = threadIdx.x & 63;
    int n = blockIdx.x * 4 + wave;
    if (n >= N) return;
    int c0 = lane * 2;
    long obase = (long)n * O_DIM + c0;
    float o0 = init ? 0.f : out[obase];
    float o1 = init ? 0.f : out[obase + 1];
    int zs[2]; float wv[2]; int na = 0;
    for (int z = 0; z < EB; ++z) {
        float w = wts[(long)n * NEXP + e0 + z];
        if (w != 0.f && na < 2) { zs[na] = z; wv[na] = w; ++na; }
    }
    if (na) {
        const ushort_t* P0 = PR + (long)zs[0] * N * 256 + c0;
        const ushort_t* P1 = PR + (long)zs[na - 1] * N * 256 + c0;
        float a00 = 0.f, a01 = 0.f, a10 = 0.f, a11 = 0.f;
        int p0 = rp[n], p1 = rp[n + 1];
        if (na == 2) {
            for (int p = p0; p < p1; ++p) {
                long s = (long)srcs[p] * 256;
                uint_t v0 = *(const uint_t*)(P0 + s);
                uint_t v1 = *(const uint_t*)(P1 + s);
                a00 += bf2f((ushort_t)(v0 & 0xffff)); a01 += bf2f((ushort_t)(v0 >> 16));
                a10 += bf2f((ushort_t)(v1 & 0xffff)); a11 += bf2f((ushort_t)(v1 >> 16));
            }
        } else {
            int p = p0;
            for (; p + 1 < p1; p += 2) {
                long s0 = (long)srcs[p] * 256;
                long s1 = (long)srcs[p + 1] * 256;
                uint_t v0 = *(const uint_t*)(P0 + s0);
                uint_t v1 = *(const uint_t*)(P0 + s1);
                a00 += bf2f((ushort_t)(v0 & 0xffff)) + bf2f((ushort_t)(v1 & 0xffff));
                a01 += bf2f((ushort_t)(v0 >> 16))    + bf2f((ushort_t)(v1 >> 16));
            }
            if (p < p1) {
                long s = (long)srcs[p] * 256;
                uint_t v = *(const uint_t*)(P0 + s);
                a00 += bf2f((ushort_t)(v & 0xffff)); a01 += bf2f((ushort_t)(v >> 16));
            }
        }
        {
            int e = e0 + zs[0];
            uint_t rv = *(const uint_t*)(PR + (long)zs[0] * N * 256 + (long)n * 256 + 128 + c0);
            o0 += wv[0] * (a00 + bf2f((ushort_t)(rv & 0xffff)) + b2[e * O_DIM + c0]);
            o1 += wv[0] * (a01 + bf2f((ushort_t)(rv >> 16))    + b2[e * O_DIM + c0 + 1]);
        }
        if (na == 2) {
            int e = e0 + zs[1];
            uint_t rv = *(const uint_t*)(PR + (long)zs[1] * N * 256 + (long)n * 256 + 128 + c0);
            o0 += wv[1] * (a10 + bf2f((ushort_t)(rv & 0xffff)) + b2[e * O_DIM + c0]);
            o1 += wv[1] * (a11 + bf2f((ushort_t)(rv >> 16))    + b2[e * O_DIM + c0 + 1]);
        }
    }
    out[obase] = o0;
    out[obase + 1] = o1;
}

// ==================== host launcher ====================
extern "C" void kernel_launch(void* const* d_in, const int* in_sizes, int n_in,
                              void* d_out, int out_size, void* d_ws, size_t ws_size,
                              hipStream_t stream) {
    const float* x       = (const float*)d_in[0];
    const int*   ei      = (const int*)  d_in[1];
    const int*   batch   = (const int*)  d_in[2];
    const float* enc_W1  = (const float*)d_in[3];
    const float* enc_b1  = (const float*)d_in[4];
    const float* enc_W2  = (const float*)d_in[5];
    const float* enc_b2  = (const float*)d_in[6];
    const float* r_W1    = (const float*)d_in[7];
    const float* r_b1    = (const float*)d_in[8];
    const float* ln_g    = (const float*)d_in[9];
    const float* ln_b    = (const float*)d_in[10];
    const float* r_W2    = (const float*)d_in[11];
    const float* r_b2    = (const float*)d_in[12];
    const float* centers = (const float*)d_in[13];
    const float* W0_rel  = (const float*)d_in[14];
    const float* b0_rel  = (const float*)d_in[15];
    const float* W0_root = (const float*)d_in[16];
    const float* W1_rel  = (const float*)d_in[17];
    const float* b1_rel  = (const float*)d_in[18];
    const float* W1_root = (const float*)d_in[19];
    const float* W2_rel  = (const float*)d_in[20];
    const float* b2_rel  = (const float*)d_in[21];
    const float* W2_root = (const float*)d_in[22];

    const int N = in_sizes[2];
    const int E = in_sizes[1] / 2;
    const int F = in_sizes[0] / N;

    // ---- workspace layout (256B-aligned slabs) ----
    char* ws = (char*)d_ws;
    size_t off = 0;
    auto alloc = [&](size_t bytes) -> void* {
        void* p = ws + off;
        off += (bytes + 255) & ~(size_t)255;
        return p;
    };
    int* cnt      = (int*)alloc((size_t)N * 4);
    int* fillc    = (int*)alloc((size_t)N * 4);
    int* gn       = (int*)alloc((size_t)G_DIM * 4);
    int* ge       = (int*)alloc((size_t)G_DIM * 4);
    size_t zero_bytes = off;
    int* row_ptr  = (int*)alloc((size_t)(N + 1) * 4);
    int* srcs     = (int*)alloc((size_t)E * 4);
    float* feats_norm = (float*)alloc((size_t)G_DIM * 3 * 4);
    float* logn_norm  = (float*)alloc((size_t)G_DIM * 4);
    float* wts    = (float*)alloc((size_t)N * NEXP * 4);
    // fused bf16 hi/lo weights
    ushort_t* wf0_h  = (ushort_t*)alloc((size_t)NEXP * 131072 * 2);
    ushort_t* wf0_l  = (ushort_t*)alloc((size_t)NEXP * 131072 * 2);
    ushort_t* wf1_h  = (ushort_t*)alloc((size_t)NEXP * 131072 * 2);
    ushort_t* wf1_l  = (ushort_t*)alloc((size_t)NEXP * 131072 * 2);
    ushort_t* wfin_h = (ushort_t*)alloc((size_t)NEXP * 65536 * 2);
    ushort_t* wfin_l = (ushort_t*)alloc((size_t)NEXP * 65536 * 2);
    // persistent bf16 activations
    const long sE = (long)N * H_DIM;               // elements per expert slab
    ushort_t* h_bf    = (ushort_t*)alloc((size_t)sE * 2);
    ushort_t* aggh_bf = (ushort_t*)alloc((size_t)sE * 2);
    // adaptive expert batch: 4 if workspace allows, else 2 (proven footprint)
    size_t fixed_end = off;
    size_t slab4 = ((size_t)4 * sE * 2 + 255) & ~(size_t)255;
    int EB = (ws_size >= fixed_end + 3 * slab4 + (1u << 20)) ? 4 : 2;
    size_t slab = ((size_t)EB * sE * 2 + 255) & ~(size_t)255;
    ushort_t* S1 = (ushort_t*)alloc(slab);   // u(fp32) -> hE0
    ushort_t* S2 = (ushort_t*)alloc(slab);   // h(fp32) -> aggE -> PR
    ushort_t* S3 = (ushort_t*)alloc(slab);   // t(fp32) -> hE1
    (void)out_size; (void)n_in;

    float* u    = (float*)S1;
    float* h    = (float*)S2;
    float* tf32 = (float*)S3;
    ushort_t* hE0  = S1;
    ushort_t* aggE = S2;
    ushort_t* hE1  = S3;
    ushort_t* PR   = S2;
    float* out = (float*)d_out;

    dim3 blk256(256);
    dim3 gR((N + 63) / 64, H_DIM / 64, 1);         // fp32 SGEMM grid (router path)
    dim3 gM((N + 127) / 128, 2, EB);               // MFMA grid
    dim3 gAgg((N + 3) / 4);
    dim3 gAggE((N + 3) / 4, EB);

    // 0) zero counters
    {
        long nz = (long)(zero_bytes / 4);
        zero_i_kernel<<<dim3((nz + 255) / 256), blk256, 0, stream>>>((int*)ws, nz);
    }
    // 0b) fused weight prep
    wsplit2_kernel<<<dim3(512, NEXP), blk256, 0, stream>>>(W0_rel, W0_root, wf0_h, wf0_l);
    wsplit2_kernel<<<dim3(512, NEXP), blk256, 0, stream>>>(W1_rel, W1_root, wf1_h, wf1_l);
    wsplitcat_kernel<<<dim3(256, NEXP), blk256, 0, stream>>>(W2_rel, W2_root, wfin_h, wfin_l);
    // 1) encoder stage 1 -> u
    encoder1_kernel<<<dim3(N), blk256, 0, stream>>>(x, enc_W1, enc_b1, u, N, F);
    // 2) h = u @ enc_W2 + enc_b2 (fp32 SGEMM + bf16 shadow)
    gemm256_kernel<<<gR, blk256, 0, stream>>>(u, enc_W2, enc_b2, h, h_bf, N, H_DIM);
    // 3-5) graph stats
    hist_nodes_kernel<<<dim3(256), blk256, 0, stream>>>(batch, N, gn);
    hist_edges_kernel<<<dim3(512), blk256, 0, stream>>>(ei, batch, E, ge);
    graph_stats_kernel<<<dim3(1), dim3(64), 0, stream>>>(gn, ge, feats_norm, logn_norm);
    // 6) t = h @ r_W1[0:256,:] (fp32 SGEMM)
    gemm256_kernel<<<gR, blk256, 0, stream>>>(h, r_W1, nullptr, tf32, nullptr, N, H_DIM);
    // 7) router epilogue -> wts
    router_epi_kernel<<<dim3((N + 3) / 4), blk256, 0, stream>>>(
        tf32, batch, feats_norm, logn_norm, r_W1, r_b1, ln_g, ln_b, r_W2, r_b2, centers, wts, N);
    // 8-10) CSR build
    count_dst_kernel<<<dim3((E + 255) / 256), blk256, 0, stream>>>(ei, E, cnt);
    scan_kernel<<<dim3(1), dim3(1024), 0, stream>>>(cnt, row_ptr, N);
    fill_csr_kernel<<<dim3((E + 255) / 256), blk256, 0, stream>>>(ei, E, row_ptr, fillc, srcs);
    // 11) agg_h = Agg(h_bf)
    agg_b2b_kernel<<<gAgg, blk256, 0, stream>>>(h_bf, aggh_bf, row_ptr, srcs, N);

    // ---- expert pipeline, EB experts per dispatch ----
    for (int b = 0; b < NEXP / EB; ++b) {
        const int e0 = b * EB;
        // hE0[z] = relu([agg_h | h] @ [W0_rel;W0_root]^T + b0)   (A shared across z)
        gemm_bf_kernel<2><<<gM, blk256, 0, stream>>>(
            aggh_bf, 0, h_bf, 0,
            wf0_h + (long)e0 * 131072, wf0_l + (long)e0 * 131072, 131072,
            b0_rel + e0 * H_DIM, H_DIM, hE0, sE, N, 256, 512, 1);
        // aggE[z] = Agg(hE0[z])
        agg_b2b_kernel<<<gAggE, blk256, 0, stream>>>(hE0, aggE, row_ptr, srcs, N);
        // hE1[z] = relu([aggE | hE0] @ [W1_rel;W1_root]^T + b1)
        gemm_bf_kernel<2><<<gM, blk256, 0, stream>>>(
            aggE, sE, hE0, sE,
            wf1_h + (long)e0 * 131072, wf1_l + (long)e0 * 131072, 131072,
            b1_rel + e0 * H_DIM, H_DIM, hE1, sE, N, 256, 512, 1);
        // PR[z] = hE1 @ [W2_rel|W2_root]^T   (overlay onto dead aggE)
        gemm_bf_kernel<1><<<gM, blk256, 0, stream>>>(
            hE1, sE, nullptr, 0,
            wfin_h + (long)e0 * 65536, wfin_l + (long)e0 * 65536, 65536,
            nullptr, 0, PR, sE, N, 256, 256, 0);
        // out (+)= sum_z w[:,e0+z] * (Agg(P[z]) + R[z] + b2[e0+z])
        final_mixE_kernel<<<gAgg, blk256, 0, stream>>>(
            PR, b2_rel, wts, e0, EB, row_ptr, srcs, out, N, b == 0 ? 1 : 0);
    }
}

// Round 8
// 1528.084 us; speedup vs baseline: 2.7050x; 1.0459x over previous
//
#include <hip/hip_runtime.h>
#include <hip/hip_bf16.h>

// ---------------- problem constants ----------------
#define H_DIM 256
#define O_DIM 128
#define NEXP 4
#define G_DIM 64

typedef unsigned short ushort_t;
typedef unsigned int uint_t;
typedef __attribute__((ext_vector_type(8))) short short8;
typedef __attribute__((ext_vector_type(4))) float floatx4;

// ---------------- bf16 helpers (RNE) ----------------
__device__ __forceinline__ float bf2f(ushort_t u) {
    union { uint_t i; float f; } c; c.i = ((uint_t)u) << 16; return c.f;
}
__device__ __forceinline__ ushort_t f2bf(float f) {
    union { float f; uint_t i; } c; c.f = f;
    uint_t x = c.i;
    uint_t r = (x + 0x7fffu + ((x >> 16) & 1u)) >> 16;
    return (ushort_t)r;
}

// ---------------- async global->LDS 16B ----------------
__device__ __forceinline__ void load16_lds(const void* g, void* l) {
    __builtin_amdgcn_global_load_lds(
        (const __attribute__((address_space(1))) unsigned int*)g,
        (__attribute__((address_space(3))) unsigned int*)l, 16, 0, 0);
}

// ---------------- utility: zero ints ----------------
__global__ void zero_i_kernel(int* __restrict__ p, long n) {
    long i = (long)blockIdx.x * blockDim.x + threadIdx.x;
    if (i < n) p[i] = 0;
}

// ---------------- fused weight prep ----------------
__global__ void wsplit2_kernel(const float* __restrict__ Wa, const float* __restrict__ Wb,
                               ushort_t* __restrict__ Wh, ushort_t* __restrict__ Wl) {
    int z = blockIdx.y;
    int i = blockIdx.x * 256 + threadIdx.x;        // 256n * 512k
    if (i >= 131072) return;
    int nn = i >> 9, kk = i & 511;
    float v = (kk < 256) ? Wa[(long)z * 65536 + kk * 256 + nn]
                         : Wb[(long)z * 65536 + (kk - 256) * 256 + nn];
    ushort_t hi = f2bf(v);
    long o = (long)z * 131072 + i;
    Wh[o] = hi; Wl[o] = f2bf(v - bf2f(hi));
}

__global__ void wsplitcat_kernel(const float* __restrict__ Wa, const float* __restrict__ Wb,
                                 ushort_t* __restrict__ Wh, ushort_t* __restrict__ Wl) {
    int z = blockIdx.y;
    int i = blockIdx.x * 256 + threadIdx.x;        // 256n * 256k
    if (i >= 65536) return;
    int nn = i >> 8, kk = i & 255;
    float v = (nn < 128) ? Wa[(long)z * 32768 + kk * 128 + nn]
                         : Wb[(long)z * 32768 + kk * 128 + (nn - 128)];
    ushort_t hi = f2bf(v);
    long o = (long)z * 65536 + i;
    Wh[o] = hi; Wl[o] = f2bf(v - bf2f(hi));
}

// ---------------- encoder stage 1 (fp32, verified) ----------------
__global__ void encoder1_kernel(const float* __restrict__ x, const float* __restrict__ W1,
                                const float* __restrict__ b1, float* __restrict__ u,
                                int N, int F) {
    int n = blockIdx.x;
    int j = threadIdx.x;
    float acc = b1[j];
    #pragma unroll
    for (int c = 0; c < 6; ++c)
        acc += x[(long)n * F + 4 + c] * W1[c * H_DIM + j];
    u[(long)n * H_DIM + j] = fmaxf(acc, 0.f);
}

// ---------------- fp32 vector SGEMM (router path — DO NOT CHANGE: top-2 flip risk) ----------------
__global__ __launch_bounds__(256)
void gemm256_kernel(const float* __restrict__ A, const float* __restrict__ W,
                    const float* __restrict__ bias, float* __restrict__ C,
                    ushort_t* __restrict__ Cbf, int M, int Nc) {
    const int K = 256;
    __shared__ float As[16][68];
    __shared__ float Ws[16][68];
    int tid = threadIdx.x;
    int tx = tid & 15, ty = tid >> 4;
    int row0 = blockIdx.x * 64;
    int col0 = blockIdx.y * 64;
    float acc[4][4] = {};
    int lrow = tid >> 2, kq = tid & 3;
    int wk = tid >> 4, wc = (tid & 15) * 4;
    for (int k0 = 0; k0 < K; k0 += 16) {
        float4 av = make_float4(0.f, 0.f, 0.f, 0.f);
        int arow = row0 + lrow;
        if (arow < M) av = *(const float4*)(A + (long)arow * K + k0 + kq * 4);
        As[kq * 4 + 0][lrow] = av.x;
        As[kq * 4 + 1][lrow] = av.y;
        As[kq * 4 + 2][lrow] = av.z;
        As[kq * 4 + 3][lrow] = av.w;
        float4 wv = *(const float4*)(W + (long)(k0 + wk) * Nc + col0 + wc);
        *(float4*)&Ws[wk][wc] = wv;
        __syncthreads();
        #pragma unroll
        for (int kk = 0; kk < 16; ++kk) {
            float a[4], b[4];
            #pragma unroll
            for (int i = 0; i < 4; ++i) a[i] = As[kk][ty * 4 + i];
            #pragma unroll
            for (int j = 0; j < 4; ++j) b[j] = Ws[kk][tx * 4 + j];
            #pragma unroll
            for (int i = 0; i < 4; ++i)
                #pragma unroll
                for (int j = 0; j < 4; ++j) acc[i][j] += a[i] * b[j];
        }
        __syncthreads();
    }
    #pragma unroll
    for (int i = 0; i < 4; ++i) {
        int r = row0 + ty * 4 + i;
        if (r >= M) break;
        #pragma unroll
        for (int j = 0; j < 4; ++j) {
            int c = col0 + tx * 4 + j;
            float v = acc[i][j];
            if (bias) v += bias[c];
            C[(long)r * Nc + c] = v;
            if (Cbf) Cbf[(long)r * Nc + c] = f2bf(v);
        }
    }
}

// ---------------- bf16 MFMA GEMM, z-batched experts, swizzled LDS, strided A/C ----------------
// C[z] = [relu]( sum_halves A_half[z](bf16) @ B[z]^T + [bias[z]] ); B fused (Nc=256, Kb) bf16 hi/lo.
// A row stride rsA* elements (256 for flat, EB*256 for [n][z][h] interleave); per-z A offset sA*z.
// C row stride rsC, per-z offset sCz. MFMA core + add-rotate LDS swizzle verified R6/R7.
template<int NH>
__global__ __launch_bounds__(256)
void gemm_bf_kernel(const ushort_t* __restrict__ A1, long sA1z, int rsA1,
                    const ushort_t* __restrict__ A2, long sA2z, int rsA2,
                    const ushort_t* __restrict__ Bh, const ushort_t* __restrict__ Bl, long sBz,
                    const float* __restrict__ bias, int sBiasz,
                    ushort_t* __restrict__ Cbf, long sCz, int rsC,
                    int M, int Kb, int relu) {
    __shared__ alignas(16) ushort_t Asl[128 * 32];
    __shared__ alignas(16) ushort_t Bhs[128 * 32];
    __shared__ alignas(16) ushort_t Bls[128 * 32];

    const int tid = threadIdx.x, wave = tid >> 6, lane = tid & 63;
    const int z = blockIdx.z;
    const int row0 = blockIdx.x * 128, col0 = blockIdx.y * 128;
    const int wr = (wave >> 1) * 64, wcx = (wave & 1) * 64;
    floatx4 acc[4][4] = {};

    A1 += (long)z * sA1z;
    A2 += (long)z * sA2z;
    Bh += (long)z * sBz; Bl += (long)z * sBz;
    if (bias) bias += (long)z * sBiasz;
    Cbf += (long)z * sCz;

    // bf16 staging map: 4 lanes/row (4x16B chunks), add-rotate swizzle
    const int bsr = lane >> 2;                    // row in group of 16
    const int bgc = ((lane & 3) - (bsr >> 1)) & 3;
    long aoff1[2], aoff2[2];
    #pragma unroll
    for (int q = 0; q < 2; ++q) {
        int ar = row0 + wave * 32 + q * 16 + bsr;
        ar = ar < M ? ar : M - 1;
        aoff1[q] = (long)ar * rsA1 + bgc * 8;
        aoff2[q] = (long)ar * rsA2 + bgc * 8;
    }
    const long brow = (long)(col0 + wave * 32 + bsr) * Kb + bgc * 8;
    const ushort_t* Bhg0 = Bh + brow;
    const ushort_t* Bhg1 = Bh + brow + (long)16 * Kb;
    const ushort_t* Blg0 = Bl + brow;
    const ushort_t* Blg1 = Bl + brow + (long)16 * Kb;
    ushort_t* Al0  = &Asl[(wave * 32) * 32];
    ushort_t* Al1  = &Asl[(wave * 32 + 16) * 32];
    ushort_t* Bhl0 = &Bhs[(wave * 32) * 32];
    ushort_t* Bhl1 = &Bhs[(wave * 32 + 16) * 32];
    ushort_t* Bll0 = &Bls[(wave * 32) * 32];
    ushort_t* Bll1 = &Bls[(wave * 32 + 16) * 32];

    const int fm = lane & 15, fq = lane >> 4;

    #pragma unroll
    for (int half = 0; half < NH; ++half) {
        const ushort_t* Ab = (half == 0) ? A1 : A2;
        const long* aoff = (half == 0) ? aoff1 : aoff2;
        for (int k0 = 0; k0 < 256; k0 += 32) {
            const int kk = half * 256 + k0;
            load16_lds(Ab + aoff[0] + k0, Al0);
            load16_lds(Ab + aoff[1] + k0, Al1);
            load16_lds(Bhg0 + kk, Bhl0);
            load16_lds(Bhg1 + kk, Bhl1);
            load16_lds(Blg0 + kk, Bll0);
            load16_lds(Blg1 + kk, Bll1);
            __syncthreads();

            short8 a[4], bh[4], bl[4];
            #pragma unroll
            for (int j = 0; j < 4; ++j) {
                int row = wcx + j * 16 + fm;
                int slot = (fq + ((row >> 1) & 3)) & 3;
                bh[j] = *(const short8*)&Bhs[row * 32 + slot * 8];
                bl[j] = *(const short8*)&Bls[row * 32 + slot * 8];
            }
            #pragma unroll
            for (int i = 0; i < 4; ++i) {
                int row = wr + i * 16 + fm;
                int slot = (fq + ((row >> 1) & 3)) & 3;
                a[i] = *(const short8*)&Asl[row * 32 + slot * 8];
            }
            #pragma unroll
            for (int i = 0; i < 4; ++i)
                #pragma unroll
                for (int j = 0; j < 4; ++j) {
                    acc[i][j] = __builtin_amdgcn_mfma_f32_16x16x32_bf16(a[i], bl[j], acc[i][j], 0, 0, 0);
                    acc[i][j] = __builtin_amdgcn_mfma_f32_16x16x32_bf16(a[i], bh[j], acc[i][j], 0, 0, 0);
                }
            __syncthreads();
        }
    }

    // epilogue: C/D layout col=lane&15, row=(lane>>4)*4+reg  [verified m89]
    #pragma unroll
    for (int i = 0; i < 4; ++i) {
        #pragma unroll
        for (int j = 0; j < 4; ++j) {
            int col = col0 + wcx + j * 16 + fm;
            int rowb = row0 + wr + i * 16 + fq * 4;
            #pragma unroll
            for (int r = 0; r < 4; ++r) {
                int row = rowb + r;
                if (row < M) {
                    float v = acc[i][j][r];
                    if (bias) v += bias[col];
                    if (relu) v = fmaxf(v, 0.f);
                    Cbf[(long)row * rsC + col] = f2bf(v);
                }
            }
        }
    }
}

// ---------------- graph-stat histograms ----------------
__global__ void hist_nodes_kernel(const int* __restrict__ batch, int n, int* __restrict__ gn) {
    __shared__ int bins[G_DIM];
    int t = threadIdx.x;
    if (t < G_DIM) bins[t] = 0;
    __syncthreads();
    for (long i = (long)blockIdx.x * blockDim.x + t; i < n; i += (long)gridDim.x * blockDim.x)
        atomicAdd(&bins[batch[i]], 1);
    __syncthreads();
    if (t < G_DIM) atomicAdd(&gn[t], bins[t]);
}

__global__ void hist_edges_kernel(const int* __restrict__ ei, const int* __restrict__ batch,
                                  int E, int* __restrict__ ge) {
    __shared__ int bins[G_DIM];
    int t = threadIdx.x;
    if (t < G_DIM) bins[t] = 0;
    __syncthreads();
    for (long i = (long)blockIdx.x * blockDim.x + t; i < E; i += (long)gridDim.x * blockDim.x)
        atomicAdd(&bins[batch[ei[i]]], 1);
    __syncthreads();
    if (t < G_DIM) atomicAdd(&ge[t], bins[t]);
}

// ---------------- graph stats ----------------
__global__ void graph_stats_kernel(const int* __restrict__ gn, const int* __restrict__ ge,
                                   float* __restrict__ feats_norm, float* __restrict__ logn_norm) {
    int g = threadIdx.x;
    float nv = fmaxf((float)gn[g], 1.0f);
    float ev = (float)ge[g];
    float density = ev / fmaxf(nv * (nv - 1.0f), 1.0f);
    float logn = logf(nv);
    float mn = logn, mx = logn;
    for (int o = 32; o; o >>= 1) {
        mn = fminf(mn, __shfl_xor(mn, o));
        mx = fmaxf(mx, __shfl_xor(mx, o));
    }
    logn_norm[g] = (logn - mn) / (mx - mn + 1e-6f);
    float f[3] = {nv, ev, density};
    #pragma unroll
    for (int c = 0; c < 3; ++c) {
        float s = f[c];
        for (int o = 32; o; o >>= 1) s += __shfl_xor(s, o);
        float mean = s / 64.f;
        float d = f[c] - mean;
        float v = d * d;
        for (int o = 32; o; o >>= 1) v += __shfl_xor(v, o);
        float stdv = sqrtf(v / 64.f);
        feats_norm[g * 3 + c] = d / (stdv + 1e-6f);
    }
}

// ---------------- router epilogue (verified) ----------------
__global__ __launch_bounds__(256)
void router_epi_kernel(const float* __restrict__ t, const int* __restrict__ batch,
                       const float* __restrict__ feats_norm, const float* __restrict__ logn_norm,
                       const float* __restrict__ rW1, const float* __restrict__ rb1,
                       const float* __restrict__ lng, const float* __restrict__ lnb,
                       const float* __restrict__ rW2, const float* __restrict__ rb2,
                       const float* __restrict__ centers, float* __restrict__ w, int N) {
    int wave = threadIdx.x >> 6, lane = threadIdx.x & 63;
    int n = blockIdx.x * 4 + wave;
    if (n >= N) return;
    int g = batch[n];
    float sf0 = feats_norm[g * 3 + 0], sf1 = feats_norm[g * 3 + 1], sf2 = feats_norm[g * 3 + 2];
    float ln = logn_norm[g];
    float tv[4];
    #pragma unroll
    for (int q = 0; q < 4; ++q) {
        int j = lane + 64 * q;
        tv[q] = t[(long)n * H_DIM + j] + rb1[j]
              + sf0 * rW1[256 * H_DIM + j] + sf1 * rW1[257 * H_DIM + j] + sf2 * rW1[258 * H_DIM + j];
    }
    float s = tv[0] + tv[1] + tv[2] + tv[3];
    for (int o = 32; o; o >>= 1) s += __shfl_xor(s, o);
    float mean = s / 256.f;
    float vs = 0.f;
    #pragma unroll
    for (int q = 0; q < 4; ++q) { float d = tv[q] - mean; vs += d * d; }
    for (int o = 32; o; o >>= 1) vs += __shfl_xor(vs, o);
    float rstd = rsqrtf(vs / 256.f + 1e-5f);
    float le[NEXP] = {0.f, 0.f, 0.f, 0.f};
    #pragma unroll
    for (int q = 0; q < 4; ++q) {
        int j = lane + 64 * q;
        float y = (tv[q] - mean) * rstd * lng[j] + lnb[j];
        y = fmaxf(y, 0.f);
        #pragma unroll
        for (int e = 0; e < NEXP; ++e) le[e] += y * rW2[j * NEXP + e];
    }
    #pragma unroll
    for (int e = 0; e < NEXP; ++e)
        for (int o = 32; o; o >>= 1) le[e] += __shfl_xor(le[e], o);
    if (lane == 0) {
        float p[NEXP];
        float m = -1e30f;
        #pragma unroll
        for (int e = 0; e < NEXP; ++e) {
            float d = ln - centers[e];
            float lv = 0.7f * (le[e] + rb2[e]) + 0.3f * (-(d * d));
            p[e] = lv;
            m = fmaxf(m, lv);
        }
        float ssum = 0.f;
        #pragma unroll
        for (int e = 0; e < NEXP; ++e) { p[e] = expf(p[e] - m); ssum += p[e]; }
        #pragma unroll
        for (int e = 0; e < NEXP; ++e) p[e] /= ssum;
        int i1 = 0;
        for (int e = 1; e < NEXP; ++e) if (p[e] > p[i1]) i1 = e;
        int i2 = -1;
        for (int e = 0; e < NEXP; ++e) { if (e == i1) continue; if (i2 < 0 || p[e] > p[i2]) i2 = e; }
        float denom = p[i1] + p[i2] + 1e-8f;
        float out4[NEXP] = {0.f, 0.f, 0.f, 0.f};
        out4[i1] = p[i1] / denom;
        out4[i2] = p[i2] / denom;
        #pragma unroll
        for (int e = 0; e < NEXP; ++e) w[(long)n * NEXP + e] = out4[e];
    }
}

// ---------------- CSR build ----------------
__global__ void count_dst_kernel(const int* __restrict__ ei, int E, int* __restrict__ cnt) {
    int i = blockIdx.x * blockDim.x + threadIdx.x;
    if (i < E) atomicAdd(&cnt[ei[E + i]], 1);
}

__global__ __launch_bounds__(1024)
void scan_kernel(const int* __restrict__ cnt, int* __restrict__ row_ptr, int n) {
    __shared__ int buf[1024];
    __shared__ int carry_s;
    int tid = threadIdx.x;
    if (tid == 0) carry_s = 0;
    __syncthreads();
    for (int base = 0; base < n; base += 1024) {
        int v = (base + tid < n) ? cnt[base + tid] : 0;
        buf[tid] = v;
        __syncthreads();
        for (int off = 1; off < 1024; off <<= 1) {
            int tv = (tid >= off) ? buf[tid - off] : 0;
            __syncthreads();
            buf[tid] += tv;
            __syncthreads();
        }
        int carry = carry_s;
        if (base + tid < n) row_ptr[base + tid] = carry + buf[tid] - v;
        __syncthreads();
        if (tid == 1023) carry_s = carry + buf[1023];
        __syncthreads();
    }
    if (tid == 0) row_ptr[n] = carry_s;
}

__global__ void fill_csr_kernel(const int* __restrict__ ei, int E, const int* __restrict__ row_ptr,
                                int* __restrict__ fillc, int* __restrict__ srcs) {
    int i = blockIdx.x * blockDim.x + threadIdx.x;
    if (i < E) {
        int d = ei[E + i];
        int pos = row_ptr[d] + atomicAdd(&fillc[d], 1);
        srcs[pos] = ei[i];
    }
}

// ---------------- flat CSR gather bf16 (agg_h), wave/node, edge-unrolled (verified R7) ----------------
__global__ __launch_bounds__(256)
void agg_b2b_kernel(const ushort_t* __restrict__ feat, ushort_t* __restrict__ outp,
                    const int* __restrict__ rp, const int* __restrict__ srcs, int N) {
    int wave = threadIdx.x >> 6, lane = threadIdx.x & 63;
    int n = blockIdx.x * 4 + wave;
    if (n >= N) return;
    float a0 = 0.f, a1 = 0.f, a2 = 0.f, a3 = 0.f;
    int p0 = rp[n], p1 = rp[n + 1];
    const ushort_t* base = feat + lane * 4;
    int p = p0;
    for (; p + 1 < p1; p += 2) {
        long s0 = (long)srcs[p] * H_DIM;
        long s1 = (long)srcs[p + 1] * H_DIM;
        uint2 v0 = *(const uint2*)(base + s0);
        uint2 v1 = *(const uint2*)(base + s1);
        a0 += bf2f((ushort_t)(v0.x & 0xffff)) + bf2f((ushort_t)(v1.x & 0xffff));
        a1 += bf2f((ushort_t)(v0.x >> 16))    + bf2f((ushort_t)(v1.x >> 16));
        a2 += bf2f((ushort_t)(v0.y & 0xffff)) + bf2f((ushort_t)(v1.y & 0xffff));
        a3 += bf2f((ushort_t)(v0.y >> 16))    + bf2f((ushort_t)(v1.y >> 16));
    }
    if (p < p1) {
        long s = (long)srcs[p] * H_DIM;
        uint2 v = *(const uint2*)(base + s);
        a0 += bf2f((ushort_t)(v.x & 0xffff));
        a1 += bf2f((ushort_t)(v.x >> 16));
        a2 += bf2f((ushort_t)(v.y & 0xffff));
        a3 += bf2f((ushort_t)(v.y >> 16));
    }
    uint2 o;
    o.x = (uint_t)f2bf(a0) | ((uint_t)f2bf(a1) << 16);
    o.y = (uint_t)f2bf(a2) | ((uint_t)f2bf(a3) << 16);
    *(uint2*)(outp + (long)n * H_DIM + lane * 4) = o;
}

// ---------------- interleaved CSR gather: feat [n][W] bf16, W = EB*256; block per node ----------------
// blockDim = W/4 (each thread 4 bf16 = 8 B); one edge = one contiguous W*2-byte coalesced read.
__global__ void aggI_kernel(const ushort_t* __restrict__ feat, ushort_t* __restrict__ outp,
                            const int* __restrict__ rp, const int* __restrict__ srcs,
                            int N, int W) {
    int n = blockIdx.x;
    int t = threadIdx.x;                      // t < W/4
    float a0 = 0.f, a1 = 0.f, a2 = 0.f, a3 = 0.f;
    int p0 = rp[n], p1 = rp[n + 1];
    const ushort_t* base = feat + t * 4;
    int p = p0;
    for (; p + 1 < p1; p += 2) {
        long s0 = (long)srcs[p] * W;
        long s1 = (long)srcs[p + 1] * W;
        uint2 v0 = *(const uint2*)(base + s0);
        uint2 v1 = *(const uint2*)(base + s1);
        a0 += bf2f((ushort_t)(v0.x & 0xffff)) + bf2f((ushort_t)(v1.x & 0xffff));
        a1 += bf2f((ushort_t)(v0.x >> 16))    + bf2f((ushort_t)(v1.x >> 16));
        a2 += bf2f((ushort_t)(v0.y & 0xffff)) + bf2f((ushort_t)(v1.y & 0xffff));
        a3 += bf2f((ushort_t)(v0.y >> 16))    + bf2f((ushort_t)(v1.y >> 16));
    }
    if (p < p1) {
        long s = (long)srcs[p] * W;
        uint2 v = *(const uint2*)(base + s);
        a0 += bf2f((ushort_t)(v.x & 0xffff));
        a1 += bf2f((ushort_t)(v.x >> 16));
        a2 += bf2f((ushort_t)(v.y & 0xffff));
        a3 += bf2f((ushort_t)(v.y >> 16));
    }
    uint2 o;
    o.x = (uint_t)f2bf(a0) | ((uint_t)f2bf(a1) << 16);
    o.y = (uint_t)f2bf(a2) | ((uint_t)f2bf(a3) << 16);
    *(uint2*)(outp + (long)n * W + t * 4) = o;
}

// ---------------- final mix on interleaved PR rows [n][z][256] (P cols 0..127, R 128..255) ----------------
__global__ __launch_bounds__(256)
void final_mixE_kernel(const ushort_t* __restrict__ PR, const float* __restrict__ b2,
                       const float* __restrict__ wts, int e0, int EB,
                       const int* __restrict__ rp, const int* __restrict__ srcs,
                       float* __restrict__ out, int N, int init) {
    int wave = threadIdx.x >> 6, lane = threadIdx.x & 63;
    int n = blockIdx.x * 4 + wave;
    if (n >= N) return;
    const int W = EB * 256;
    int c0 = lane * 2;
    long obase = (long)n * O_DIM + c0;
    float o0 = init ? 0.f : out[obase];
    float o1 = init ? 0.f : out[obase + 1];
    int zs[2]; float wv[2]; int na = 0;
    for (int z = 0; z < EB; ++z) {
        float w = wts[(long)n * NEXP + e0 + z];
        if (w != 0.f && na < 2) { zs[na] = z; wv[na] = w; ++na; }
    }
    if (na) {
        const ushort_t* P0 = PR + zs[0] * 256 + c0;
        const ushort_t* P1 = PR + zs[na - 1] * 256 + c0;
        float a00 = 0.f, a01 = 0.f, a10 = 0.f, a11 = 0.f;
        int p0 = rp[n], p1 = rp[n + 1];
        if (na == 2) {
            for (int p = p0; p < p1; ++p) {
                long s = (long)srcs[p] * W;
                uint_t v0 = *(const uint_t*)(P0 + s);
                uint_t v1 = *(const uint_t*)(P1 + s);
                a00 += bf2f((ushort_t)(v0 & 0xffff)); a01 += bf2f((ushort_t)(v0 >> 16));
                a10 += bf2f((ushort_t)(v1 & 0xffff)); a11 += bf2f((ushort_t)(v1 >> 16));
            }
        } else {
            int p = p0;
            for (; p + 1 < p1; p += 2) {
                long s0 = (long)srcs[p] * W;
                long s1 = (long)srcs[p + 1] * W;
                uint_t v0 = *(const uint_t*)(P0 + s0);
                uint_t v1 = *(const uint_t*)(P0 + s1);
                a00 += bf2f((ushort_t)(v0 & 0xffff)) + bf2f((ushort_t)(v1 & 0xffff));
                a01 += bf2f((ushort_t)(v0 >> 16))    + bf2f((ushort_t)(v1 >> 16));
            }
            if (p < p1) {
                long s = (long)srcs[p] * W;
                uint_t v = *(const uint_t*)(P0 + s);
                a00 += bf2f((ushort_t)(v & 0xffff)); a01 += bf2f((ushort_t)(v >> 16));
            }
        }
        {
            int e = e0 + zs[0];
            uint_t rv = *(const uint_t*)(PR + (long)n * W + zs[0] * 256 + 128 + c0);
            o0 += wv[0] * (a00 + bf2f((ushort_t)(rv & 0xffff)) + b2[e * O_DIM + c0]);
            o1 += wv[0] * (a01 + bf2f((ushort_t)(rv >> 16))    + b2[e * O_DIM + c0 + 1]);
        }
        if (na == 2) {
            int e = e0 + zs[1];
            uint_t rv = *(const uint_t*)(PR + (long)n * W + zs[1] * 256 + 128 + c0);
            o0 += wv[1] * (a10 + bf2f((ushort_t)(rv & 0xffff)) + b2[e * O_DIM + c0]);
            o1 += wv[1] * (a11 + bf2f((ushort_t)(rv >> 16))    + b2[e * O_DIM + c0 + 1]);
        }
    }
    out[obase] = o0;
    out[obase + 1] = o1;
}

// ==================== host launcher ====================
extern "C" void kernel_launch(void* const* d_in, const int* in_sizes, int n_in,
                              void* d_out, int out_size, void* d_ws, size_t ws_size,
                              hipStream_t stream) {
    const float* x       = (const float*)d_in[0];
    const int*   ei      = (const int*)  d_in[1];
    const int*   batch   = (const int*)  d_in[2];
    const float* enc_W1  = (const float*)d_in[3];
    const float* enc_b1  = (const float*)d_in[4];
    const float* enc_W2  = (const float*)d_in[5];
    const float* enc_b2  = (const float*)d_in[6];
    const float* r_W1    = (const float*)d_in[7];
    const float* r_b1    = (const float*)d_in[8];
    const float* ln_g    = (const float*)d_in[9];
    const float* ln_b    = (const float*)d_in[10];
    const float* r_W2    = (const float*)d_in[11];
    const float* r_b2    = (const float*)d_in[12];
    const float* centers = (const float*)d_in[13];
    const float* W0_rel  = (const float*)d_in[14];
    const float* b0_rel  = (const float*)d_in[15];
    const float* W0_root = (const float*)d_in[16];
    const float* W1_rel  = (const float*)d_in[17];
    const float* b1_rel  = (const float*)d_in[18];
    const float* W1_root = (const float*)d_in[19];
    const float* W2_rel  = (const float*)d_in[20];
    const float* b2_rel  = (const float*)d_in[21];
    const float* W2_root = (const float*)d_in[22];

    const int N = in_sizes[2];
    const int E = in_sizes[1] / 2;
    const int F = in_sizes[0] / N;

    // ---- workspace layout (256B-aligned slabs) ----
    char* ws = (char*)d_ws;
    size_t off = 0;
    auto alloc = [&](size_t bytes) -> void* {
        void* p = ws + off;
        off += (bytes + 255) & ~(size_t)255;
        return p;
    };
    int* cnt      = (int*)alloc((size_t)N * 4);
    int* fillc    = (int*)alloc((size_t)N * 4);
    int* gn       = (int*)alloc((size_t)G_DIM * 4);
    int* ge       = (int*)alloc((size_t)G_DIM * 4);
    size_t zero_bytes = off;
    int* row_ptr  = (int*)alloc((size_t)(N + 1) * 4);
    int* srcs     = (int*)alloc((size_t)E * 4);
    float* feats_norm = (float*)alloc((size_t)G_DIM * 3 * 4);
    float* logn_norm  = (float*)alloc((size_t)G_DIM * 4);
    float* wts    = (float*)alloc((size_t)N * NEXP * 4);
    // fused bf16 hi/lo weights
    ushort_t* wf0_h  = (ushort_t*)alloc((size_t)NEXP * 131072 * 2);
    ushort_t* wf0_l  = (ushort_t*)alloc((size_t)NEXP * 131072 * 2);
    ushort_t* wf1_h  = (ushort_t*)alloc((size_t)NEXP * 131072 * 2);
    ushort_t* wf1_l  = (ushort_t*)alloc((size_t)NEXP * 131072 * 2);
    ushort_t* wfin_h = (ushort_t*)alloc((size_t)NEXP * 65536 * 2);
    ushort_t* wfin_l = (ushort_t*)alloc((size_t)NEXP * 65536 * 2);
    // persistent bf16 activations
    const long sE = (long)N * H_DIM;               // elements per expert slab
    ushort_t* h_bf    = (ushort_t*)alloc((size_t)sE * 2);
    ushort_t* aggh_bf = (ushort_t*)alloc((size_t)sE * 2);
    // adaptive expert batch: 4 if workspace allows, else 2 (proven footprint)
    size_t fixed_end = off;
    size_t slab4 = ((size_t)4 * sE * 2 + 255) & ~(size_t)255;
    int EB = (ws_size >= fixed_end + 3 * slab4 + (1u << 20)) ? 4 : 2;
    size_t slab = ((size_t)EB * sE * 2 + 255) & ~(size_t)255;
    ushort_t* S1 = (ushort_t*)alloc(slab);   // u(fp32) -> hE0 [n][z][h]
    ushort_t* S2 = (ushort_t*)alloc(slab);   // h(fp32) -> aggE -> PR [n][z][h]
    ushort_t* S3 = (ushort_t*)alloc(slab);   // t(fp32) -> hE1 [n][z][h]
    (void)out_size; (void)n_in;

    float* u    = (float*)S1;
    float* h    = (float*)S2;
    float* tf32 = (float*)S3;
    ushort_t* hE0  = S1;
    ushort_t* aggE = S2;
    ushort_t* hE1  = S3;
    ushort_t* PR   = S2;
    float* out = (float*)d_out;

    const int W  = EB * 256;                 // interleaved row width (elements)
    dim3 blk256(256);
    dim3 gR((N + 63) / 64, H_DIM / 64, 1);   // fp32 SGEMM grid (router path)
    dim3 gM((N + 127) / 128, 2, EB);         // MFMA grid
    dim3 gAgg((N + 3) / 4);

    // 0) zero counters
    {
        long nz = (long)(zero_bytes / 4);
        zero_i_kernel<<<dim3((nz + 255) / 256), blk256, 0, stream>>>((int*)ws, nz);
    }
    // 0b) fused weight prep
    wsplit2_kernel<<<dim3(512, NEXP), blk256, 0, stream>>>(W0_rel, W0_root, wf0_h, wf0_l);
    wsplit2_kernel<<<dim3(512, NEXP), blk256, 0, stream>>>(W1_rel, W1_root, wf1_h, wf1_l);
    wsplitcat_kernel<<<dim3(256, NEXP), blk256, 0, stream>>>(W2_rel, W2_root, wfin_h, wfin_l);
    // 1) encoder stage 1 -> u
    encoder1_kernel<<<dim3(N), blk256, 0, stream>>>(x, enc_W1, enc_b1, u, N, F);
    // 2) h = u @ enc_W2 + enc_b2 (fp32 SGEMM + bf16 shadow)
    gemm256_kernel<<<gR, blk256, 0, stream>>>(u, enc_W2, enc_b2, h, h_bf, N, H_DIM);
    // 3-5) graph stats
    hist_nodes_kernel<<<dim3(256), blk256, 0, stream>>>(batch, N, gn);
    hist_edges_kernel<<<dim3(512), blk256, 0, stream>>>(ei, batch, E, ge);
    graph_stats_kernel<<<dim3(1), dim3(64), 0, stream>>>(gn, ge, feats_norm, logn_norm);
    // 6) t = h @ r_W1[0:256,:] (fp32 SGEMM)
    gemm256_kernel<<<gR, blk256, 0, stream>>>(h, r_W1, nullptr, tf32, nullptr, N, H_DIM);
    // 7) router epilogue -> wts
    router_epi_kernel<<<dim3((N + 3) / 4), blk256, 0, stream>>>(
        tf32, batch, feats_norm, logn_norm, r_W1, r_b1, ln_g, ln_b, r_W2, r_b2, centers, wts, N);
    // 8-10) CSR build
    count_dst_kernel<<<dim3((E + 255) / 256), blk256, 0, stream>>>(ei, E, cnt);
    scan_kernel<<<dim3(1), dim3(1024), 0, stream>>>(cnt, row_ptr, N);
    fill_csr_kernel<<<dim3((E + 255) / 256), blk256, 0, stream>>>(ei, E, row_ptr, fillc, srcs);
    // 11) agg_h = Agg(h_bf)  (flat gather, verified)
    agg_b2b_kernel<<<gAgg, blk256, 0, stream>>>(h_bf, aggh_bf, row_ptr, srcs, N);

    // ---- expert pipeline, EB experts per dispatch, interleaved [n][z][h] slabs ----
    for (int b = 0; b < NEXP / EB; ++b) {
        const int e0 = b * EB;
        // hE0[n][z] = relu([agg_h | h] @ [W0_rel;W0_root]^T + b0)   (A shared across z)
        gemm_bf_kernel<2><<<gM, blk256, 0, stream>>>(
            aggh_bf, 0, 256, h_bf, 0, 256,
            wf0_h + (long)e0 * 131072, wf0_l + (long)e0 * 131072, 131072,
            b0_rel + e0 * H_DIM, H_DIM, hE0, 256, W, N, 512, 1);
        // aggE[n][z] = Agg(hE0)  — one dispatch, 2KB-contiguous edge reads
        aggI_kernel<<<dim3(N), dim3(W / 4), 0, stream>>>(hE0, aggE, row_ptr, srcs, N, W);
        // hE1[n][z] = relu([aggE | hE0] @ [W1_rel;W1_root]^T + b1)
        gemm_bf_kernel<2><<<gM, blk256, 0, stream>>>(
            aggE, 256, W, hE0, 256, W,
            wf1_h + (long)e0 * 131072, wf1_l + (long)e0 * 131072, 131072,
            b1_rel + e0 * H_DIM, H_DIM, hE1, 256, W, N, 512, 1);
        // PR[n][z] = hE1 @ [W2_rel|W2_root]^T   (overlay onto dead aggE)
        gemm_bf_kernel<1><<<gM, blk256, 0, stream>>>(
            hE1, 256, W, nullptr, 0, 256,
            wfin_h + (long)e0 * 65536, wfin_l + (long)e0 * 65536, 65536,
            nullptr, 0, PR, 256, W, N, 256, 0);
        // out (+)= sum_z w[:,e0+z] * (Agg(P[z]) + R[z] + b2[e0+z])
        final_mixE_kernel<<<gAgg, blk256, 0, stream>>>(
            PR, b2_rel, wts, e0, EB, row_ptr, srcs, out, N, b == 0 ? 1 : 0);
    }
}

// Round 9
// 1305.709 us; speedup vs baseline: 3.1657x; 1.1703x over previous
//
#include <hip/hip_runtime.h>
#include <hip/hip_bf16.h>

// ---------------- problem constants ----------------
#define H_DIM 256
#define O_DIM 128
#define NEXP 4
#define G_DIM 64

typedef unsigned short ushort_t;
typedef unsigned int uint_t;
typedef __attribute__((ext_vector_type(8))) short short8;
typedef __attribute__((ext_vector_type(4))) float floatx4;

// ---------------- bf16 helpers (RNE) ----------------
__device__ __forceinline__ float bf2f(ushort_t u) {
    union { uint_t i; float f; } c; c.i = ((uint_t)u) << 16; return c.f;
}
__device__ __forceinline__ ushort_t f2bf(float f) {
    union { float f; uint_t i; } c; c.f = f;
    uint_t x = c.i;
    uint_t r = (x + 0x7fffu + ((x >> 16) & 1u)) >> 16;
    return (ushort_t)r;
}

// ---------------- async global->LDS 16B ----------------
__device__ __forceinline__ void load16_lds(const void* g, void* l) {
    __builtin_amdgcn_global_load_lds(
        (const __attribute__((address_space(1))) unsigned int*)g,
        (__attribute__((address_space(3))) unsigned int*)l, 16, 0, 0);
}

// ---------------- utility: zero ints ----------------
__global__ void zero_i_kernel(int* __restrict__ p, long n) {
    long i = (long)blockIdx.x * blockDim.x + threadIdx.x;
    if (i < n) p[i] = 0;
}

// ---------------- fused weight prep (single bf16, transposed) ----------------
// vertical k-concat: Wt[z][n][k], k<256 from Wa[z][k][n], k>=256 from Wb[z][k-256][n]; Nc=256, K=512
__global__ void wsplit2_kernel(const float* __restrict__ Wa, const float* __restrict__ Wb,
                               ushort_t* __restrict__ Wh) {
    int z = blockIdx.y;
    int i = blockIdx.x * 256 + threadIdx.x;        // 256n * 512k
    if (i >= 131072) return;
    int nn = i >> 9, kk = i & 511;
    float v = (kk < 256) ? Wa[(long)z * 65536 + kk * 256 + nn]
                         : Wb[(long)z * 65536 + (kk - 256) * 256 + nn];
    Wh[(long)z * 131072 + i] = f2bf(v);
}

// horizontal n-concat: Wt[z][n][k], n<128 from W2_rel[z][k][n], else W2_root[z][k][n-128]; Nc=256, K=256
__global__ void wsplitcat_kernel(const float* __restrict__ Wa, const float* __restrict__ Wb,
                                 ushort_t* __restrict__ Wh) {
    int z = blockIdx.y;
    int i = blockIdx.x * 256 + threadIdx.x;        // 256n * 256k
    if (i >= 65536) return;
    int nn = i >> 8, kk = i & 255;
    float v = (nn < 128) ? Wa[(long)z * 32768 + kk * 128 + nn]
                         : Wb[(long)z * 32768 + kk * 128 + (nn - 128)];
    Wh[(long)z * 65536 + i] = f2bf(v);
}

// ---------------- encoder stage 1 (fp32, verified) ----------------
__global__ void encoder1_kernel(const float* __restrict__ x, const float* __restrict__ W1,
                                const float* __restrict__ b1, float* __restrict__ u,
                                int N, int F) {
    int n = blockIdx.x;
    int j = threadIdx.x;
    float acc = b1[j];
    #pragma unroll
    for (int c = 0; c < 6; ++c)
        acc += x[(long)n * F + 4 + c] * W1[c * H_DIM + j];
    u[(long)n * H_DIM + j] = fmaxf(acc, 0.f);
}

// ---------------- fp32 vector SGEMM (router path — DO NOT CHANGE: top-2 flip risk) ----------------
__global__ __launch_bounds__(256)
void gemm256_kernel(const float* __restrict__ A, const float* __restrict__ W,
                    const float* __restrict__ bias, float* __restrict__ C,
                    ushort_t* __restrict__ Cbf, int M, int Nc) {
    const int K = 256;
    __shared__ float As[16][68];
    __shared__ float Ws[16][68];
    int tid = threadIdx.x;
    int tx = tid & 15, ty = tid >> 4;
    int row0 = blockIdx.x * 64;
    int col0 = blockIdx.y * 64;
    float acc[4][4] = {};
    int lrow = tid >> 2, kq = tid & 3;
    int wk = tid >> 4, wc = (tid & 15) * 4;
    for (int k0 = 0; k0 < K; k0 += 16) {
        float4 av = make_float4(0.f, 0.f, 0.f, 0.f);
        int arow = row0 + lrow;
        if (arow < M) av = *(const float4*)(A + (long)arow * K + k0 + kq * 4);
        As[kq * 4 + 0][lrow] = av.x;
        As[kq * 4 + 1][lrow] = av.y;
        As[kq * 4 + 2][lrow] = av.z;
        As[kq * 4 + 3][lrow] = av.w;
        float4 wv = *(const float4*)(W + (long)(k0 + wk) * Nc + col0 + wc);
        *(float4*)&Ws[wk][wc] = wv;
        __syncthreads();
        #pragma unroll
        for (int kk = 0; kk < 16; ++kk) {
            float a[4], b[4];
            #pragma unroll
            for (int i = 0; i < 4; ++i) a[i] = As[kk][ty * 4 + i];
            #pragma unroll
            for (int j = 0; j < 4; ++j) b[j] = Ws[kk][tx * 4 + j];
            #pragma unroll
            for (int i = 0; i < 4; ++i)
                #pragma unroll
                for (int j = 0; j < 4; ++j) acc[i][j] += a[i] * b[j];
        }
        __syncthreads();
    }
    #pragma unroll
    for (int i = 0; i < 4; ++i) {
        int r = row0 + ty * 4 + i;
        if (r >= M) break;
        #pragma unroll
        for (int j = 0; j < 4; ++j) {
            int c = col0 + tx * 4 + j;
            float v = acc[i][j];
            if (bias) v += bias[c];
            C[(long)r * Nc + c] = v;
            if (Cbf) Cbf[(long)r * Nc + c] = f2bf(v);
        }
    }
}

// ---------------- bf16 MFMA GEMM, z-batched experts, swizzled LDS, strided A/C ----------------
// C[z] = [relu]( sum_halves A_half[z](bf16) @ B[z]^T + [bias[z]] ); B fused (Nc=256, Kb) single bf16.
// 128x128 tile, BK=32, 4 waves 2x2, 4x4 frags of 16x16x32. Add-rotate LDS swizzle (verified R6-R8).
template<int NH>
__global__ __launch_bounds__(256)
void gemm_bf_kernel(const ushort_t* __restrict__ A1, long sA1z, int rsA1,
                    const ushort_t* __restrict__ A2, long sA2z, int rsA2,
                    const ushort_t* __restrict__ B, long sBz,
                    const float* __restrict__ bias, int sBiasz,
                    ushort_t* __restrict__ Cbf, long sCz, int rsC,
                    int M, int Kb, int relu) {
    __shared__ alignas(16) ushort_t Asl[128 * 32];
    __shared__ alignas(16) ushort_t Bsl[128 * 32];

    const int tid = threadIdx.x, wave = tid >> 6, lane = tid & 63;
    const int z = blockIdx.z;
    const int row0 = blockIdx.x * 128, col0 = blockIdx.y * 128;
    const int wr = (wave >> 1) * 64, wcx = (wave & 1) * 64;
    floatx4 acc[4][4] = {};

    A1 += (long)z * sA1z;
    A2 += (long)z * sA2z;
    B += (long)z * sBz;
    if (bias) bias += (long)z * sBiasz;
    Cbf += (long)z * sCz;

    // staging map: 4 lanes/row (4x16B chunks), add-rotate swizzle
    const int bsr = lane >> 2;                    // row in group of 16
    const int bgc = ((lane & 3) - (bsr >> 1)) & 3;
    long aoff1[2], aoff2[2];
    #pragma unroll
    for (int q = 0; q < 2; ++q) {
        int ar = row0 + wave * 32 + q * 16 + bsr;
        ar = ar < M ? ar : M - 1;
        aoff1[q] = (long)ar * rsA1 + bgc * 8;
        aoff2[q] = (long)ar * rsA2 + bgc * 8;
    }
    const long brow = (long)(col0 + wave * 32 + bsr) * Kb + bgc * 8;
    const ushort_t* Bg0 = B + brow;
    const ushort_t* Bg1 = B + brow + (long)16 * Kb;
    ushort_t* Al0 = &Asl[(wave * 32) * 32];
    ushort_t* Al1 = &Asl[(wave * 32 + 16) * 32];
    ushort_t* Bl0 = &Bsl[(wave * 32) * 32];
    ushort_t* Bl1 = &Bsl[(wave * 32 + 16) * 32];

    const int fm = lane & 15, fq = lane >> 4;

    #pragma unroll
    for (int half = 0; half < NH; ++half) {
        const ushort_t* Ab = (half == 0) ? A1 : A2;
        const long* aoff = (half == 0) ? aoff1 : aoff2;
        for (int k0 = 0; k0 < 256; k0 += 32) {
            const int kk = half * 256 + k0;
            load16_lds(Ab + aoff[0] + k0, Al0);
            load16_lds(Ab + aoff[1] + k0, Al1);
            load16_lds(Bg0 + kk, Bl0);
            load16_lds(Bg1 + kk, Bl1);
            __syncthreads();

            short8 a[4], b[4];
            #pragma unroll
            for (int j = 0; j < 4; ++j) {
                int row = wcx + j * 16 + fm;
                int slot = (fq + ((row >> 1) & 3)) & 3;
                b[j] = *(const short8*)&Bsl[row * 32 + slot * 8];
            }
            #pragma unroll
            for (int i = 0; i < 4; ++i) {
                int row = wr + i * 16 + fm;
                int slot = (fq + ((row >> 1) & 3)) & 3;
                a[i] = *(const short8*)&Asl[row * 32 + slot * 8];
            }
            #pragma unroll
            for (int i = 0; i < 4; ++i)
                #pragma unroll
                for (int j = 0; j < 4; ++j)
                    acc[i][j] = __builtin_amdgcn_mfma_f32_16x16x32_bf16(a[i], b[j], acc[i][j], 0, 0, 0);
            __syncthreads();
        }
    }

    // epilogue: C/D layout col=lane&15, row=(lane>>4)*4+reg  [verified m89]
    #pragma unroll
    for (int i = 0; i < 4; ++i) {
        #pragma unroll
        for (int j = 0; j < 4; ++j) {
            int col = col0 + wcx + j * 16 + fm;
            int rowb = row0 + wr + i * 16 + fq * 4;
            #pragma unroll
            for (int r = 0; r < 4; ++r) {
                int row = rowb + r;
                if (row < M) {
                    float v = acc[i][j][r];
                    if (bias) v += bias[col];
                    if (relu) v = fmaxf(v, 0.f);
                    Cbf[(long)row * rsC + col] = f2bf(v);
                }
            }
        }
    }
}

// ---------------- graph-stat histograms ----------------
__global__ void hist_nodes_kernel(const int* __restrict__ batch, int n, int* __restrict__ gn) {
    __shared__ int bins[G_DIM];
    int t = threadIdx.x;
    if (t < G_DIM) bins[t] = 0;
    __syncthreads();
    for (long i = (long)blockIdx.x * blockDim.x + t; i < n; i += (long)gridDim.x * blockDim.x)
        atomicAdd(&bins[batch[i]], 1);
    __syncthreads();
    if (t < G_DIM) atomicAdd(&gn[t], bins[t]);
}

__global__ void hist_edges_kernel(const int* __restrict__ ei, const int* __restrict__ batch,
                                  int E, int* __restrict__ ge) {
    __shared__ int bins[G_DIM];
    int t = threadIdx.x;
    if (t < G_DIM) bins[t] = 0;
    __syncthreads();
    for (long i = (long)blockIdx.x * blockDim.x + t; i < E; i += (long)gridDim.x * blockDim.x)
        atomicAdd(&bins[batch[ei[i]]], 1);
    __syncthreads();
    if (t < G_DIM) atomicAdd(&ge[t], bins[t]);
}

// ---------------- graph stats ----------------
__global__ void graph_stats_kernel(const int* __restrict__ gn, const int* __restrict__ ge,
                                   float* __restrict__ feats_norm, float* __restrict__ logn_norm) {
    int g = threadIdx.x;
    float nv = fmaxf((float)gn[g], 1.0f);
    float ev = (float)ge[g];
    float density = ev / fmaxf(nv * (nv - 1.0f), 1.0f);
    float logn = logf(nv);
    float mn = logn, mx = logn;
    for (int o = 32; o; o >>= 1) {
        mn = fminf(mn, __shfl_xor(mn, o));
        mx = fmaxf(mx, __shfl_xor(mx, o));
    }
    logn_norm[g] = (logn - mn) / (mx - mn + 1e-6f);
    float f[3] = {nv, ev, density};
    #pragma unroll
    for (int c = 0; c < 3; ++c) {
        float s = f[c];
        for (int o = 32; o; o >>= 1) s += __shfl_xor(s, o);
        float mean = s / 64.f;
        float d = f[c] - mean;
        float v = d * d;
        for (int o = 32; o; o >>= 1) v += __shfl_xor(v, o);
        float stdv = sqrtf(v / 64.f);
        feats_norm[g * 3 + c] = d / (stdv + 1e-6f);
    }
}

// ---------------- router epilogue (verified) ----------------
__global__ __launch_bounds__(256)
void router_epi_kernel(const float* __restrict__ t, const int* __restrict__ batch,
                       const float* __restrict__ feats_norm, const float* __restrict__ logn_norm,
                       const float* __restrict__ rW1, const float* __restrict__ rb1,
                       const float* __restrict__ lng, const float* __restrict__ lnb,
                       const float* __restrict__ rW2, const float* __restrict__ rb2,
                       const float* __restrict__ centers, float* __restrict__ w, int N) {
    int wave = threadIdx.x >> 6, lane = threadIdx.x & 63;
    int n = blockIdx.x * 4 + wave;
    if (n >= N) return;
    int g = batch[n];
    float sf0 = feats_norm[g * 3 + 0], sf1 = feats_norm[g * 3 + 1], sf2 = feats_norm[g * 3 + 2];
    float ln = logn_norm[g];
    float tv[4];
    #pragma unroll
    for (int q = 0; q < 4; ++q) {
        int j = lane + 64 * q;
        tv[q] = t[(long)n * H_DIM + j] + rb1[j]
              + sf0 * rW1[256 * H_DIM + j] + sf1 * rW1[257 * H_DIM + j] + sf2 * rW1[258 * H_DIM + j];
    }
    float s = tv[0] + tv[1] + tv[2] + tv[3];
    for (int o = 32; o; o >>= 1) s += __shfl_xor(s, o);
    float mean = s / 256.f;
    float vs = 0.f;
    #pragma unroll
    for (int q = 0; q < 4; ++q) { float d = tv[q] - mean; vs += d * d; }
    for (int o = 32; o; o >>= 1) vs += __shfl_xor(vs, o);
    float rstd = rsqrtf(vs / 256.f + 1e-5f);
    float le[NEXP] = {0.f, 0.f, 0.f, 0.f};
    #pragma unroll
    for (int q = 0; q < 4; ++q) {
        int j = lane + 64 * q;
        float y = (tv[q] - mean) * rstd * lng[j] + lnb[j];
        y = fmaxf(y, 0.f);
        #pragma unroll
        for (int e = 0; e < NEXP; ++e) le[e] += y * rW2[j * NEXP + e];
    }
    #pragma unroll
    for (int e = 0; e < NEXP; ++e)
        for (int o = 32; o; o >>= 1) le[e] += __shfl_xor(le[e], o);
    if (lane == 0) {
        float p[NEXP];
        float m = -1e30f;
        #pragma unroll
        for (int e = 0; e < NEXP; ++e) {
            float d = ln - centers[e];
            float lv = 0.7f * (le[e] + rb2[e]) + 0.3f * (-(d * d));
            p[e] = lv;
            m = fmaxf(m, lv);
        }
        float ssum = 0.f;
        #pragma unroll
        for (int e = 0; e < NEXP; ++e) { p[e] = expf(p[e] - m); ssum += p[e]; }
        #pragma unroll
        for (int e = 0; e < NEXP; ++e) p[e] /= ssum;
        int i1 = 0;
        for (int e = 1; e < NEXP; ++e) if (p[e] > p[i1]) i1 = e;
        int i2 = -1;
        for (int e = 0; e < NEXP; ++e) { if (e == i1) continue; if (i2 < 0 || p[e] > p[i2]) i2 = e; }
        float denom = p[i1] + p[i2] + 1e-8f;
        float out4[NEXP] = {0.f, 0.f, 0.f, 0.f};
        out4[i1] = p[i1] / denom;
        out4[i2] = p[i2] / denom;
        #pragma unroll
        for (int e = 0; e < NEXP; ++e) w[(long)n * NEXP + e] = out4[e];
    }
}

// ---------------- CSR build ----------------
__global__ void count_dst_kernel(const int* __restrict__ ei, int E, int* __restrict__ cnt) {
    int i = blockIdx.x * blockDim.x + threadIdx.x;
    if (i < E) atomicAdd(&cnt[ei[E + i]], 1);
}

__global__ __launch_bounds__(1024)
void scan_kernel(const int* __restrict__ cnt, int* __restrict__ row_ptr, int n) {
    __shared__ int buf[1024];
    __shared__ int carry_s;
    int tid = threadIdx.x;
    if (tid == 0) carry_s = 0;
    __syncthreads();
    for (int base = 0; base < n; base += 1024) {
        int v = (base + tid < n) ? cnt[base + tid] : 0;
        buf[tid] = v;
        __syncthreads();
        for (int off = 1; off < 1024; off <<= 1) {
            int tv = (tid >= off) ? buf[tid - off] : 0;
            __syncthreads();
            buf[tid] += tv;
            __syncthreads();
        }
        int carry = carry_s;
        if (base + tid < n) row_ptr[base + tid] = carry + buf[tid] - v;
        __syncthreads();
        if (tid == 1023) carry_s = carry + buf[1023];
        __syncthreads();
    }
    if (tid == 0) row_ptr[n] = carry_s;
}

__global__ void fill_csr_kernel(const int* __restrict__ ei, int E, const int* __restrict__ row_ptr,
                                int* __restrict__ fillc, int* __restrict__ srcs) {
    int i = blockIdx.x * blockDim.x + threadIdx.x;
    if (i < E) {
        int d = ei[E + i];
        int pos = row_ptr[d] + atomicAdd(&fillc[d], 1);
        srcs[pos] = ei[i];
    }
}

// ---------------- flat CSR gather bf16 (agg_h), wave/node, edge-unrolled x4 ----------------
__global__ __launch_bounds__(256)
void agg_b2b_kernel(const ushort_t* __restrict__ feat, ushort_t* __restrict__ outp,
                    const int* __restrict__ rp, const int* __restrict__ srcs, int N) {
    int wave = threadIdx.x >> 6, lane = threadIdx.x & 63;
    int n = blockIdx.x * 4 + wave;
    if (n >= N) return;
    float a0 = 0.f, a1 = 0.f, a2 = 0.f, a3 = 0.f;
    int p0 = rp[n], p1 = rp[n + 1];
    const ushort_t* base = feat + lane * 4;
    int p = p0;
    for (; p + 3 < p1; p += 4) {
        uint2 v0 = *(const uint2*)(base + (long)srcs[p] * H_DIM);
        uint2 v1 = *(const uint2*)(base + (long)srcs[p + 1] * H_DIM);
        uint2 v2 = *(const uint2*)(base + (long)srcs[p + 2] * H_DIM);
        uint2 v3 = *(const uint2*)(base + (long)srcs[p + 3] * H_DIM);
        a0 += bf2f((ushort_t)(v0.x & 0xffff)) + bf2f((ushort_t)(v1.x & 0xffff))
            + bf2f((ushort_t)(v2.x & 0xffff)) + bf2f((ushort_t)(v3.x & 0xffff));
        a1 += bf2f((ushort_t)(v0.x >> 16)) + bf2f((ushort_t)(v1.x >> 16))
            + bf2f((ushort_t)(v2.x >> 16)) + bf2f((ushort_t)(v3.x >> 16));
        a2 += bf2f((ushort_t)(v0.y & 0xffff)) + bf2f((ushort_t)(v1.y & 0xffff))
            + bf2f((ushort_t)(v2.y & 0xffff)) + bf2f((ushort_t)(v3.y & 0xffff));
        a3 += bf2f((ushort_t)(v0.y >> 16)) + bf2f((ushort_t)(v1.y >> 16))
            + bf2f((ushort_t)(v2.y >> 16)) + bf2f((ushort_t)(v3.y >> 16));
    }
    for (; p < p1; ++p) {
        uint2 v = *(const uint2*)(base + (long)srcs[p] * H_DIM);
        a0 += bf2f((ushort_t)(v.x & 0xffff));
        a1 += bf2f((ushort_t)(v.x >> 16));
        a2 += bf2f((ushort_t)(v.y & 0xffff));
        a3 += bf2f((ushort_t)(v.y >> 16));
    }
    uint2 o;
    o.x = (uint_t)f2bf(a0) | ((uint_t)f2bf(a1) << 16);
    o.y = (uint_t)f2bf(a2) | ((uint_t)f2bf(a3) << 16);
    *(uint2*)(outp + (long)n * H_DIM + lane * 4) = o;
}

// ---------------- interleaved CSR gather: feat [n][W] bf16, W = EB*256; block per node ----------------
__global__ void aggI_kernel(const ushort_t* __restrict__ feat, ushort_t* __restrict__ outp,
                            const int* __restrict__ rp, const int* __restrict__ srcs,
                            int N, int W) {
    int n = blockIdx.x;
    int t = threadIdx.x;                      // t < W/4
    float a0 = 0.f, a1 = 0.f, a2 = 0.f, a3 = 0.f;
    int p0 = rp[n], p1 = rp[n + 1];
    const ushort_t* base = feat + t * 4;
    int p = p0;
    for (; p + 3 < p1; p += 4) {
        uint2 v0 = *(const uint2*)(base + (long)srcs[p] * W);
        uint2 v1 = *(const uint2*)(base + (long)srcs[p + 1] * W);
        uint2 v2 = *(const uint2*)(base + (long)srcs[p + 2] * W);
        uint2 v3 = *(const uint2*)(base + (long)srcs[p + 3] * W);
        a0 += bf2f((ushort_t)(v0.x & 0xffff)) + bf2f((ushort_t)(v1.x & 0xffff))
            + bf2f((ushort_t)(v2.x & 0xffff)) + bf2f((ushort_t)(v3.x & 0xffff));
        a1 += bf2f((ushort_t)(v0.x >> 16)) + bf2f((ushort_t)(v1.x >> 16))
            + bf2f((ushort_t)(v2.x >> 16)) + bf2f((ushort_t)(v3.x >> 16));
        a2 += bf2f((ushort_t)(v0.y & 0xffff)) + bf2f((ushort_t)(v1.y & 0xffff))
            + bf2f((ushort_t)(v2.y & 0xffff)) + bf2f((ushort_t)(v3.y & 0xffff));
        a3 += bf2f((ushort_t)(v0.y >> 16)) + bf2f((ushort_t)(v1.y >> 16))
            + bf2f((ushort_t)(v2.y >> 16)) + bf2f((ushort_t)(v3.y >> 16));
    }
    for (; p < p1; ++p) {
        uint2 v = *(const uint2*)(base + (long)srcs[p] * W);
        a0 += bf2f((ushort_t)(v.x & 0xffff));
        a1 += bf2f((ushort_t)(v.x >> 16));
        a2 += bf2f((ushort_t)(v.y & 0xffff));
        a3 += bf2f((ushort_t)(v.y >> 16));
    }
    uint2 o;
    o.x = (uint_t)f2bf(a0) | ((uint_t)f2bf(a1) << 16);
    o.y = (uint_t)f2bf(a2) | ((uint_t)f2bf(a3) << 16);
    *(uint2*)(outp + (long)n * W + t * 4) = o;
}

// ---------------- final mix on interleaved PR rows [n][z][256] (P cols 0..127, R 128..255) ----------------
__global__ __launch_bounds__(256)
void final_mixE_kernel(const ushort_t* __restrict__ PR, const float* __restrict__ b2,
                       const float* __restrict__ wts, int e0, int EB,
                       const int* __restrict__ rp, const int* __restrict__ srcs,
                       float* __restrict__ out, int N, int init) {
    int wave = threadIdx.x >> 6, lane = threadIdx.x & 63;
    int n = blockIdx.x * 4 + wave;
    if (n >= N) return;
    const int W = EB * 256;
    int c0 = lane * 2;
    long obase = (long)n * O_DIM + c0;
    float o0 = init ? 0.f : out[obase];
    float o1 = init ? 0.f : out[obase + 1];
    int zs[2]; float wv[2]; int na = 0;
    for (int z = 0; z < EB; ++z) {
        float w = wts[(long)n * NEXP + e0 + z];
        if (w != 0.f && na < 2) { zs[na] = z; wv[na] = w; ++na; }
    }
    if (na) {
        const ushort_t* P0 = PR + zs[0] * 256 + c0;
        const ushort_t* P1 = PR + zs[na - 1] * 256 + c0;
        float a00 = 0.f, a01 = 0.f, a10 = 0.f, a11 = 0.f;
        int p0 = rp[n], p1 = rp[n + 1];
        if (na == 2) {
            int p = p0;
            for (; p + 1 < p1; p += 2) {
                long s0 = (long)srcs[p] * W;
                long s1 = (long)srcs[p + 1] * W;
                uint_t v00 = *(const uint_t*)(P0 + s0);
                uint_t v10 = *(const uint_t*)(P1 + s0);
                uint_t v01 = *(const uint_t*)(P0 + s1);
                uint_t v11 = *(const uint_t*)(P1 + s1);
                a00 += bf2f((ushort_t)(v00 & 0xffff)) + bf2f((ushort_t)(v01 & 0xffff));
                a01 += bf2f((ushort_t)(v00 >> 16))    + bf2f((ushort_t)(v01 >> 16));
                a10 += bf2f((ushort_t)(v10 & 0xffff)) + bf2f((ushort_t)(v11 & 0xffff));
                a11 += bf2f((ushort_t)(v10 >> 16))    + bf2f((ushort_t)(v11 >> 16));
            }
            if (p < p1) {
                long s = (long)srcs[p] * W;
                uint_t v0 = *(const uint_t*)(P0 + s);
                uint_t v1 = *(const uint_t*)(P1 + s);
                a00 += bf2f((ushort_t)(v0 & 0xffff)); a01 += bf2f((ushort_t)(v0 >> 16));
                a10 += bf2f((ushort_t)(v1 & 0xffff)); a11 += bf2f((ushort_t)(v1 >> 16));
            }
        } else {
            int p = p0;
            for (; p + 3 < p1; p += 4) {
                uint_t v0 = *(const uint_t*)(P0 + (long)srcs[p] * W);
                uint_t v1 = *(const uint_t*)(P0 + (long)srcs[p + 1] * W);
                uint_t v2 = *(const uint_t*)(P0 + (long)srcs[p + 2] * W);
                uint_t v3 = *(const uint_t*)(P0 + (long)srcs[p + 3] * W);
                a00 += bf2f((ushort_t)(v0 & 0xffff)) + bf2f((ushort_t)(v1 & 0xffff))
                     + bf2f((ushort_t)(v2 & 0xffff)) + bf2f((ushort_t)(v3 & 0xffff));
                a01 += bf2f((ushort_t)(v0 >> 16)) + bf2f((ushort_t)(v1 >> 16))
                     + bf2f((ushort_t)(v2 >> 16)) + bf2f((ushort_t)(v3 >> 16));
            }
            for (; p < p1; ++p) {
                uint_t v = *(const uint_t*)(P0 + (long)srcs[p] * W);
                a00 += bf2f((ushort_t)(v & 0xffff)); a01 += bf2f((ushort_t)(v >> 16));
            }
        }
        {
            int e = e0 + zs[0];
            uint_t rv = *(const uint_t*)(PR + (long)n * W + zs[0] * 256 + 128 + c0);
            o0 += wv[0] * (a00 + bf2f((ushort_t)(rv & 0xffff)) + b2[e * O_DIM + c0]);
            o1 += wv[0] * (a01 + bf2f((ushort_t)(rv >> 16))    + b2[e * O_DIM + c0 + 1]);
        }
        if (na == 2) {
            int e = e0 + zs[1];
            uint_t rv = *(const uint_t*)(PR + (long)n * W + zs[1] * 256 + 128 + c0);
            o0 += wv[1] * (a10 + bf2f((ushort_t)(rv & 0xffff)) + b2[e * O_DIM + c0]);
            o1 += wv[1] * (a11 + bf2f((ushort_t)(rv >> 16))    + b2[e * O_DIM + c0 + 1]);
        }
    }
    out[obase] = o0;
    out[obase + 1] = o1;
}

// ==================== host launcher ====================
extern "C" void kernel_launch(void* const* d_in, const int* in_sizes, int n_in,
                              void* d_out, int out_size, void* d_ws, size_t ws_size,
                              hipStream_t stream) {
    const float* x       = (const float*)d_in[0];
    const int*   ei      = (const int*)  d_in[1];
    const int*   batch   = (const int*)  d_in[2];
    const float* enc_W1  = (const float*)d_in[3];
    const float* enc_b1  = (const float*)d_in[4];
    const float* enc_W2  = (const float*)d_in[5];
    const float* enc_b2  = (const float*)d_in[6];
    const float* r_W1    = (const float*)d_in[7];
    const float* r_b1    = (const float*)d_in[8];
    const float* ln_g    = (const float*)d_in[9];
    const float* ln_b    = (const float*)d_in[10];
    const float* r_W2    = (const float*)d_in[11];
    const float* r_b2    = (const float*)d_in[12];
    const float* centers = (const float*)d_in[13];
    const float* W0_rel  = (const float*)d_in[14];
    const float* b0_rel  = (const float*)d_in[15];
    const float* W0_root = (const float*)d_in[16];
    const float* W1_rel  = (const float*)d_in[17];
    const float* b1_rel  = (const float*)d_in[18];
    const float* W1_root = (const float*)d_in[19];
    const float* W2_rel  = (const float*)d_in[20];
    const float* b2_rel  = (const float*)d_in[21];
    const float* W2_root = (const float*)d_in[22];

    const int N = in_sizes[2];
    const int E = in_sizes[1] / 2;
    const int F = in_sizes[0] / N;

    // ---- workspace layout (256B-aligned slabs) ----
    char* ws = (char*)d_ws;
    size_t off = 0;
    auto alloc = [&](size_t bytes) -> void* {
        void* p = ws + off;
        off += (bytes + 255) & ~(size_t)255;
        return p;
    };
    int* cnt      = (int*)alloc((size_t)N * 4);
    int* fillc    = (int*)alloc((size_t)N * 4);
    int* gn       = (int*)alloc((size_t)G_DIM * 4);
    int* ge       = (int*)alloc((size_t)G_DIM * 4);
    size_t zero_bytes = off;
    int* row_ptr  = (int*)alloc((size_t)(N + 1) * 4);
    int* srcs     = (int*)alloc((size_t)E * 4);
    float* feats_norm = (float*)alloc((size_t)G_DIM * 3 * 4);
    float* logn_norm  = (float*)alloc((size_t)G_DIM * 4);
    float* wts    = (float*)alloc((size_t)N * NEXP * 4);
    // fused bf16 weights (single precision level)
    ushort_t* wf0  = (ushort_t*)alloc((size_t)NEXP * 131072 * 2);
    ushort_t* wf1  = (ushort_t*)alloc((size_t)NEXP * 131072 * 2);
    ushort_t* wfin = (ushort_t*)alloc((size_t)NEXP * 65536 * 2);
    // persistent bf16 activations
    const long sE = (long)N * H_DIM;               // elements per expert slab
    ushort_t* h_bf    = (ushort_t*)alloc((size_t)sE * 2);
    ushort_t* aggh_bf = (ushort_t*)alloc((size_t)sE * 2);
    // adaptive expert batch: 4 if workspace allows, else 2 (proven footprint)
    size_t fixed_end = off;
    size_t slab4 = ((size_t)4 * sE * 2 + 255) & ~(size_t)255;
    int EB = (ws_size >= fixed_end + 3 * slab4 + (1u << 20)) ? 4 : 2;
    size_t slab = ((size_t)EB * sE * 2 + 255) & ~(size_t)255;
    ushort_t* S1 = (ushort_t*)alloc(slab);   // u(fp32) -> hE0 [n][z][h]
    ushort_t* S2 = (ushort_t*)alloc(slab);   // h(fp32) -> aggE -> PR [n][z][h]
    ushort_t* S3 = (ushort_t*)alloc(slab);   // t(fp32) -> hE1 [n][z][h]
    (void)out_size; (void)n_in;

    float* u    = (float*)S1;
    float* h    = (float*)S2;
    float* tf32 = (float*)S3;
    ushort_t* hE0  = S1;
    ushort_t* aggE = S2;
    ushort_t* hE1  = S3;
    ushort_t* PR   = S2;
    float* out = (float*)d_out;

    const int W  = EB * 256;                 // interleaved row width (elements)
    dim3 blk256(256);
    dim3 gR((N + 63) / 64, H_DIM / 64, 1);   // fp32 SGEMM grid (router path)
    dim3 gM((N + 127) / 128, 2, EB);         // MFMA grid
    dim3 gAgg((N + 3) / 4);

    // 0) zero counters
    {
        long nz = (long)(zero_bytes / 4);
        zero_i_kernel<<<dim3((nz + 255) / 256), blk256, 0, stream>>>((int*)ws, nz);
    }
    // 0b) fused weight prep (single bf16)
    wsplit2_kernel<<<dim3(512, NEXP), blk256, 0, stream>>>(W0_rel, W0_root, wf0);
    wsplit2_kernel<<<dim3(512, NEXP), blk256, 0, stream>>>(W1_rel, W1_root, wf1);
    wsplitcat_kernel<<<dim3(256, NEXP), blk256, 0, stream>>>(W2_rel, W2_root, wfin);
    // 1) encoder stage 1 -> u
    encoder1_kernel<<<dim3(N), blk256, 0, stream>>>(x, enc_W1, enc_b1, u, N, F);
    // 2) h = u @ enc_W2 + enc_b2 (fp32 SGEMM + bf16 shadow)
    gemm256_kernel<<<gR, blk256, 0, stream>>>(u, enc_W2, enc_b2, h, h_bf, N, H_DIM);
    // 3-5) graph stats
    hist_nodes_kernel<<<dim3(256), blk256, 0, stream>>>(batch, N, gn);
    hist_edges_kernel<<<dim3(512), blk256, 0, stream>>>(ei, batch, E, ge);
    graph_stats_kernel<<<dim3(1), dim3(64), 0, stream>>>(gn, ge, feats_norm, logn_norm);
    // 6) t = h @ r_W1[0:256,:] (fp32 SGEMM)
    gemm256_kernel<<<gR, blk256, 0, stream>>>(h, r_W1, nullptr, tf32, nullptr, N, H_DIM);
    // 7) router epilogue -> wts
    router_epi_kernel<<<dim3((N + 3) / 4), blk256, 0, stream>>>(
        tf32, batch, feats_norm, logn_norm, r_W1, r_b1, ln_g, ln_b, r_W2, r_b2, centers, wts, N);
    // 8-10) CSR build
    count_dst_kernel<<<dim3((E + 255) / 256), blk256, 0, stream>>>(ei, E, cnt);
    scan_kernel<<<dim3(1), dim3(1024), 0, stream>>>(cnt, row_ptr, N);
    fill_csr_kernel<<<dim3((E + 255) / 256), blk256, 0, stream>>>(ei, E, row_ptr, fillc, srcs);
    // 11) agg_h = Agg(h_bf)  (flat gather)
    agg_b2b_kernel<<<gAgg, blk256, 0, stream>>>(h_bf, aggh_bf, row_ptr, srcs, N);

    // ---- expert pipeline, EB experts per dispatch, interleaved [n][z][h] slabs ----
    for (int b = 0; b < NEXP / EB; ++b) {
        const int e0 = b * EB;
        // hE0[n][z] = relu([agg_h | h] @ [W0_rel;W0_root]^T + b0)   (A shared across z)
        gemm_bf_kernel<2><<<gM, blk256, 0, stream>>>(
            aggh_bf, 0, 256, h_bf, 0, 256,
            wf0 + (long)e0 * 131072, 131072,
            b0_rel + e0 * H_DIM, H_DIM, hE0, 256, W, N, 512, 1);
        // aggE[n][z] = Agg(hE0)
        aggI_kernel<<<dim3(N), dim3(W / 4), 0, stream>>>(hE0, aggE, row_ptr, srcs, N, W);
        // hE1[n][z] = relu([aggE | hE0] @ [W1_rel;W1_root]^T + b1)
        gemm_bf_kernel<2><<<gM, blk256, 0, stream>>>(
            aggE, 256, W, hE0, 256, W,
            wf1 + (long)e0 * 131072, 131072,
            b1_rel + e0 * H_DIM, H_DIM, hE1, 256, W, N, 512, 1);
        // PR[n][z] = hE1 @ [W2_rel|W2_root]^T   (overlay onto dead aggE)
        gemm_bf_kernel<1><<<gM, blk256, 0, stream>>>(
            hE1, 256, W, nullptr, 0, 256,
            wfin + (long)e0 * 65536, 65536,
            nullptr, 0, PR, 256, W, N, 256, 0);
        // out (+)= sum_z w[:,e0+z] * (Agg(P[z]) + R[z] + b2[e0+z])
        final_mixE_kernel<<<gAgg, blk256, 0, stream>>>(
            PR, b2_rel, wts, e0, EB, row_ptr, srcs, out, N, b == 0 ? 1 : 0);
    }
}

// Round 10
// 1293.817 us; speedup vs baseline: 3.1948x; 1.0092x over previous
//
#include <hip/hip_runtime.h>
#include <hip/hip_bf16.h>

// ---------------- problem constants ----------------
#define H_DIM 256
#define O_DIM 128
#define NEXP 4
#define G_DIM 64

typedef unsigned short ushort_t;
typedef unsigned int uint_t;
typedef __attribute__((ext_vector_type(8))) short short8;
typedef __attribute__((ext_vector_type(4))) float floatx4;

// ---------------- bf16 helpers (RNE) ----------------
__device__ __forceinline__ float bf2f(ushort_t u) {
    union { uint_t i; float f; } c; c.i = ((uint_t)u) << 16; return c.f;
}
__device__ __forceinline__ ushort_t f2bf(float f) {
    union { float f; uint_t i; } c; c.f = f;
    uint_t x = c.i;
    uint_t r = (x + 0x7fffu + ((x >> 16) & 1u)) >> 16;
    return (ushort_t)r;
}

// ---------------- async global->LDS 16B ----------------
__device__ __forceinline__ void load16_lds(const void* g, void* l) {
    __builtin_amdgcn_global_load_lds(
        (const __attribute__((address_space(1))) unsigned int*)g,
        (__attribute__((address_space(3))) unsigned int*)l, 16, 0, 0);
}

// ---------------- utility: zero ints ----------------
__global__ void zero_i_kernel(int* __restrict__ p, long n) {
    long i = (long)blockIdx.x * blockDim.x + threadIdx.x;
    if (i < n) p[i] = 0;
}

// ---------------- fused weight prep (single bf16, transposed) ----------------
__global__ void wsplit2_kernel(const float* __restrict__ Wa, const float* __restrict__ Wb,
                               ushort_t* __restrict__ Wh) {
    int z = blockIdx.y;
    int i = blockIdx.x * 256 + threadIdx.x;        // 256n * 512k
    if (i >= 131072) return;
    int nn = i >> 9, kk = i & 511;
    float v = (kk < 256) ? Wa[(long)z * 65536 + kk * 256 + nn]
                         : Wb[(long)z * 65536 + (kk - 256) * 256 + nn];
    Wh[(long)z * 131072 + i] = f2bf(v);
}

__global__ void wsplitcat_kernel(const float* __restrict__ Wa, const float* __restrict__ Wb,
                                 ushort_t* __restrict__ Wh) {
    int z = blockIdx.y;
    int i = blockIdx.x * 256 + threadIdx.x;        // 256n * 256k
    if (i >= 65536) return;
    int nn = i >> 8, kk = i & 255;
    float v = (nn < 128) ? Wa[(long)z * 32768 + kk * 128 + nn]
                         : Wb[(long)z * 32768 + kk * 128 + (nn - 128)];
    Wh[(long)z * 65536 + i] = f2bf(v);
}

// ---------------- encoder stage 1 (fp32, verified) ----------------
__global__ void encoder1_kernel(const float* __restrict__ x, const float* __restrict__ W1,
                                const float* __restrict__ b1, float* __restrict__ u,
                                int N, int F) {
    int n = blockIdx.x;
    int j = threadIdx.x;
    float acc = b1[j];
    #pragma unroll
    for (int c = 0; c < 6; ++c)
        acc += x[(long)n * F + 4 + c] * W1[c * H_DIM + j];
    u[(long)n * H_DIM + j] = fmaxf(acc, 0.f);
}

// ---------------- fp32 vector SGEMM (router path — DO NOT CHANGE: top-2 flip risk) ----------------
__global__ __launch_bounds__(256)
void gemm256_kernel(const float* __restrict__ A, const float* __restrict__ W,
                    const float* __restrict__ bias, float* __restrict__ C,
                    ushort_t* __restrict__ Cbf, int M, int Nc) {
    const int K = 256;
    __shared__ float As[16][68];
    __shared__ float Ws[16][68];
    int tid = threadIdx.x;
    int tx = tid & 15, ty = tid >> 4;
    int row0 = blockIdx.x * 64;
    int col0 = blockIdx.y * 64;
    float acc[4][4] = {};
    int lrow = tid >> 2, kq = tid & 3;
    int wk = tid >> 4, wc = (tid & 15) * 4;
    for (int k0 = 0; k0 < K; k0 += 16) {
        float4 av = make_float4(0.f, 0.f, 0.f, 0.f);
        int arow = row0 + lrow;
        if (arow < M) av = *(const float4*)(A + (long)arow * K + k0 + kq * 4);
        As[kq * 4 + 0][lrow] = av.x;
        As[kq * 4 + 1][lrow] = av.y;
        As[kq * 4 + 2][lrow] = av.z;
        As[kq * 4 + 3][lrow] = av.w;
        float4 wv = *(const float4*)(W + (long)(k0 + wk) * Nc + col0 + wc);
        *(float4*)&Ws[wk][wc] = wv;
        __syncthreads();
        #pragma unroll
        for (int kk = 0; kk < 16; ++kk) {
            float a[4], b[4];
            #pragma unroll
            for (int i = 0; i < 4; ++i) a[i] = As[kk][ty * 4 + i];
            #pragma unroll
            for (int j = 0; j < 4; ++j) b[j] = Ws[kk][tx * 4 + j];
            #pragma unroll
            for (int i = 0; i < 4; ++i)
                #pragma unroll
                for (int j = 0; j < 4; ++j) acc[i][j] += a[i] * b[j];
        }
        __syncthreads();
    }
    #pragma unroll
    for (int i = 0; i < 4; ++i) {
        int r = row0 + ty * 4 + i;
        if (r >= M) break;
        #pragma unroll
        for (int j = 0; j < 4; ++j) {
            int c = col0 + tx * 4 + j;
            float v = acc[i][j];
            if (bias) v += bias[c];
            C[(long)r * Nc + c] = v;
            if (Cbf) Cbf[(long)r * Nc + c] = f2bf(v);
        }
    }
}

// ---------------- bf16 MFMA GEMM, double-buffered LDS pipeline ----------------
// C[z] = [relu]( sum_halves A_half[z](bf16) @ B[z]^T + [bias[z]] ); B fused (Nc=256, Kb) single bf16.
// 128x128 tile, BK=32, 4 waves 2x2, 4x4 frags of 16x16x32; add-rotate LDS swizzle (verified R6-R9).
// Stage k+1 into alternate buffer before MFMA on k -> loads in flight during compute; 1 barrier/k-step.
template<int NH>
__global__ __launch_bounds__(256)
void gemm_bf_kernel(const ushort_t* __restrict__ A1, long sA1z, int rsA1,
                    const ushort_t* __restrict__ A2, long sA2z, int rsA2,
                    const ushort_t* __restrict__ B, long sBz,
                    const float* __restrict__ bias, int sBiasz,
                    ushort_t* __restrict__ Cbf, long sCz, int rsC,
                    int M, int Kb, int relu) {
    __shared__ alignas(16) ushort_t Asl[2][128 * 32];
    __shared__ alignas(16) ushort_t Bsl[2][128 * 32];

    const int tid = threadIdx.x, wave = tid >> 6, lane = tid & 63;
    const int z = blockIdx.z;
    const int row0 = blockIdx.x * 128, col0 = blockIdx.y * 128;
    const int wr = (wave >> 1) * 64, wcx = (wave & 1) * 64;
    floatx4 acc[4][4] = {};

    A1 += (long)z * sA1z;
    A2 += (long)z * sA2z;
    B += (long)z * sBz;
    if (bias) bias += (long)z * sBiasz;
    Cbf += (long)z * sCz;

    // staging map: 4 lanes/row (4x16B chunks), add-rotate swizzle
    const int bsr = lane >> 2;                    // row in group of 16
    const int bgc = ((lane & 3) - (bsr >> 1)) & 3;
    long aoff1[2], aoff2[2];
    #pragma unroll
    for (int q = 0; q < 2; ++q) {
        int ar = row0 + wave * 32 + q * 16 + bsr;
        ar = ar < M ? ar : M - 1;
        aoff1[q] = (long)ar * rsA1 + bgc * 8;
        aoff2[q] = (long)ar * rsA2 + bgc * 8;
    }
    const long brow = (long)(col0 + wave * 32 + bsr) * Kb + bgc * 8;
    const ushort_t* Bg0 = B + brow;
    const ushort_t* Bg1 = B + brow + (long)16 * Kb;
    const int la0 = (wave * 32) * 32;
    const int la1 = (wave * 32 + 16) * 32;

    const int fm = lane & 15, fq = lane >> 4;
    const int NK = NH * 8;

    // stage k=0 into buffer 0
    load16_lds(A1 + aoff1[0], &Asl[0][la0]);
    load16_lds(A1 + aoff1[1], &Asl[0][la1]);
    load16_lds(Bg0, &Bsl[0][la0]);
    load16_lds(Bg1, &Bsl[0][la1]);
    __syncthreads();

    for (int k = 0; k < NK; ++k) {
        const int buf = k & 1;
        short8 a[4], b[4];
        #pragma unroll
        for (int j = 0; j < 4; ++j) {
            int row = wcx + j * 16 + fm;
            int slot = (fq + ((row >> 1) & 3)) & 3;
            b[j] = *(const short8*)&Bsl[buf][row * 32 + slot * 8];
        }
        #pragma unroll
        for (int i = 0; i < 4; ++i) {
            int row = wr + i * 16 + fm;
            int slot = (fq + ((row >> 1) & 3)) & 3;
            a[i] = *(const short8*)&Asl[buf][row * 32 + slot * 8];
        }
        if (k + 1 < NK) {
            const int kn = k + 1, bn = kn & 1;
            const ushort_t* Ab = (kn >> 3) ? A2 : A1;
            const long* ao = (kn >> 3) ? aoff2 : aoff1;
            const int k0 = (kn & 7) * 32;          // within-half A offset
            const int kk = kn * 32;                // fused-K B offset
            load16_lds(Ab + ao[0] + k0, &Asl[bn][la0]);
            load16_lds(Ab + ao[1] + k0, &Asl[bn][la1]);
            load16_lds(Bg0 + kk, &Bsl[bn][la0]);
            load16_lds(Bg1 + kk, &Bsl[bn][la1]);
        }
        #pragma unroll
        for (int i = 0; i < 4; ++i)
            #pragma unroll
            for (int j = 0; j < 4; ++j)
                acc[i][j] = __builtin_amdgcn_mfma_f32_16x16x32_bf16(a[i], b[j], acc[i][j], 0, 0, 0);
        if (k + 1 < NK) __syncthreads();
    }

    // epilogue: C/D layout col=lane&15, row=(lane>>4)*4+reg  [verified m89]
    #pragma unroll
    for (int i = 0; i < 4; ++i) {
        #pragma unroll
        for (int j = 0; j < 4; ++j) {
            int col = col0 + wcx + j * 16 + fm;
            int rowb = row0 + wr + i * 16 + fq * 4;
            #pragma unroll
            for (int r = 0; r < 4; ++r) {
                int row = rowb + r;
                if (row < M) {
                    float v = acc[i][j][r];
                    if (bias) v += bias[col];
                    if (relu) v = fmaxf(v, 0.f);
                    Cbf[(long)row * rsC + col] = f2bf(v);
                }
            }
        }
    }
}

// ---------------- graph-stat histograms ----------------
__global__ void hist_nodes_kernel(const int* __restrict__ batch, int n, int* __restrict__ gn) {
    __shared__ int bins[G_DIM];
    int t = threadIdx.x;
    if (t < G_DIM) bins[t] = 0;
    __syncthreads();
    for (long i = (long)blockIdx.x * blockDim.x + t; i < n; i += (long)gridDim.x * blockDim.x)
        atomicAdd(&bins[batch[i]], 1);
    __syncthreads();
    if (t < G_DIM) atomicAdd(&gn[t], bins[t]);
}

__global__ void hist_edges_kernel(const int* __restrict__ ei, const int* __restrict__ batch,
                                  int E, int* __restrict__ ge) {
    __shared__ int bins[G_DIM];
    int t = threadIdx.x;
    if (t < G_DIM) bins[t] = 0;
    __syncthreads();
    for (long i = (long)blockIdx.x * blockDim.x + t; i < E; i += (long)gridDim.x * blockDim.x)
        atomicAdd(&bins[batch[ei[i]]], 1);
    __syncthreads();
    if (t < G_DIM) atomicAdd(&ge[t], bins[t]);
}

// ---------------- graph stats ----------------
__global__ void graph_stats_kernel(const int* __restrict__ gn, const int* __restrict__ ge,
                                   float* __restrict__ feats_norm, float* __restrict__ logn_norm) {
    int g = threadIdx.x;
    float nv = fmaxf((float)gn[g], 1.0f);
    float ev = (float)ge[g];
    float density = ev / fmaxf(nv * (nv - 1.0f), 1.0f);
    float logn = logf(nv);
    float mn = logn, mx = logn;
    for (int o = 32; o; o >>= 1) {
        mn = fminf(mn, __shfl_xor(mn, o));
        mx = fmaxf(mx, __shfl_xor(mx, o));
    }
    logn_norm[g] = (logn - mn) / (mx - mn + 1e-6f);
    float f[3] = {nv, ev, density};
    #pragma unroll
    for (int c = 0; c < 3; ++c) {
        float s = f[c];
        for (int o = 32; o; o >>= 1) s += __shfl_xor(s, o);
        float mean = s / 64.f;
        float d = f[c] - mean;
        float v = d * d;
        for (int o = 32; o; o >>= 1) v += __shfl_xor(v, o);
        float stdv = sqrtf(v / 64.f);
        feats_norm[g * 3 + c] = d / (stdv + 1e-6f);
    }
}

// ---------------- router epilogue (verified) ----------------
__global__ __launch_bounds__(256)
void router_epi_kernel(const float* __restrict__ t, const int* __restrict__ batch,
                       const float* __restrict__ feats_norm, const float* __restrict__ logn_norm,
                       const float* __restrict__ rW1, const float* __restrict__ rb1,
                       const float* __restrict__ lng, const float* __restrict__ lnb,
                       const float* __restrict__ rW2, const float* __restrict__ rb2,
                       const float* __restrict__ centers, float* __restrict__ w, int N) {
    int wave = threadIdx.x >> 6, lane = threadIdx.x & 63;
    int n = blockIdx.x * 4 + wave;
    if (n >= N) return;
    int g = batch[n];
    float sf0 = feats_norm[g * 3 + 0], sf1 = feats_norm[g * 3 + 1], sf2 = feats_norm[g * 3 + 2];
    float ln = logn_norm[g];
    float tv[4];
    #pragma unroll
    for (int q = 0; q < 4; ++q) {
        int j = lane + 64 * q;
        tv[q] = t[(long)n * H_DIM + j] + rb1[j]
              + sf0 * rW1[256 * H_DIM + j] + sf1 * rW1[257 * H_DIM + j] + sf2 * rW1[258 * H_DIM + j];
    }
    float s = tv[0] + tv[1] + tv[2] + tv[3];
    for (int o = 32; o; o >>= 1) s += __shfl_xor(s, o);
    float mean = s / 256.f;
    float vs = 0.f;
    #pragma unroll
    for (int q = 0; q < 4; ++q) { float d = tv[q] - mean; vs += d * d; }
    for (int o = 32; o; o >>= 1) vs += __shfl_xor(vs, o);
    float rstd = rsqrtf(vs / 256.f + 1e-5f);
    float le[NEXP] = {0.f, 0.f, 0.f, 0.f};
    #pragma unroll
    for (int q = 0; q < 4; ++q) {
        int j = lane + 64 * q;
        float y = (tv[q] - mean) * rstd * lng[j] + lnb[j];
        y = fmaxf(y, 0.f);
        #pragma unroll
        for (int e = 0; e < NEXP; ++e) le[e] += y * rW2[j * NEXP + e];
    }
    #pragma unroll
    for (int e = 0; e < NEXP; ++e)
        for (int o = 32; o; o >>= 1) le[e] += __shfl_xor(le[e], o);
    if (lane == 0) {
        float p[NEXP];
        float m = -1e30f;
        #pragma unroll
        for (int e = 0; e < NEXP; ++e) {
            float d = ln - centers[e];
            float lv = 0.7f * (le[e] + rb2[e]) + 0.3f * (-(d * d));
            p[e] = lv;
            m = fmaxf(m, lv);
        }
        float ssum = 0.f;
        #pragma unroll
        for (int e = 0; e < NEXP; ++e) { p[e] = expf(p[e] - m); ssum += p[e]; }
        #pragma unroll
        for (int e = 0; e < NEXP; ++e) p[e] /= ssum;
        int i1 = 0;
        for (int e = 1; e < NEXP; ++e) if (p[e] > p[i1]) i1 = e;
        int i2 = -1;
        for (int e = 0; e < NEXP; ++e) { if (e == i1) continue; if (i2 < 0 || p[e] > p[i2]) i2 = e; }
        float denom = p[i1] + p[i2] + 1e-8f;
        float out4[NEXP] = {0.f, 0.f, 0.f, 0.f};
        out4[i1] = p[i1] / denom;
        out4[i2] = p[i2] / denom;
        #pragma unroll
        for (int e = 0; e < NEXP; ++e) w[(long)n * NEXP + e] = out4[e];
    }
}

// ---------------- CSR build ----------------
__global__ void count_dst_kernel(const int* __restrict__ ei, int E, int* __restrict__ cnt) {
    int i = blockIdx.x * blockDim.x + threadIdx.x;
    if (i < E) atomicAdd(&cnt[ei[E + i]], 1);
}

__global__ __launch_bounds__(1024)
void scan_kernel(const int* __restrict__ cnt, int* __restrict__ row_ptr, int n) {
    __shared__ int buf[1024];
    __shared__ int carry_s;
    int tid = threadIdx.x;
    if (tid == 0) carry_s = 0;
    __syncthreads();
    for (int base = 0; base < n; base += 1024) {
        int v = (base + tid < n) ? cnt[base + tid] : 0;
        buf[tid] = v;
        __syncthreads();
        for (int off = 1; off < 1024; off <<= 1) {
            int tv = (tid >= off) ? buf[tid - off] : 0;
            __syncthreads();
            buf[tid] += tv;
            __syncthreads();
        }
        int carry = carry_s;
        if (base + tid < n) row_ptr[base + tid] = carry + buf[tid] - v;
        __syncthreads();
        if (tid == 1023) carry_s = carry + buf[1023];
        __syncthreads();
    }
    if (tid == 0) row_ptr[n] = carry_s;
}

__global__ void fill_csr_kernel(const int* __restrict__ ei, int E, const int* __restrict__ row_ptr,
                                int* __restrict__ fillc, int* __restrict__ srcs) {
    int i = blockIdx.x * blockDim.x + threadIdx.x;
    if (i < E) {
        int d = ei[E + i];
        int pos = row_ptr[d] + atomicAdd(&fillc[d], 1);
        srcs[pos] = ei[i];
    }
}

// ---------------- flat CSR gather bf16 (agg_h), wave/node, edge-unrolled x4 (verified R9) ----------------
__global__ __launch_bounds__(256)
void agg_b2b_kernel(const ushort_t* __restrict__ feat, ushort_t* __restrict__ outp,
                    const int* __restrict__ rp, const int* __restrict__ srcs, int N) {
    int wave = threadIdx.x >> 6, lane = threadIdx.x & 63;
    int n = blockIdx.x * 4 + wave;
    if (n >= N) return;
    float a0 = 0.f, a1 = 0.f, a2 = 0.f, a3 = 0.f;
    int p0 = rp[n], p1 = rp[n + 1];
    const ushort_t* base = feat + lane * 4;
    int p = p0;
    for (; p + 3 < p1; p += 4) {
        uint2 v0 = *(const uint2*)(base + (long)srcs[p] * H_DIM);
        uint2 v1 = *(const uint2*)(base + (long)srcs[p + 1] * H_DIM);
        uint2 v2 = *(const uint2*)(base + (long)srcs[p + 2] * H_DIM);
        uint2 v3 = *(const uint2*)(base + (long)srcs[p + 3] * H_DIM);
        a0 += bf2f((ushort_t)(v0.x & 0xffff)) + bf2f((ushort_t)(v1.x & 0xffff))
            + bf2f((ushort_t)(v2.x & 0xffff)) + bf2f((ushort_t)(v3.x & 0xffff));
        a1 += bf2f((ushort_t)(v0.x >> 16)) + bf2f((ushort_t)(v1.x >> 16))
            + bf2f((ushort_t)(v2.x >> 16)) + bf2f((ushort_t)(v3.x >> 16));
        a2 += bf2f((ushort_t)(v0.y & 0xffff)) + bf2f((ushort_t)(v1.y & 0xffff))
            + bf2f((ushort_t)(v2.y & 0xffff)) + bf2f((ushort_t)(v3.y & 0xffff));
        a3 += bf2f((ushort_t)(v0.y >> 16)) + bf2f((ushort_t)(v1.y >> 16))
            + bf2f((ushort_t)(v2.y >> 16)) + bf2f((ushort_t)(v3.y >> 16));
    }
    for (; p < p1; ++p) {
        uint2 v = *(const uint2*)(base + (long)srcs[p] * H_DIM);
        a0 += bf2f((ushort_t)(v.x & 0xffff));
        a1 += bf2f((ushort_t)(v.x >> 16));
        a2 += bf2f((ushort_t)(v.y & 0xffff));
        a3 += bf2f((ushort_t)(v.y >> 16));
    }
    uint2 o;
    o.x = (uint_t)f2bf(a0) | ((uint_t)f2bf(a1) << 16);
    o.y = (uint_t)f2bf(a2) | ((uint_t)f2bf(a3) << 16);
    *(uint2*)(outp + (long)n * H_DIM + lane * 4) = o;
}

// ---------------- interleaved CSR gather, 16B/lane: feat [n][W] bf16; block = W/8 threads ----------------
__global__ void aggI_kernel(const ushort_t* __restrict__ feat, ushort_t* __restrict__ outp,
                            const int* __restrict__ rp, const int* __restrict__ srcs,
                            int N, int W) {
    int n = blockIdx.x;
    int t = threadIdx.x;                      // t < W/8, 8 bf16 per thread
    float a[8] = {0.f, 0.f, 0.f, 0.f, 0.f, 0.f, 0.f, 0.f};
    int p0 = rp[n], p1 = rp[n + 1];
    const ushort_t* base = feat + t * 8;
    int p = p0;
    for (; p + 3 < p1; p += 4) {
        uint4 v0 = *(const uint4*)(base + (long)srcs[p] * W);
        uint4 v1 = *(const uint4*)(base + (long)srcs[p + 1] * W);
        uint4 v2 = *(const uint4*)(base + (long)srcs[p + 2] * W);
        uint4 v3 = *(const uint4*)(base + (long)srcs[p + 3] * W);
        uint_t w0[4] = {v0.x, v0.y, v0.z, v0.w};
        uint_t w1[4] = {v1.x, v1.y, v1.z, v1.w};
        uint_t w2[4] = {v2.x, v2.y, v2.z, v2.w};
        uint_t w3[4] = {v3.x, v3.y, v3.z, v3.w};
        #pragma unroll
        for (int q = 0; q < 4; ++q) {
            a[2 * q]     += bf2f((ushort_t)(w0[q] & 0xffff)) + bf2f((ushort_t)(w1[q] & 0xffff))
                          + bf2f((ushort_t)(w2[q] & 0xffff)) + bf2f((ushort_t)(w3[q] & 0xffff));
            a[2 * q + 1] += bf2f((ushort_t)(w0[q] >> 16)) + bf2f((ushort_t)(w1[q] >> 16))
                          + bf2f((ushort_t)(w2[q] >> 16)) + bf2f((ushort_t)(w3[q] >> 16));
        }
    }
    for (; p < p1; ++p) {
        uint4 v = *(const uint4*)(base + (long)srcs[p] * W);
        uint_t w[4] = {v.x, v.y, v.z, v.w};
        #pragma unroll
        for (int q = 0; q < 4; ++q) {
            a[2 * q]     += bf2f((ushort_t)(w[q] & 0xffff));
            a[2 * q + 1] += bf2f((ushort_t)(w[q] >> 16));
        }
    }
    uint4 o;
    o.x = (uint_t)f2bf(a[0]) | ((uint_t)f2bf(a[1]) << 16);
    o.y = (uint_t)f2bf(a[2]) | ((uint_t)f2bf(a[3]) << 16);
    o.z = (uint_t)f2bf(a[4]) | ((uint_t)f2bf(a[5]) << 16);
    o.w = (uint_t)f2bf(a[6]) | ((uint_t)f2bf(a[7]) << 16);
    *(uint4*)(outp + (long)n * W + t * 8) = o;
}

// ---------------- final mix on interleaved PR rows [n][z][256] (P cols 0..127, R 128..255) ----------------
__global__ __launch_bounds__(256)
void final_mixE_kernel(const ushort_t* __restrict__ PR, const float* __restrict__ b2,
                       const float* __restrict__ wts, int e0, int EB,
                       const int* __restrict__ rp, const int* __restrict__ srcs,
                       float* __restrict__ out, int N, int init) {
    int wave = threadIdx.x >> 6, lane = threadIdx.x & 63;
    int n = blockIdx.x * 4 + wave;
    if (n >= N) return;
    const int W = EB * 256;
    int c0 = lane * 2;
    long obase = (long)n * O_DIM + c0;
    float o0 = init ? 0.f : out[obase];
    float o1 = init ? 0.f : out[obase + 1];
    int zs[2]; float wv[2]; int na = 0;
    for (int z = 0; z < EB; ++z) {
        float w = wts[(long)n * NEXP + e0 + z];
        if (w != 0.f && na < 2) { zs[na] = z; wv[na] = w; ++na; }
    }
    if (na) {
        const ushort_t* P0 = PR + zs[0] * 256 + c0;
        const ushort_t* P1 = PR + zs[na - 1] * 256 + c0;
        float a00 = 0.f, a01 = 0.f, a10 = 0.f, a11 = 0.f;
        int p0 = rp[n], p1 = rp[n + 1];
        if (na == 2) {
            int p = p0;
            for (; p + 1 < p1; p += 2) {
                long s0 = (long)srcs[p] * W;
                long s1 = (long)srcs[p + 1] * W;
                uint_t v00 = *(const uint_t*)(P0 + s0);
                uint_t v10 = *(const uint_t*)(P1 + s0);
                uint_t v01 = *(const uint_t*)(P0 + s1);
                uint_t v11 = *(const uint_t*)(P1 + s1);
                a00 += bf2f((ushort_t)(v00 & 0xffff)) + bf2f((ushort_t)(v01 & 0xffff));
                a01 += bf2f((ushort_t)(v00 >> 16))    + bf2f((ushort_t)(v01 >> 16));
                a10 += bf2f((ushort_t)(v10 & 0xffff)) + bf2f((ushort_t)(v11 & 0xffff));
                a11 += bf2f((ushort_t)(v10 >> 16))    + bf2f((ushort_t)(v11 >> 16));
            }
            if (p < p1) {
                long s = (long)srcs[p] * W;
                uint_t v0 = *(const uint_t*)(P0 + s);
                uint_t v1 = *(const uint_t*)(P1 + s);
                a00 += bf2f((ushort_t)(v0 & 0xffff)); a01 += bf2f((ushort_t)(v0 >> 16));
                a10 += bf2f((ushort_t)(v1 & 0xffff)); a11 += bf2f((ushort_t)(v1 >> 16));
            }
        } else {
            int p = p0;
            for (; p + 3 < p1; p += 4) {
                uint_t v0 = *(const uint_t*)(P0 + (long)srcs[p] * W);
                uint_t v1 = *(const uint_t*)(P0 + (long)srcs[p + 1] * W);
                uint_t v2 = *(const uint_t*)(P0 + (long)srcs[p + 2] * W);
                uint_t v3 = *(const uint_t*)(P0 + (long)srcs[p + 3] * W);
                a00 += bf2f((ushort_t)(v0 & 0xffff)) + bf2f((ushort_t)(v1 & 0xffff))
                     + bf2f((ushort_t)(v2 & 0xffff)) + bf2f((ushort_t)(v3 & 0xffff));
                a01 += bf2f((ushort_t)(v0 >> 16)) + bf2f((ushort_t)(v1 >> 16))
                     + bf2f((ushort_t)(v2 >> 16)) + bf2f((ushort_t)(v3 >> 16));
            }
            for (; p < p1; ++p) {
                uint_t v = *(const uint_t*)(P0 + (long)srcs[p] * W);
                a00 += bf2f((ushort_t)(v & 0xffff)); a01 += bf2f((ushort_t)(v >> 16));
            }
        }
        {
            int e = e0 + zs[0];
            uint_t rv = *(const uint_t*)(PR + (long)n * W + zs[0] * 256 + 128 + c0);
            o0 += wv[0] * (a00 + bf2f((ushort_t)(rv & 0xffff)) + b2[e * O_DIM + c0]);
            o1 += wv[0] * (a01 + bf2f((ushort_t)(rv >> 16))    + b2[e * O_DIM + c0 + 1]);
        }
        if (na == 2) {
            int e = e0 + zs[1];
            uint_t rv = *(const uint_t*)(PR + (long)n * W + zs[1] * 256 + 128 + c0);
            o0 += wv[1] * (a10 + bf2f((ushort_t)(rv & 0xffff)) + b2[e * O_DIM + c0]);
            o1 += wv[1] * (a11 + bf2f((ushort_t)(rv >> 16))    + b2[e * O_DIM + c0 + 1]);
        }
    }
    out[obase] = o0;
    out[obase + 1] = o1;
}

// ==================== host launcher ====================
extern "C" void kernel_launch(void* const* d_in, const int* in_sizes, int n_in,
                              void* d_out, int out_size, void* d_ws, size_t ws_size,
                              hipStream_t stream) {
    const float* x       = (const float*)d_in[0];
    const int*   ei      = (const int*)  d_in[1];
    const int*   batch   = (const int*)  d_in[2];
    const float* enc_W1  = (const float*)d_in[3];
    const float* enc_b1  = (const float*)d_in[4];
    const float* enc_W2  = (const float*)d_in[5];
    const float* enc_b2  = (const float*)d_in[6];
    const float* r_W1    = (const float*)d_in[7];
    const float* r_b1    = (const float*)d_in[8];
    const float* ln_g    = (const float*)d_in[9];
    const float* ln_b    = (const float*)d_in[10];
    const float* r_W2    = (const float*)d_in[11];
    const float* r_b2    = (const float*)d_in[12];
    const float* centers = (const float*)d_in[13];
    const float* W0_rel  = (const float*)d_in[14];
    const float* b0_rel  = (const float*)d_in[15];
    const float* W0_root = (const float*)d_in[16];
    const float* W1_rel  = (const float*)d_in[17];
    const float* b1_rel  = (const float*)d_in[18];
    const float* W1_root = (const float*)d_in[19];
    const float* W2_rel  = (const float*)d_in[20];
    const float* b2_rel  = (const float*)d_in[21];
    const float* W2_root = (const float*)d_in[22];

    const int N = in_sizes[2];
    const int E = in_sizes[1] / 2;
    const int F = in_sizes[0] / N;

    // ---- workspace layout (256B-aligned slabs) ----
    char* ws = (char*)d_ws;
    size_t off = 0;
    auto alloc = [&](size_t bytes) -> void* {
        void* p = ws + off;
        off += (bytes + 255) & ~(size_t)255;
        return p;
    };
    int* cnt      = (int*)alloc((size_t)N * 4);
    int* fillc    = (int*)alloc((size_t)N * 4);
    int* gn       = (int*)alloc((size_t)G_DIM * 4);
    int* ge       = (int*)alloc((size_t)G_DIM * 4);
    size_t zero_bytes = off;
    int* row_ptr  = (int*)alloc((size_t)(N + 1) * 4);
    int* srcs     = (int*)alloc((size_t)E * 4);
    float* feats_norm = (float*)alloc((size_t)G_DIM * 3 * 4);
    float* logn_norm  = (float*)alloc((size_t)G_DIM * 4);
    float* wts    = (float*)alloc((size_t)N * NEXP * 4);
    // fused bf16 weights
    ushort_t* wf0  = (ushort_t*)alloc((size_t)NEXP * 131072 * 2);
    ushort_t* wf1  = (ushort_t*)alloc((size_t)NEXP * 131072 * 2);
    ushort_t* wfin = (ushort_t*)alloc((size_t)NEXP * 65536 * 2);
    // persistent bf16 activations
    const long sE = (long)N * H_DIM;               // elements per expert slab
    ushort_t* h_bf    = (ushort_t*)alloc((size_t)sE * 2);
    ushort_t* aggh_bf = (ushort_t*)alloc((size_t)sE * 2);
    // adaptive expert batch: 4 if workspace allows, else 2 (proven footprint)
    size_t fixed_end = off;
    size_t slab4 = ((size_t)4 * sE * 2 + 255) & ~(size_t)255;
    int EB = (ws_size >= fixed_end + 3 * slab4 + (1u << 20)) ? 4 : 2;
    size_t slab = ((size_t)EB * sE * 2 + 255) & ~(size_t)255;
    ushort_t* S1 = (ushort_t*)alloc(slab);   // u(fp32) -> hE0 [n][z][h]
    ushort_t* S2 = (ushort_t*)alloc(slab);   // h(fp32) -> aggE -> PR [n][z][h]
    ushort_t* S3 = (ushort_t*)alloc(slab);   // t(fp32) -> hE1 [n][z][h]
    (void)out_size; (void)n_in;

    float* u    = (float*)S1;
    float* h    = (float*)S2;
    float* tf32 = (float*)S3;
    ushort_t* hE0  = S1;
    ushort_t* aggE = S2;
    ushort_t* hE1  = S3;
    ushort_t* PR   = S2;
    float* out = (float*)d_out;

    const int W  = EB * 256;                 // interleaved row width (elements)
    dim3 blk256(256);
    dim3 gR((N + 63) / 64, H_DIM / 64, 1);   // fp32 SGEMM grid (router path)
    dim3 gM((N + 127) / 128, 2, EB);         // MFMA grid
    dim3 gAgg((N + 3) / 4);

    // 0) zero counters
    {
        long nz = (long)(zero_bytes / 4);
        zero_i_kernel<<<dim3((nz + 255) / 256), blk256, 0, stream>>>((int*)ws, nz);
    }
    // 0b) fused weight prep (single bf16)
    wsplit2_kernel<<<dim3(512, NEXP), blk256, 0, stream>>>(W0_rel, W0_root, wf0);
    wsplit2_kernel<<<dim3(512, NEXP), blk256, 0, stream>>>(W1_rel, W1_root, wf1);
    wsplitcat_kernel<<<dim3(256, NEXP), blk256, 0, stream>>>(W2_rel, W2_root, wfin);
    // 1) encoder stage 1 -> u
    encoder1_kernel<<<dim3(N), blk256, 0, stream>>>(x, enc_W1, enc_b1, u, N, F);
    // 2) h = u @ enc_W2 + enc_b2 (fp32 SGEMM + bf16 shadow)
    gemm256_kernel<<<gR, blk256, 0, stream>>>(u, enc_W2, enc_b2, h, h_bf, N, H_DIM);
    // 3-5) graph stats
    hist_nodes_kernel<<<dim3(256), blk256, 0, stream>>>(batch, N, gn);
    hist_edges_kernel<<<dim3(512), blk256, 0, stream>>>(ei, batch, E, ge);
    graph_stats_kernel<<<dim3(1), dim3(64), 0, stream>>>(gn, ge, feats_norm, logn_norm);
    // 6) t = h @ r_W1[0:256,:] (fp32 SGEMM)
    gemm256_kernel<<<gR, blk256, 0, stream>>>(h, r_W1, nullptr, tf32, nullptr, N, H_DIM);
    // 7) router epilogue -> wts
    router_epi_kernel<<<dim3((N + 3) / 4), blk256, 0, stream>>>(
        tf32, batch, feats_norm, logn_norm, r_W1, r_b1, ln_g, ln_b, r_W2, r_b2, centers, wts, N);
    // 8-10) CSR build
    count_dst_kernel<<<dim3((E + 255) / 256), blk256, 0, stream>>>(ei, E, cnt);
    scan_kernel<<<dim3(1), dim3(1024), 0, stream>>>(cnt, row_ptr, N);
    fill_csr_kernel<<<dim3((E + 255) / 256), blk256, 0, stream>>>(ei, E, row_ptr, fillc, srcs);
    // 11) agg_h = Agg(h_bf)  (flat gather)
    agg_b2b_kernel<<<gAgg, blk256, 0, stream>>>(h_bf, aggh_bf, row_ptr, srcs, N);

    // ---- expert pipeline, EB experts per dispatch, interleaved [n][z][h] slabs ----
    for (int b = 0; b < NEXP / EB; ++b) {
        const int e0 = b * EB;
        // hE0[n][z] = relu([agg_h | h] @ [W0_rel;W0_root]^T + b0)   (A shared across z)
        gemm_bf_kernel<2><<<gM, blk256, 0, stream>>>(
            aggh_bf, 0, 256, h_bf, 0, 256,
            wf0 + (long)e0 * 131072, 131072,
            b0_rel + e0 * H_DIM, H_DIM, hE0, 256, W, N, 512, 1);
        // aggE[n][z] = Agg(hE0)
        aggI_kernel<<<dim3(N), dim3(W / 8), 0, stream>>>(hE0, aggE, row_ptr, srcs, N, W);
        // hE1[n][z] = relu([aggE | hE0] @ [W1_rel;W1_root]^T + b1)
        gemm_bf_kernel<2><<<gM, blk256, 0, stream>>>(
            aggE, 256, W, hE0, 256, W,
            wf1 + (long)e0 * 131072, 131072,
            b1_rel + e0 * H_DIM, H_DIM, hE1, 256, W, N, 512, 1);
        // PR[n][z] = hE1 @ [W2_rel|W2_root]^T   (overlay onto dead aggE)
        gemm_bf_kernel<1><<<gM, blk256, 0, stream>>>(
            hE1, 256, W, nullptr, 0, 256,
            wfin + (long)e0 * 65536, 65536,
            nullptr, 0, PR, 256, W, N, 256, 0);
        // out (+)= sum_z w[:,e0+z] * (Agg(P[z]) + R[z] + b2[e0+z])
        final_mixE_kernel<<<gAgg, blk256, 0, stream>>>(
            PR, b2_rel, wts, e0, EB, row_ptr, srcs, out, N, b == 0 ? 1 : 0);
    }
}

// Round 11
// 1262.870 us; speedup vs baseline: 3.2731x; 1.0245x over previous
//
#include <hip/hip_runtime.h>
#include <hip/hip_bf16.h>

// ---------------- problem constants ----------------
#define H_DIM 256
#define O_DIM 128
#define NEXP 4
#define G_DIM 64

typedef unsigned short ushort_t;
typedef unsigned int uint_t;
typedef __attribute__((ext_vector_type(8))) short short8;
typedef __attribute__((ext_vector_type(4))) float floatx4;

// ---------------- bf16 helpers (RNE) ----------------
__device__ __forceinline__ float bf2f(ushort_t u) {
    union { uint_t i; float f; } c; c.i = ((uint_t)u) << 16; return c.f;
}
__device__ __forceinline__ ushort_t f2bf(float f) {
    union { float f; uint_t i; } c; c.f = f;
    uint_t x = c.i;
    uint_t r = (x + 0x7fffu + ((x >> 16) & 1u)) >> 16;
    return (ushort_t)r;
}

// ---------------- async global->LDS 16B ----------------
__device__ __forceinline__ void load16_lds(const void* g, void* l) {
    __builtin_amdgcn_global_load_lds(
        (const __attribute__((address_space(1))) unsigned int*)g,
        (__attribute__((address_space(3))) unsigned int*)l, 16, 0, 0);
}

// ---------------- utility: zero ints ----------------
__global__ void zero_i_kernel(int* __restrict__ p, long n) {
    long i = (long)blockIdx.x * blockDim.x + threadIdx.x;
    if (i < n) p[i] = 0;
}

// ---------------- fused weight prep (single bf16, transposed) ----------------
__global__ void wsplit2_kernel(const float* __restrict__ Wa, const float* __restrict__ Wb,
                               ushort_t* __restrict__ Wh) {
    int z = blockIdx.y;
    int i = blockIdx.x * 256 + threadIdx.x;        // 256n * 512k
    if (i >= 131072) return;
    int nn = i >> 9, kk = i & 511;
    float v = (kk < 256) ? Wa[(long)z * 65536 + kk * 256 + nn]
                         : Wb[(long)z * 65536 + (kk - 256) * 256 + nn];
    Wh[(long)z * 131072 + i] = f2bf(v);
}

__global__ void wsplitcat_kernel(const float* __restrict__ Wa, const float* __restrict__ Wb,
                                 ushort_t* __restrict__ Wh) {
    int z = blockIdx.y;
    int i = blockIdx.x * 256 + threadIdx.x;        // 256n * 256k
    if (i >= 65536) return;
    int nn = i >> 8, kk = i & 255;
    float v = (nn < 128) ? Wa[(long)z * 32768 + kk * 128 + nn]
                         : Wb[(long)z * 32768 + kk * 128 + (nn - 128)];
    Wh[(long)z * 65536 + i] = f2bf(v);
}

// ---------------- encoder stage 1 (fp32, verified) ----------------
__global__ void encoder1_kernel(const float* __restrict__ x, const float* __restrict__ W1,
                                const float* __restrict__ b1, float* __restrict__ u,
                                int N, int F) {
    int n = blockIdx.x;
    int j = threadIdx.x;
    float acc = b1[j];
    #pragma unroll
    for (int c = 0; c < 6; ++c)
        acc += x[(long)n * F + 4 + c] * W1[c * H_DIM + j];
    u[(long)n * H_DIM + j] = fmaxf(acc, 0.f);
}

// ---------------- fp32 vector SGEMM (router path — DO NOT CHANGE: top-2 flip risk) ----------------
__global__ __launch_bounds__(256)
void gemm256_kernel(const float* __restrict__ A, const float* __restrict__ W,
                    const float* __restrict__ bias, float* __restrict__ C,
                    ushort_t* __restrict__ Cbf, int M, int Nc) {
    const int K = 256;
    __shared__ float As[16][68];
    __shared__ float Ws[16][68];
    int tid = threadIdx.x;
    int tx = tid & 15, ty = tid >> 4;
    int row0 = blockIdx.x * 64;
    int col0 = blockIdx.y * 64;
    float acc[4][4] = {};
    int lrow = tid >> 2, kq = tid & 3;
    int wk = tid >> 4, wc = (tid & 15) * 4;
    for (int k0 = 0; k0 < K; k0 += 16) {
        float4 av = make_float4(0.f, 0.f, 0.f, 0.f);
        int arow = row0 + lrow;
        if (arow < M) av = *(const float4*)(A + (long)arow * K + k0 + kq * 4);
        As[kq * 4 + 0][lrow] = av.x;
        As[kq * 4 + 1][lrow] = av.y;
        As[kq * 4 + 2][lrow] = av.z;
        As[kq * 4 + 3][lrow] = av.w;
        float4 wv = *(const float4*)(W + (long)(k0 + wk) * Nc + col0 + wc);
        *(float4*)&Ws[wk][wc] = wv;
        __syncthreads();
        #pragma unroll
        for (int kk = 0; kk < 16; ++kk) {
            float a[4], b[4];
            #pragma unroll
            for (int i = 0; i < 4; ++i) a[i] = As[kk][ty * 4 + i];
            #pragma unroll
            for (int j = 0; j < 4; ++j) b[j] = Ws[kk][tx * 4 + j];
            #pragma unroll
            for (int i = 0; i < 4; ++i)
                #pragma unroll
                for (int j = 0; j < 4; ++j) acc[i][j] += a[i] * b[j];
        }
        __syncthreads();
    }
    #pragma unroll
    for (int i = 0; i < 4; ++i) {
        int r = row0 + ty * 4 + i;
        if (r >= M) break;
        #pragma unroll
        for (int j = 0; j < 4; ++j) {
            int c = col0 + tx * 4 + j;
            float v = acc[i][j];
            if (bias) v += bias[c];
            C[(long)r * Nc + c] = v;
            if (Cbf) Cbf[(long)r * Nc + c] = f2bf(v);
        }
    }
}

// ---------------- bf16 MFMA GEMM, 64x128 tile, double-buffered, z-batched ----------------
// C[z] = [relu]( sum_halves A_half[z](bf16) @ B[z]^T + [bias[z]] ); B fused (Nc=256, Kb) bf16.
// 64x128 tile, BK=32, 4 waves (2x2, wave tile 32x64), 2x4 frags of 16x16x32.
// LDS 24 KB -> ~6 resident blocks/CU; grid 2x vs 128-tile -> latency hidden by TLP.
// Add-rotate LDS swizzle (modulo-4 algebra verified R6-R10).
template<int NH>
__global__ __launch_bounds__(256)
void gemm_bf_kernel(const ushort_t* __restrict__ A1, long sA1z, int rsA1,
                    const ushort_t* __restrict__ A2, long sA2z, int rsA2,
                    const ushort_t* __restrict__ B, long sBz,
                    const float* __restrict__ bias, int sBiasz,
                    ushort_t* __restrict__ Cbf, long sCz, int rsC,
                    int M, int Kb, int relu) {
    __shared__ alignas(16) ushort_t Asl[2][64 * 32];
    __shared__ alignas(16) ushort_t Bsl[2][128 * 32];

    const int tid = threadIdx.x, wave = tid >> 6, lane = tid & 63;
    const int z = blockIdx.z;
    const int row0 = blockIdx.x * 64, col0 = blockIdx.y * 128;
    const int wr = (wave >> 1) * 32, wcx = (wave & 1) * 64;
    floatx4 acc[2][4] = {};

    A1 += (long)z * sA1z;
    A2 += (long)z * sA2z;
    B += (long)z * sBz;
    if (bias) bias += (long)z * sBiasz;
    Cbf += (long)z * sCz;

    // staging map: 4 lanes/row (4x16B chunks), add-rotate swizzle
    const int bsr = lane >> 2;                    // row in group of 16
    const int bgc = ((lane & 3) - (bsr >> 1)) & 3;
    long aoff1, aoff2;
    {
        int ar = row0 + wave * 16 + bsr;          // A: 16 rows per wave
        ar = ar < M ? ar : M - 1;
        aoff1 = (long)ar * rsA1 + bgc * 8;
        aoff2 = (long)ar * rsA2 + bgc * 8;
    }
    const long brow = (long)(col0 + wave * 32 + bsr) * Kb + bgc * 8;
    const ushort_t* Bg0 = B + brow;
    const ushort_t* Bg1 = B + brow + (long)16 * Kb;
    const int laA  = (wave * 16) * 32;
    const int laB0 = (wave * 32) * 32;
    const int laB1 = (wave * 32 + 16) * 32;

    const int fm = lane & 15, fq = lane >> 4;
    const int NK = NH * 8;

    // stage k=0 into buffer 0
    load16_lds(A1 + aoff1, &Asl[0][laA]);
    load16_lds(Bg0, &Bsl[0][laB0]);
    load16_lds(Bg1, &Bsl[0][laB1]);
    __syncthreads();

    for (int k = 0; k < NK; ++k) {
        const int buf = k & 1;
        short8 a[2], b[4];
        #pragma unroll
        for (int j = 0; j < 4; ++j) {
            int row = wcx + j * 16 + fm;
            int slot = (fq + ((row >> 1) & 3)) & 3;
            b[j] = *(const short8*)&Bsl[buf][row * 32 + slot * 8];
        }
        #pragma unroll
        for (int i = 0; i < 2; ++i) {
            int row = wr + i * 16 + fm;
            int slot = (fq + ((row >> 1) & 3)) & 3;
            a[i] = *(const short8*)&Asl[buf][row * 32 + slot * 8];
        }
        if (k + 1 < NK) {
            const int kn = k + 1, bn = kn & 1;
            const ushort_t* Ab = (kn >> 3) ? A2 : A1;
            const long ao = (kn >> 3) ? aoff2 : aoff1;
            const int k0 = (kn & 7) * 32;          // within-half A offset
            const int kk = kn * 32;                // fused-K B offset
            load16_lds(Ab + ao + k0, &Asl[bn][laA]);
            load16_lds(Bg0 + kk, &Bsl[bn][laB0]);
            load16_lds(Bg1 + kk, &Bsl[bn][laB1]);
        }
        #pragma unroll
        for (int i = 0; i < 2; ++i)
            #pragma unroll
            for (int j = 0; j < 4; ++j)
                acc[i][j] = __builtin_amdgcn_mfma_f32_16x16x32_bf16(a[i], b[j], acc[i][j], 0, 0, 0);
        if (k + 1 < NK) __syncthreads();
    }

    // epilogue: C/D layout col=lane&15, row=(lane>>4)*4+reg  [verified m89]
    #pragma unroll
    for (int i = 0; i < 2; ++i) {
        #pragma unroll
        for (int j = 0; j < 4; ++j) {
            int col = col0 + wcx + j * 16 + fm;
            int rowb = row0 + wr + i * 16 + fq * 4;
            #pragma unroll
            for (int r = 0; r < 4; ++r) {
                int row = rowb + r;
                if (row < M) {
                    float v = acc[i][j][r];
                    if (bias) v += bias[col];
                    if (relu) v = fmaxf(v, 0.f);
                    Cbf[(long)row * rsC + col] = f2bf(v);
                }
            }
        }
    }
}

// ---------------- graph-stat histograms ----------------
__global__ void hist_nodes_kernel(const int* __restrict__ batch, int n, int* __restrict__ gn) {
    __shared__ int bins[G_DIM];
    int t = threadIdx.x;
    if (t < G_DIM) bins[t] = 0;
    __syncthreads();
    for (long i = (long)blockIdx.x * blockDim.x + t; i < n; i += (long)gridDim.x * blockDim.x)
        atomicAdd(&bins[batch[i]], 1);
    __syncthreads();
    if (t < G_DIM) atomicAdd(&gn[t], bins[t]);
}

__global__ void hist_edges_kernel(const int* __restrict__ ei, const int* __restrict__ batch,
                                  int E, int* __restrict__ ge) {
    __shared__ int bins[G_DIM];
    int t = threadIdx.x;
    if (t < G_DIM) bins[t] = 0;
    __syncthreads();
    for (long i = (long)blockIdx.x * blockDim.x + t; i < E; i += (long)gridDim.x * blockDim.x)
        atomicAdd(&bins[batch[ei[i]]], 1);
    __syncthreads();
    if (t < G_DIM) atomicAdd(&ge[t], bins[t]);
}

// ---------------- graph stats ----------------
__global__ void graph_stats_kernel(const int* __restrict__ gn, const int* __restrict__ ge,
                                   float* __restrict__ feats_norm, float* __restrict__ logn_norm) {
    int g = threadIdx.x;
    float nv = fmaxf((float)gn[g], 1.0f);
    float ev = (float)ge[g];
    float density = ev / fmaxf(nv * (nv - 1.0f), 1.0f);
    float logn = logf(nv);
    float mn = logn, mx = logn;
    for (int o = 32; o; o >>= 1) {
        mn = fminf(mn, __shfl_xor(mn, o));
        mx = fmaxf(mx, __shfl_xor(mx, o));
    }
    logn_norm[g] = (logn - mn) / (mx - mn + 1e-6f);
    float f[3] = {nv, ev, density};
    #pragma unroll
    for (int c = 0; c < 3; ++c) {
        float s = f[c];
        for (int o = 32; o; o >>= 1) s += __shfl_xor(s, o);
        float mean = s / 64.f;
        float d = f[c] - mean;
        float v = d * d;
        for (int o = 32; o; o >>= 1) v += __shfl_xor(v, o);
        float stdv = sqrtf(v / 64.f);
        feats_norm[g * 3 + c] = d / (stdv + 1e-6f);
    }
}

// ---------------- router epilogue (verified) ----------------
__global__ __launch_bounds__(256)
void router_epi_kernel(const float* __restrict__ t, const int* __restrict__ batch,
                       const float* __restrict__ feats_norm, const float* __restrict__ logn_norm,
                       const float* __restrict__ rW1, const float* __restrict__ rb1,
                       const float* __restrict__ lng, const float* __restrict__ lnb,
                       const float* __restrict__ rW2, const float* __restrict__ rb2,
                       const float* __restrict__ centers, float* __restrict__ w, int N) {
    int wave = threadIdx.x >> 6, lane = threadIdx.x & 63;
    int n = blockIdx.x * 4 + wave;
    if (n >= N) return;
    int g = batch[n];
    float sf0 = feats_norm[g * 3 + 0], sf1 = feats_norm[g * 3 + 1], sf2 = feats_norm[g * 3 + 2];
    float ln = logn_norm[g];
    float tv[4];
    #pragma unroll
    for (int q = 0; q < 4; ++q) {
        int j = lane + 64 * q;
        tv[q] = t[(long)n * H_DIM + j] + rb1[j]
              + sf0 * rW1[256 * H_DIM + j] + sf1 * rW1[257 * H_DIM + j] + sf2 * rW1[258 * H_DIM + j];
    }
    float s = tv[0] + tv[1] + tv[2] + tv[3];
    for (int o = 32; o; o >>= 1) s += __shfl_xor(s, o);
    float mean = s / 256.f;
    float vs = 0.f;
    #pragma unroll
    for (int q = 0; q < 4; ++q) { float d = tv[q] - mean; vs += d * d; }
    for (int o = 32; o; o >>= 1) vs += __shfl_xor(vs, o);
    float rstd = rsqrtf(vs / 256.f + 1e-5f);
    float le[NEXP] = {0.f, 0.f, 0.f, 0.f};
    #pragma unroll
    for (int q = 0; q < 4; ++q) {
        int j = lane + 64 * q;
        float y = (tv[q] - mean) * rstd * lng[j] + lnb[j];
        y = fmaxf(y, 0.f);
        #pragma unroll
        for (int e = 0; e < NEXP; ++e) le[e] += y * rW2[j * NEXP + e];
    }
    #pragma unroll
    for (int e = 0; e < NEXP; ++e)
        for (int o = 32; o; o >>= 1) le[e] += __shfl_xor(le[e], o);
    if (lane == 0) {
        float p[NEXP];
        float m = -1e30f;
        #pragma unroll
        for (int e = 0; e < NEXP; ++e) {
            float d = ln - centers[e];
            float lv = 0.7f * (le[e] + rb2[e]) + 0.3f * (-(d * d));
            p[e] = lv;
            m = fmaxf(m, lv);
        }
        float ssum = 0.f;
        #pragma unroll
        for (int e = 0; e < NEXP; ++e) { p[e] = expf(p[e] - m); ssum += p[e]; }
        #pragma unroll
        for (int e = 0; e < NEXP; ++e) p[e] /= ssum;
        int i1 = 0;
        for (int e = 1; e < NEXP; ++e) if (p[e] > p[i1]) i1 = e;
        int i2 = -1;
        for (int e = 0; e < NEXP; ++e) { if (e == i1) continue; if (i2 < 0 || p[e] > p[i2]) i2 = e; }
        float denom = p[i1] + p[i2] + 1e-8f;
        float out4[NEXP] = {0.f, 0.f, 0.f, 0.f};
        out4[i1] = p[i1] / denom;
        out4[i2] = p[i2] / denom;
        #pragma unroll
        for (int e = 0; e < NEXP; ++e) w[(long)n * NEXP + e] = out4[e];
    }
}

// ---------------- CSR build ----------------
__global__ void count_dst_kernel(const int* __restrict__ ei, int E, int* __restrict__ cnt) {
    int i = blockIdx.x * blockDim.x + threadIdx.x;
    if (i < E) atomicAdd(&cnt[ei[E + i]], 1);
}

__global__ __launch_bounds__(1024)
void scan_kernel(const int* __restrict__ cnt, int* __restrict__ row_ptr, int n) {
    __shared__ int buf[1024];
    __shared__ int carry_s;
    int tid = threadIdx.x;
    if (tid == 0) carry_s = 0;
    __syncthreads();
    for (int base = 0; base < n; base += 1024) {
        int v = (base + tid < n) ? cnt[base + tid] : 0;
        buf[tid] = v;
        __syncthreads();
        for (int off = 1; off < 1024; off <<= 1) {
            int tv = (tid >= off) ? buf[tid - off] : 0;
            __syncthreads();
            buf[tid] += tv;
            __syncthreads();
        }
        int carry = carry_s;
        if (base + tid < n) row_ptr[base + tid] = carry + buf[tid] - v;
        __syncthreads();
        if (tid == 1023) carry_s = carry + buf[1023];
        __syncthreads();
    }
    if (tid == 0) row_ptr[n] = carry_s;
}

__global__ void fill_csr_kernel(const int* __restrict__ ei, int E, const int* __restrict__ row_ptr,
                                int* __restrict__ fillc, int* __restrict__ srcs) {
    int i = blockIdx.x * blockDim.x + threadIdx.x;
    if (i < E) {
        int d = ei[E + i];
        int pos = row_ptr[d] + atomicAdd(&fillc[d], 1);
        srcs[pos] = ei[i];
    }
}

// ---------------- flat CSR gather bf16 (agg_h), wave/node, edge-unrolled x4 (verified R9) ----------------
__global__ __launch_bounds__(256)
void agg_b2b_kernel(const ushort_t* __restrict__ feat, ushort_t* __restrict__ outp,
                    const int* __restrict__ rp, const int* __restrict__ srcs, int N) {
    int wave = threadIdx.x >> 6, lane = threadIdx.x & 63;
    int n = blockIdx.x * 4 + wave;
    if (n >= N) return;
    float a0 = 0.f, a1 = 0.f, a2 = 0.f, a3 = 0.f;
    int p0 = rp[n], p1 = rp[n + 1];
    const ushort_t* base = feat + lane * 4;
    int p = p0;
    for (; p + 3 < p1; p += 4) {
        uint2 v0 = *(const uint2*)(base + (long)srcs[p] * H_DIM);
        uint2 v1 = *(const uint2*)(base + (long)srcs[p + 1] * H_DIM);
        uint2 v2 = *(const uint2*)(base + (long)srcs[p + 2] * H_DIM);
        uint2 v3 = *(const uint2*)(base + (long)srcs[p + 3] * H_DIM);
        a0 += bf2f((ushort_t)(v0.x & 0xffff)) + bf2f((ushort_t)(v1.x & 0xffff))
            + bf2f((ushort_t)(v2.x & 0xffff)) + bf2f((ushort_t)(v3.x & 0xffff));
        a1 += bf2f((ushort_t)(v0.x >> 16)) + bf2f((ushort_t)(v1.x >> 16))
            + bf2f((ushort_t)(v2.x >> 16)) + bf2f((ushort_t)(v3.x >> 16));
        a2 += bf2f((ushort_t)(v0.y & 0xffff)) + bf2f((ushort_t)(v1.y & 0xffff))
            + bf2f((ushort_t)(v2.y & 0xffff)) + bf2f((ushort_t)(v3.y & 0xffff));
        a3 += bf2f((ushort_t)(v0.y >> 16)) + bf2f((ushort_t)(v1.y >> 16))
            + bf2f((ushort_t)(v2.y >> 16)) + bf2f((ushort_t)(v3.y >> 16));
    }
    for (; p < p1; ++p) {
        uint2 v = *(const uint2*)(base + (long)srcs[p] * H_DIM);
        a0 += bf2f((ushort_t)(v.x & 0xffff));
        a1 += bf2f((ushort_t)(v.x >> 16));
        a2 += bf2f((ushort_t)(v.y & 0xffff));
        a3 += bf2f((ushort_t)(v.y >> 16));
    }
    uint2 o;
    o.x = (uint_t)f2bf(a0) | ((uint_t)f2bf(a1) << 16);
    o.y = (uint_t)f2bf(a2) | ((uint_t)f2bf(a3) << 16);
    *(uint2*)(outp + (long)n * H_DIM + lane * 4) = o;
}

// ---------------- interleaved CSR gather, 16B/lane: feat [n][W] bf16; block = W/8 threads ----------------
__global__ void aggI_kernel(const ushort_t* __restrict__ feat, ushort_t* __restrict__ outp,
                            const int* __restrict__ rp, const int* __restrict__ srcs,
                            int N, int W) {
    int n = blockIdx.x;
    int t = threadIdx.x;                      // t < W/8, 8 bf16 per thread
    float a[8] = {0.f, 0.f, 0.f, 0.f, 0.f, 0.f, 0.f, 0.f};
    int p0 = rp[n], p1 = rp[n + 1];
    const ushort_t* base = feat + t * 8;
    int p = p0;
    for (; p + 3 < p1; p += 4) {
        uint4 v0 = *(const uint4*)(base + (long)srcs[p] * W);
        uint4 v1 = *(const uint4*)(base + (long)srcs[p + 1] * W);
        uint4 v2 = *(const uint4*)(base + (long)srcs[p + 2] * W);
        uint4 v3 = *(const uint4*)(base + (long)srcs[p + 3] * W);
        uint_t w0[4] = {v0.x, v0.y, v0.z, v0.w};
        uint_t w1[4] = {v1.x, v1.y, v1.z, v1.w};
        uint_t w2[4] = {v2.x, v2.y, v2.z, v2.w};
        uint_t w3[4] = {v3.x, v3.y, v3.z, v3.w};
        #pragma unroll
        for (int q = 0; q < 4; ++q) {
            a[2 * q]     += bf2f((ushort_t)(w0[q] & 0xffff)) + bf2f((ushort_t)(w1[q] & 0xffff))
                          + bf2f((ushort_t)(w2[q] & 0xffff)) + bf2f((ushort_t)(w3[q] & 0xffff));
            a[2 * q + 1] += bf2f((ushort_t)(w0[q] >> 16)) + bf2f((ushort_t)(w1[q] >> 16))
                          + bf2f((ushort_t)(w2[q] >> 16)) + bf2f((ushort_t)(w3[q] >> 16));
        }
    }
    for (; p < p1; ++p) {
        uint4 v = *(const uint4*)(base + (long)srcs[p] * W);
        uint_t w[4] = {v.x, v.y, v.z, v.w};
        #pragma unroll
        for (int q = 0; q < 4; ++q) {
            a[2 * q]     += bf2f((ushort_t)(w[q] & 0xffff));
            a[2 * q + 1] += bf2f((ushort_t)(w[q] >> 16));
        }
    }
    uint4 o;
    o.x = (uint_t)f2bf(a[0]) | ((uint_t)f2bf(a[1]) << 16);
    o.y = (uint_t)f2bf(a[2]) | ((uint_t)f2bf(a[3]) << 16);
    o.z = (uint_t)f2bf(a[4]) | ((uint_t)f2bf(a[5]) << 16);
    o.w = (uint_t)f2bf(a[6]) | ((uint_t)f2bf(a[7]) << 16);
    *(uint4*)(outp + (long)n * W + t * 8) = o;
}

// ---------------- final mix on interleaved PR rows [n][z][256] (P cols 0..127, R 128..255) ----------------
__global__ __launch_bounds__(256)
void final_mixE_kernel(const ushort_t* __restrict__ PR, const float* __restrict__ b2,
                       const float* __restrict__ wts, int e0, int EB,
                       const int* __restrict__ rp, const int* __restrict__ srcs,
                       float* __restrict__ out, int N, int init) {
    int wave = threadIdx.x >> 6, lane = threadIdx.x & 63;
    int n = blockIdx.x * 4 + wave;
    if (n >= N) return;
    const int W = EB * 256;
    int c0 = lane * 2;
    long obase = (long)n * O_DIM + c0;
    float o0 = init ? 0.f : out[obase];
    float o1 = init ? 0.f : out[obase + 1];
    int zs[2]; float wv[2]; int na = 0;
    for (int z = 0; z < EB; ++z) {
        float w = wts[(long)n * NEXP + e0 + z];
        if (w != 0.f && na < 2) { zs[na] = z; wv[na] = w; ++na; }
    }
    if (na) {
        const ushort_t* P0 = PR + zs[0] * 256 + c0;
        const ushort_t* P1 = PR + zs[na - 1] * 256 + c0;
        float a00 = 0.f, a01 = 0.f, a10 = 0.f, a11 = 0.f;
        int p0 = rp[n], p1 = rp[n + 1];
        if (na == 2) {
            int p = p0;
            for (; p + 1 < p1; p += 2) {
                long s0 = (long)srcs[p] * W;
                long s1 = (long)srcs[p + 1] * W;
                uint_t v00 = *(const uint_t*)(P0 + s0);
                uint_t v10 = *(const uint_t*)(P1 + s0);
                uint_t v01 = *(const uint_t*)(P0 + s1);
                uint_t v11 = *(const uint_t*)(P1 + s1);
                a00 += bf2f((ushort_t)(v00 & 0xffff)) + bf2f((ushort_t)(v01 & 0xffff));
                a01 += bf2f((ushort_t)(v00 >> 16))    + bf2f((ushort_t)(v01 >> 16));
                a10 += bf2f((ushort_t)(v10 & 0xffff)) + bf2f((ushort_t)(v11 & 0xffff));
                a11 += bf2f((ushort_t)(v10 >> 16))    + bf2f((ushort_t)(v11 >> 16));
            }
            if (p < p1) {
                long s = (long)srcs[p] * W;
                uint_t v0 = *(const uint_t*)(P0 + s);
                uint_t v1 = *(const uint_t*)(P1 + s);
                a00 += bf2f((ushort_t)(v0 & 0xffff)); a01 += bf2f((ushort_t)(v0 >> 16));
                a10 += bf2f((ushort_t)(v1 & 0xffff)); a11 += bf2f((ushort_t)(v1 >> 16));
            }
        } else {
            int p = p0;
            for (; p + 3 < p1; p += 4) {
                uint_t v0 = *(const uint_t*)(P0 + (long)srcs[p] * W);
                uint_t v1 = *(const uint_t*)(P0 + (long)srcs[p + 1] * W);
                uint_t v2 = *(const uint_t*)(P0 + (long)srcs[p + 2] * W);
                uint_t v3 = *(const uint_t*)(P0 + (long)srcs[p + 3] * W);
                a00 += bf2f((ushort_t)(v0 & 0xffff)) + bf2f((ushort_t)(v1 & 0xffff))
                     + bf2f((ushort_t)(v2 & 0xffff)) + bf2f((ushort_t)(v3 & 0xffff));
                a01 += bf2f((ushort_t)(v0 >> 16)) + bf2f((ushort_t)(v1 >> 16))
                     + bf2f((ushort_t)(v2 >> 16)) + bf2f((ushort_t)(v3 >> 16));
            }
            for (; p < p1; ++p) {
                uint_t v = *(const uint_t*)(P0 + (long)srcs[p] * W);
                a00 += bf2f((ushort_t)(v & 0xffff)); a01 += bf2f((ushort_t)(v >> 16));
            }
        }
        {
            int e = e0 + zs[0];
            uint_t rv = *(const uint_t*)(PR + (long)n * W + zs[0] * 256 + 128 + c0);
            o0 += wv[0] * (a00 + bf2f((ushort_t)(rv & 0xffff)) + b2[e * O_DIM + c0]);
            o1 += wv[0] * (a01 + bf2f((ushort_t)(rv >> 16))    + b2[e * O_DIM + c0 + 1]);
        }
        if (na == 2) {
            int e = e0 + zs[1];
            uint_t rv = *(const uint_t*)(PR + (long)n * W + zs[1] * 256 + 128 + c0);
            o0 += wv[1] * (a10 + bf2f((ushort_t)(rv & 0xffff)) + b2[e * O_DIM + c0]);
            o1 += wv[1] * (a11 + bf2f((ushort_t)(rv >> 16))    + b2[e * O_DIM + c0 + 1]);
        }
    }
    out[obase] = o0;
    out[obase + 1] = o1;
}

// ==================== host launcher ====================
extern "C" void kernel_launch(void* const* d_in, const int* in_sizes, int n_in,
                              void* d_out, int out_size, void* d_ws, size_t ws_size,
                              hipStream_t stream) {
    const float* x       = (const float*)d_in[0];
    const int*   ei      = (const int*)  d_in[1];
    const int*   batch   = (const int*)  d_in[2];
    const float* enc_W1  = (const float*)d_in[3];
    const float* enc_b1  = (const float*)d_in[4];
    const float* enc_W2  = (const float*)d_in[5];
    const float* enc_b2  = (const float*)d_in[6];
    const float* r_W1    = (const float*)d_in[7];
    const float* r_b1    = (const float*)d_in[8];
    const float* ln_g    = (const float*)d_in[9];
    const float* ln_b    = (const float*)d_in[10];
    const float* r_W2    = (const float*)d_in[11];
    const float* r_b2    = (const float*)d_in[12];
    const float* centers = (const float*)d_in[13];
    const float* W0_rel  = (const float*)d_in[14];
    const float* b0_rel  = (const float*)d_in[15];
    const float* W0_root = (const float*)d_in[16];
    const float* W1_rel  = (const float*)d_in[17];
    const float* b1_rel  = (const float*)d_in[18];
    const float* W1_root = (const float*)d_in[19];
    const float* W2_rel  = (const float*)d_in[20];
    const float* b2_rel  = (const float*)d_in[21];
    const float* W2_root = (const float*)d_in[22];

    const int N = in_sizes[2];
    const int E = in_sizes[1] / 2;
    const int F = in_sizes[0] / N;

    // ---- workspace layout (256B-aligned slabs) ----
    char* ws = (char*)d_ws;
    size_t off = 0;
    auto alloc = [&](size_t bytes) -> void* {
        void* p = ws + off;
        off += (bytes + 255) & ~(size_t)255;
        return p;
    };
    int* cnt      = (int*)alloc((size_t)N * 4);
    int* fillc    = (int*)alloc((size_t)N * 4);
    int* gn       = (int*)alloc((size_t)G_DIM * 4);
    int* ge       = (int*)alloc((size_t)G_DIM * 4);
    size_t zero_bytes = off;
    int* row_ptr  = (int*)alloc((size_t)(N + 1) * 4);
    int* srcs     = (int*)alloc((size_t)E * 4);
    float* feats_norm = (float*)alloc((size_t)G_DIM * 3 * 4);
    float* logn_norm  = (float*)alloc((size_t)G_DIM * 4);
    float* wts    = (float*)alloc((size_t)N * NEXP * 4);
    // fused bf16 weights
    ushort_t* wf0  = (ushort_t*)alloc((size_t)NEXP * 131072 * 2);
    ushort_t* wf1  = (ushort_t*)alloc((size_t)NEXP * 131072 * 2);
    ushort_t* wfin = (ushort_t*)alloc((size_t)NEXP * 65536 * 2);

    const long sE = (long)N * H_DIM;               // elements per expert slab
    size_t fixed_end = off;
    size_t slab4 = ((size_t)4 * sE * 2 + 255) & ~(size_t)255;
    size_t slab2 = ((size_t)2 * sE * 2 + 255) & ~(size_t)255;
    size_t need4 = fixed_end + 3 * slab4 + (1u << 20);

    int EB;
    ushort_t *S1, *S2, *S3, *h_bf, *aggh_bf;
    float *u, *h, *tf32;
    if (ws_size >= need4) {
        // EB=4 overlay layout: h_bf/aggh_bf/t packed into S3 (die before hE1 write)
        EB = 4;
        S1 = (ushort_t*)alloc(slab4);   // u(fp32, first half) -> hE0 -> PR
        S2 = (ushort_t*)alloc(slab4);   // h(fp32, first half) -> aggE
        S3 = (ushort_t*)alloc(slab4);   // [h_bf | aggh_bf | t(fp32)] -> hE1
        u = (float*)S1; h = (float*)S2;
        h_bf = S3; aggh_bf = S3 + sE;
        tf32 = (float*)(S3 + 2 * sE);   // 51.2 MB, second half of S3
    } else {
        // EB=2 fallback (proven R10 footprint)
        EB = 2;
        h_bf    = (ushort_t*)alloc((size_t)sE * 2);
        aggh_bf = (ushort_t*)alloc((size_t)sE * 2);
        S1 = (ushort_t*)alloc(slab2);
        S2 = (ushort_t*)alloc(slab2);
        S3 = (ushort_t*)alloc(slab2);
        u = (float*)S1; h = (float*)S2; tf32 = (float*)S3;
    }
    (void)out_size; (void)n_in;

    ushort_t* hE0  = S1;
    ushort_t* aggE = S2;
    ushort_t* hE1  = S3;
    ushort_t* PR   = S1;                 // hE0 dead after GEMM1
    float* out = (float*)d_out;

    const int W  = EB * 256;             // interleaved row width (elements)
    dim3 blk256(256);
    dim3 gR((N + 63) / 64, H_DIM / 64, 1);   // fp32 SGEMM grid (router path)
    dim3 gM((N + 63) / 64, 2, EB);           // MFMA grid, 64-row tiles
    dim3 gAgg((N + 3) / 4);

    // 0) zero counters
    {
        long nz = (long)(zero_bytes / 4);
        zero_i_kernel<<<dim3((nz + 255) / 256), blk256, 0, stream>>>((int*)ws, nz);
    }
    // 0b) fused weight prep (single bf16)
    wsplit2_kernel<<<dim3(512, NEXP), blk256, 0, stream>>>(W0_rel, W0_root, wf0);
    wsplit2_kernel<<<dim3(512, NEXP), blk256, 0, stream>>>(W1_rel, W1_root, wf1);
    wsplitcat_kernel<<<dim3(256, NEXP), blk256, 0, stream>>>(W2_rel, W2_root, wfin);
    // 1) encoder stage 1 -> u
    encoder1_kernel<<<dim3(N), blk256, 0, stream>>>(x, enc_W1, enc_b1, u, N, F);
    // 2) h = u @ enc_W2 + enc_b2 (fp32 SGEMM + bf16 shadow)
    gemm256_kernel<<<gR, blk256, 0, stream>>>(u, enc_W2, enc_b2, h, h_bf, N, H_DIM);
    // 3-5) graph stats
    hist_nodes_kernel<<<dim3(256), blk256, 0, stream>>>(batch, N, gn);
    hist_edges_kernel<<<dim3(512), blk256, 0, stream>>>(ei, batch, E, ge);
    graph_stats_kernel<<<dim3(1), dim3(64), 0, stream>>>(gn, ge, feats_norm, logn_norm);
    // 6) t = h @ r_W1[0:256,:] (fp32 SGEMM)
    gemm256_kernel<<<gR, blk256, 0, stream>>>(h, r_W1, nullptr, tf32, nullptr, N, H_DIM);
    // 7) router epilogue -> wts
    router_epi_kernel<<<dim3((N + 3) / 4), blk256, 0, stream>>>(
        tf32, batch, feats_norm, logn_norm, r_W1, r_b1, ln_g, ln_b, r_W2, r_b2, centers, wts, N);
    // 8-10) CSR build
    count_dst_kernel<<<dim3((E + 255) / 256), blk256, 0, stream>>>(ei, E, cnt);
    scan_kernel<<<dim3(1), dim3(1024), 0, stream>>>(cnt, row_ptr, N);
    fill_csr_kernel<<<dim3((E + 255) / 256), blk256, 0, stream>>>(ei, E, row_ptr, fillc, srcs);
    // 11) agg_h = Agg(h_bf)  (flat gather)
    agg_b2b_kernel<<<gAgg, blk256, 0, stream>>>(h_bf, aggh_bf, row_ptr, srcs, N);

    // ---- expert pipeline, EB experts per dispatch, interleaved [n][z][h] slabs ----
    for (int b = 0; b < NEXP / EB; ++b) {
        const int e0 = b * EB;
        // hE0[n][z] = relu([agg_h | h] @ [W0_rel;W0_root]^T + b0)   (A shared across z)
        gemm_bf_kernel<2><<<gM, blk256, 0, stream>>>(
            aggh_bf, 0, 256, h_bf, 0, 256,
            wf0 + (long)e0 * 131072, 131072,
            b0_rel + e0 * H_DIM, H_DIM, hE0, 256, W, N, 512, 1);
        // aggE[n][z] = Agg(hE0)
        aggI_kernel<<<dim3(N), dim3(W / 8), 0, stream>>>(hE0, aggE, row_ptr, srcs, N, W);
        // hE1[n][z] = relu([aggE | hE0] @ [W1_rel;W1_root]^T + b1)
        gemm_bf_kernel<2><<<gM, blk256, 0, stream>>>(
            aggE, 256, W, hE0, 256, W,
            wf1 + (long)e0 * 131072, 131072,
            b1_rel + e0 * H_DIM, H_DIM, hE1, 256, W, N, 512, 1);
        // PR[n][z] = hE1 @ [W2_rel|W2_root]^T   (overlay onto dead hE0/S1)
        gemm_bf_kernel<1><<<gM, blk256, 0, stream>>>(
            hE1, 256, W, nullptr, 0, 256,
            wfin + (long)e0 * 65536, 65536,
            nullptr, 0, PR, 256, W, N, 256, 0);
        // out (+)= sum_z w[:,e0+z] * (Agg(P[z]) + R[z] + b2[e0+z])
        final_mixE_kernel<<<gAgg, blk256, 0, stream>>>(
            PR, b2_rel, wts, e0, EB, row_ptr, srcs, out, N, b == 0 ? 1 : 0);
    }
}